// Round 1
// baseline (827.454 us; speedup 1.0000x reference)
//
#include <hip/hip_runtime.h>
#include <math.h>

#define NN 25000
#define EE 400000
#define GG 64

// ---- workspace layout (element offsets, all 16B-aligned) ----
static const int O_INBN = 0;        // 8 floats: sum x, sum x^2 (zeroed)
static const int O_GCNT = 8;        // 64 ints (zeroed)
static const int O_DEG  = 72;       // 25000 ints (zeroed)
static const int ZERO_END = 25072;  // memset [0, ZERO_END) floats
static const int O_ROWS = 25072;    // 25001 ints
static const int O_CUR  = 50080;    // 25000 ints
static const int O_GOFF = 75080;    // 65 ints
static const int O_WS   = 75152;    // 512 f
static const int O_WD   = 75664;    // 512 f
static const int O_WE   = 76176;    // 8 f
static const int O_BNSUM= 76184;    // 64 f
static const int O_BNSS = 76248;    // 64 f
static const int O_PMEAN= 76312;    // 4096 f
static const int O_PMAX = 80408;    // 4096 f
static const int O_CSRC = 84504;    // 400000 int
static const int O_CDST = 484504;   // 400000 int
static const int O_CEA  = 884504;   // 400000 f
static const int O_EZ   = 1284504;  // 3.2M f
static const int O_XS   = 4484504;  // 12.8M f (xs for layers 0/1; z for layer 2)
static const int O_ASRC = 17284504; // 200000 f
static const int O_ADST = 17484504; // 200000 f
static const int O_AGG  = 17684504; // 1.6M f
static const int O_X    = 19284504; // 1.6M f

// ---------------- input BN stats ----------------
__global__ void k_instats(const float* __restrict__ x, float* __restrict__ sums) {
    int t = threadIdx.x;
    int gid = blockIdx.x * blockDim.x + t;
    float s[3] = {0,0,0}, q[3] = {0,0,0};
    for (int n = gid; n < NN; n += gridDim.x * blockDim.x) {
#pragma unroll
        for (int i = 0; i < 3; i++) { float v = x[n*3+i]; s[i] += v; q[i] += v*v; }
    }
    __shared__ float sd[256*6];
#pragma unroll
    for (int i = 0; i < 3; i++) { sd[t*6+i] = s[i]; sd[t*6+3+i] = q[i]; }
    __syncthreads();
    for (int off = 128; off > 0; off >>= 1) {
        if (t < off) {
#pragma unroll
            for (int i = 0; i < 6; i++) sd[t*6+i] += sd[(t+off)*6+i];
        }
        __syncthreads();
    }
    if (t < 6) atomicAdd(&sums[t], sd[t]);
}

// ---------------- CSR build ----------------
__global__ void k_hist(const int* __restrict__ ei, int* __restrict__ deg) {
    int e = blockIdx.x * 256 + threadIdx.x;
    if (e < EE) atomicAdd(&deg[ei[EE + e]], 1);
}

__global__ void k_scan(const int* __restrict__ deg, int* __restrict__ rows, int* __restrict__ cur) {
    const int C = 25; // 1024*25 >= 25000
    int t = threadIdx.x;
    int base = t * C;
    int mysum = 0;
    for (int k = 0; k < C; k++) { int i = base + k; if (i < NN) mysum += deg[i]; }
    __shared__ int sd[1024];
    sd[t] = mysum; __syncthreads();
    for (int off = 1; off < 1024; off <<= 1) {
        int v = (t >= off) ? sd[t - off] : 0;
        __syncthreads();
        sd[t] += v;
        __syncthreads();
    }
    int run = sd[t] - mysum;
    for (int k = 0; k < C; k++) {
        int i = base + k;
        if (i < NN) { int v = deg[i]; rows[i] = run; cur[i] = run; run += v; }
    }
    if (t == 0) rows[NN] = EE;
}

__global__ void k_fill(const int* __restrict__ ei, const float* __restrict__ ea,
                       int* __restrict__ cur, int* __restrict__ csrc,
                       int* __restrict__ cdst, float* __restrict__ cea) {
    int e = blockIdx.x * 256 + threadIdx.x;
    if (e >= EE) return;
    int s = ei[e], d = ei[EE + e];
    int pos = atomicAdd(&cur[d], 1);
    csrc[pos] = s; cdst[pos] = d; cea[pos] = ea[e];
}

__global__ void k_ghist(const int* __restrict__ batch, int* __restrict__ gcnt) {
    int n = blockIdx.x * 256 + threadIdx.x;
    if (n < NN) atomicAdd(&gcnt[batch[n]], 1);
}

__global__ void k_gscan(const int* __restrict__ gcnt, int* __restrict__ goff) {
    if (threadIdx.x == 0) {
        int run = 0;
        for (int g = 0; g < GG; g++) { goff[g] = run; run += gcnt[g]; }
        goff[GG] = run;
    }
}

// ---------------- per-layer precompute: Ws, Wd, we; zero bn stats ----------------
__global__ void k_prew(const float* __restrict__ W, const float* __restrict__ Wep,
                       const float* __restrict__ as_, const float* __restrict__ ad_,
                       const float* __restrict__ ae_, int INF, int CC,
                       float* __restrict__ Ws, float* __restrict__ Wd, float* __restrict__ wev,
                       float* __restrict__ bnsum, float* __restrict__ bnss) {
    int t = threadIdx.x; // 512 threads
    int HC = 8 * CC;
    if (t < INF * 8) {
        int i = t >> 3, h = t & 7;
        float s = 0.f, d = 0.f;
        for (int c = 0; c < CC; c++) {
            float w = W[i*HC + h*CC + c];
            s += w * as_[h*CC + c];
            d += w * ad_[h*CC + c];
        }
        Ws[i*8 + h] = s; Wd[i*8 + h] = d;
    }
    if (t < 8) {
        float s = 0.f;
        for (int c = 0; c < CC; c++) s += Wep[t*CC + c] * ae_[t*CC + c];
        wev[t] = s;
    }
    if (t < 64) { bnsum[t] = 0.f; bnss[t] = 0.f; }
}

// ---------------- layer-0 projection (input BN fused, in=3) ----------------
__global__ void k_proj0(const float* __restrict__ x, const float* __restrict__ sums,
                        const float* __restrict__ g, const float* __restrict__ b,
                        const float* __restrict__ W0,
                        const float* __restrict__ Ws, const float* __restrict__ Wd,
                        float* __restrict__ xs, float* __restrict__ asrc, float* __restrict__ adst) {
    int idx = blockIdx.x * 256 + threadIdx.x;
    if (idx >= NN * 64) return;
    int n = idx >> 6, j = idx & 63;
    float xn[3];
#pragma unroll
    for (int i = 0; i < 3; i++) {
        float m = sums[i] * (1.0f / NN);
        float v = sums[3+i] * (1.0f / NN) - m*m;
        xn[i] = (x[n*3+i] - m) * rsqrtf(v + 1e-5f) * g[i] + b[i];
    }
    float a = 0.f;
#pragma unroll
    for (int i = 0; i < 3; i++) a += xn[i] * W0[i*64 + j];
    xs[n*64 + j] = a;
    if (j < 16) {
        const float* WA = (j < 8) ? Ws : Wd;
        int h = j & 7;
        float s = 0.f;
#pragma unroll
        for (int i = 0; i < 3; i++) s += xn[i] * WA[i*8 + h];
        if (j < 8) asrc[n*8 + h] = s; else adst[n*8 + h] = s;
    }
}

// ---------------- generic projection (in=64), wave per M nodes ----------------
template<int HC, int M>
__global__ void k_proj(const float* __restrict__ x, const float* __restrict__ W,
                       const float* __restrict__ Ws, const float* __restrict__ Wd,
                       float* __restrict__ xs, float* __restrict__ asrc, float* __restrict__ adst) {
    const int JB = HC / 64;
    int lane = threadIdx.x & 63;
    int wid = (blockIdx.x * blockDim.x + threadIdx.x) >> 6;
    int n0 = wid * M;
    if (n0 >= NN) return;
    float xl[M];
#pragma unroll
    for (int m = 0; m < M; m++) { int n = n0 + m; xl[m] = (n < NN) ? x[n*64 + lane] : 0.f; }
    float acc[JB][M];
#pragma unroll
    for (int jb = 0; jb < JB; jb++)
#pragma unroll
        for (int m = 0; m < M; m++) acc[jb][m] = 0.f;
    float accA[M];
#pragma unroll
    for (int m = 0; m < M; m++) accA[m] = 0.f;
    int al = lane & 7;
    const float* WA = (lane & 8) ? Wd : Ws;
    for (int i = 0; i < 64; i++) {
        float wa = WA[i*8 + al];
        float wv[JB];
#pragma unroll
        for (int jb = 0; jb < JB; jb++) wv[jb] = W[i*HC + jb*64 + lane];
#pragma unroll
        for (int m = 0; m < M; m++) {
            float xi = __shfl(xl[m], i);
            accA[m] += xi * wa;
#pragma unroll
            for (int jb = 0; jb < JB; jb++) acc[jb][m] += xi * wv[jb];
        }
    }
#pragma unroll
    for (int m = 0; m < M; m++) {
        int n = n0 + m;
        if (n >= NN) break;
#pragma unroll
        for (int jb = 0; jb < JB; jb++) xs[n*HC + jb*64 + lane] = acc[jb][m];
        if (lane < 8) asrc[n*8 + lane] = accA[m];
        else if (lane < 16) adst[n*8 + (lane - 8)] = accA[m];
    }
}

// ---------------- layer-2 attention-only projection ----------------
__global__ void k_attn(const float* __restrict__ x, const float* __restrict__ Ws,
                       const float* __restrict__ Wd,
                       float* __restrict__ asrc, float* __restrict__ adst) {
    int idx = blockIdx.x * 256 + threadIdx.x;
    if (idx >= NN * 16) return;
    int n = idx >> 4, r = idx & 15, h = r & 7;
    const float* WA = (r < 8) ? Ws : Wd;
    const float4* xr = (const float4*)(x + n*64);
    float s = 0.f;
#pragma unroll
    for (int i = 0; i < 16; i++) {
        float4 v = xr[i];
        s += v.x * WA[(4*i+0)*8 + h] + v.y * WA[(4*i+1)*8 + h]
           + v.z * WA[(4*i+2)*8 + h] + v.w * WA[(4*i+3)*8 + h];
    }
    if (r < 8) asrc[n*8 + h] = s; else adst[n*8 + h] = s;
}

// ---------------- edge logits -> exp (CSR order) ----------------
__global__ void k_edge(const int* __restrict__ csrc, const int* __restrict__ cdst,
                       const float* __restrict__ cea,
                       const float* __restrict__ asrc, const float* __restrict__ adst,
                       const float* __restrict__ wev, float* __restrict__ ez) {
    int t = blockIdx.x * 256 + threadIdx.x;
    if (t >= EE * 8) return;
    int pos = t >> 3, h = t & 7;
    int s = csrc[pos], d = cdst[pos];
    float l = asrc[s*8 + h] + adst[d*8 + h] + cea[pos] * wev[h];
    l = fmaxf(l, 0.2f * l);      // leaky_relu(0.2)
    ez[t] = __expf(l);
}

// ---------------- aggregation, C=8 (layers 0,1): wave per node ----------------
__global__ void k_agg8(const int* __restrict__ rows, const int* __restrict__ csrc,
                       const float* __restrict__ ez, const float* __restrict__ xs,
                       float* __restrict__ agg) {
    int lane = threadIdx.x & 63;
    int d = (blockIdx.x * blockDim.x + threadIdx.x) >> 6;
    if (d >= NN) return;
    int h = lane >> 3;
    int rs = rows[d], re = rows[d+1];
    float acc = 0.f, den = 0.f;
    for (int p = rs; p < re; p++) {
        int s = csrc[p];
        float e = ez[p*8 + h];
        den += e;
        acc += e * xs[s*64 + lane];
    }
    agg[d*64 + lane] = acc / fmaxf(den, 1e-16f);
}

// ---------------- layer-2 aggregation of raw x into z[n,h,64] ----------------
__global__ void k_agg2(const int* __restrict__ rows, const int* __restrict__ csrc,
                       const float* __restrict__ ez, const float* __restrict__ x,
                       float* __restrict__ z) {
    int lane = threadIdx.x & 63;
    int d = (blockIdx.x * blockDim.x + threadIdx.x) >> 6;
    if (d >= NN) return;
    int rs = rows[d], re = rows[d+1];
    float acc[8] = {0,0,0,0,0,0,0,0};
    int hl = lane & 7;
    float den = 0.f;
    for (int p = rs; p < re; p++) {
        int s = csrc[p];
        float4 e0 = *(const float4*)(ez + p*8);
        float4 e1 = *(const float4*)(ez + p*8 + 4);
        float xv = x[s*64 + lane];
        acc[0] += e0.x * xv; acc[1] += e0.y * xv; acc[2] += e0.z * xv; acc[3] += e0.w * xv;
        acc[4] += e1.x * xv; acc[5] += e1.y * xv; acc[6] += e1.z * xv; acc[7] += e1.w * xv;
        den += ez[p*8 + hl];
    }
#pragma unroll
    for (int h = 0; h < 8; h++) {
        float dh = __shfl(den, h);   // lane h holds den for head h
        z[d*512 + h*64 + lane] = acc[h] / fmaxf(dh, 1e-16f);
    }
}

// ---------------- layer-2 output projection: agg[n,c] = (1/8) sum_h z[n,h,:] @ W2_h[:,c] ----------------
template<int M>
__global__ void k_out2(const float* __restrict__ z, const float* __restrict__ W2,
                       float* __restrict__ agg) {
    int lane = threadIdx.x & 63;
    int wid = (blockIdx.x * blockDim.x + threadIdx.x) >> 6;
    int n0 = wid * M;
    if (n0 >= NN) return;
    float acc[M];
#pragma unroll
    for (int m = 0; m < M; m++) acc[m] = 0.f;
    for (int h = 0; h < 8; h++) {
        for (int i = 0; i < 64; i++) {
            float w = W2[i*512 + h*64 + lane];
#pragma unroll
            for (int m = 0; m < M; m++)
                acc[m] += z[(n0+m)*512 + h*64 + i] * w;
        }
    }
#pragma unroll
    for (int m = 0; m < M; m++) {
        int n = n0 + m;
        if (n < NN) agg[n*64 + lane] = acc[m] * 0.125f;
    }
}

// ---------------- BN stats over nodes (64 channels) ----------------
__global__ void k_bnstats(const float* __restrict__ agg, const float* __restrict__ bias,
                          float* __restrict__ bnsum, float* __restrict__ bnss) {
    int t = threadIdx.x;
    int c = t & 63;
    int r0 = blockIdx.x * 4 + (t >> 6);
    float s = 0.f, q = 0.f;
    float bc = bias[c];
    for (int n = r0; n < NN; n += gridDim.x * 4) {
        float y = agg[n*64 + c] + bc;
        s += y; q += y*y;
    }
    __shared__ float sd[512];
    sd[t] = s; sd[256 + t] = q;
    __syncthreads();
    if (t < 128) { sd[t] += sd[t+128]; sd[256+t] += sd[256+t+128]; }
    __syncthreads();
    if (t < 64) {
        atomicAdd(&bnsum[c], sd[t] + sd[t+64]);
        atomicAdd(&bnss[c],  sd[256+t] + sd[256+t+64]);
    }
}

// ---------------- BN apply + ELU (+ residual) ----------------
__global__ void k_bnapply(const float* __restrict__ agg, const float* __restrict__ bias,
                          const float* __restrict__ bnsum, const float* __restrict__ bnss,
                          const float* __restrict__ gam, const float* __restrict__ bet,
                          float* __restrict__ x, int residual) {
    int idx = blockIdx.x * 256 + threadIdx.x;
    if (idx >= NN * 64) return;
    int c = idx & 63;
    float m = bnsum[c] * (1.0f / NN);
    float v = bnss[c] * (1.0f / NN) - m*m;
    float y = agg[idx] + bias[c];
    float o = (y - m) * rsqrtf(v + 1e-5f) * gam[c] + bet[c];
    float e = (o > 0.f) ? o : (__expf(o) - 1.0f);
    x[idx] = residual ? (x[idx] + e) : e;
}

// ---------------- per-graph dual pooling ----------------
__global__ void k_pool(const float* __restrict__ x, const int* __restrict__ goff,
                       float* __restrict__ pmean, float* __restrict__ pmax) {
    int g = blockIdx.x;
    int t = threadIdx.x;
    int c = t & 63, r = t >> 6;
    int st = goff[g], en = goff[g+1];
    float s = 0.f, mx = -INFINITY;
    for (int n = st + r; n < en; n += 4) {
        float v = x[n*64 + c];
        s += v; mx = fmaxf(mx, v);
    }
    __shared__ float sd[512];
    sd[t] = s; sd[256 + t] = mx;
    __syncthreads();
    if (t < 128) { sd[t] += sd[t+128]; sd[256+t] = fmaxf(sd[256+t], sd[256+t+128]); }
    __syncthreads();
    if (t < 64) {
        float cnt = (float)(en - st);
        pmean[g*64 + c] = (sd[t] + sd[t+64]) / fmaxf(cnt, 1.0f);
        pmax[g*64 + c]  = fmaxf(sd[256+t], sd[256+t+64]);
    }
}

// ---------------- MLP head ----------------
__global__ void k_mlp(const float* __restrict__ pmean, const float* __restrict__ pmax,
                      const float* __restrict__ fc1w, const float* __restrict__ fc1b,
                      const float* __restrict__ fc2w, const float* __restrict__ fc2b,
                      const float* __restrict__ fgw, const float* __restrict__ fgb,
                      const float* __restrict__ fbw, const float* __restrict__ fbb,
                      float* __restrict__ out) {
    int g = blockIdx.x, t = threadIdx.x; // 128 threads
    __shared__ float sg[128], s1[128], s2[64];
    sg[t] = (t < 64) ? pmean[g*64 + t] : pmax[g*64 + (t - 64)];
    __syncthreads();
    float a = fc1b[t];
    for (int i = 0; i < 128; i++) a += sg[i] * fc1w[i*128 + t];
    a = (a > 0.f) ? a : (__expf(a) - 1.f);
    s1[t] = a;
    __syncthreads();
    if (t < 64) {
        float b = fc2b[t];
        for (int i = 0; i < 128; i++) b += s1[i] * fc2w[i*64 + t];
        s2[t] = (b > 0.f) ? b : (__expf(b) - 1.f);
    }
    __syncthreads();
    if (t == 0) {
        float ga = fgb[0], be = fbb[0];
        for (int i = 0; i < 64; i++) { ga += s2[i] * fgw[i]; be += s2[i] * fbw[i]; }
        out[g*2 + 0] = ga;
        out[g*2 + 1] = be;
    }
}

extern "C" void kernel_launch(void* const* d_in, const int* in_sizes, int n_in,
                              void* d_out, int out_size, void* d_ws, size_t ws_size,
                              hipStream_t stream) {
    (void)in_sizes; (void)n_in; (void)out_size; (void)ws_size;
    const float* x3    = (const float*)d_in[0];
    const int*   ei    = (const int*)d_in[1];
    const float* ea    = (const float*)d_in[2];
    const int*   batch = (const int*)d_in[3];
    const float* ing   = (const float*)d_in[4];
    const float* inb   = (const float*)d_in[5];
    const float* w0    = (const float*)d_in[6];
    const float* we0   = (const float*)d_in[7];
    const float* as0   = (const float*)d_in[8];
    const float* ad0   = (const float*)d_in[9];
    const float* ae0   = (const float*)d_in[10];
    const float* b0    = (const float*)d_in[11];
    const float* bng0  = (const float*)d_in[12];
    const float* bnb0  = (const float*)d_in[13];
    const float* w1    = (const float*)d_in[14];
    const float* we1   = (const float*)d_in[15];
    const float* as1   = (const float*)d_in[16];
    const float* ad1   = (const float*)d_in[17];
    const float* ae1   = (const float*)d_in[18];
    const float* b1    = (const float*)d_in[19];
    const float* bng1  = (const float*)d_in[20];
    const float* bnb1  = (const float*)d_in[21];
    const float* w2    = (const float*)d_in[22];
    const float* we2   = (const float*)d_in[23];
    const float* as2   = (const float*)d_in[24];
    const float* ad2   = (const float*)d_in[25];
    const float* ae2   = (const float*)d_in[26];
    const float* b2    = (const float*)d_in[27];
    const float* bng2  = (const float*)d_in[28];
    const float* bnb2  = (const float*)d_in[29];
    const float* fc1w  = (const float*)d_in[30];
    const float* fc1b  = (const float*)d_in[31];
    const float* fc2w  = (const float*)d_in[32];
    const float* fc2b  = (const float*)d_in[33];
    const float* fgw   = (const float*)d_in[34];
    const float* fgb   = (const float*)d_in[35];
    const float* fbw   = (const float*)d_in[36];
    const float* fbb   = (const float*)d_in[37];

    float* fws = (float*)d_ws;
    int*   iws = (int*)d_ws;
    float* inbn  = fws + O_INBN;
    int*   gcnt  = iws + O_GCNT;
    int*   deg   = iws + O_DEG;
    int*   rows  = iws + O_ROWS;
    int*   cur   = iws + O_CUR;
    int*   goff  = iws + O_GOFF;
    float* Ws    = fws + O_WS;
    float* Wd    = fws + O_WD;
    float* wev   = fws + O_WE;
    float* bnsum = fws + O_BNSUM;
    float* bnss  = fws + O_BNSS;
    float* pmean = fws + O_PMEAN;
    float* pmax  = fws + O_PMAX;
    int*   csrc  = iws + O_CSRC;
    int*   cdst  = iws + O_CDST;
    float* cea   = fws + O_CEA;
    float* ez    = fws + O_EZ;
    float* xs    = fws + O_XS;    // z for layer 2
    float* asrc  = fws + O_ASRC;
    float* adst  = fws + O_ADST;
    float* agg   = fws + O_AGG;
    float* xb    = fws + O_X;

    hipMemsetAsync(d_ws, 0, (size_t)ZERO_END * sizeof(float), stream);

    k_instats<<<128, 256, 0, stream>>>(x3, inbn);
    k_hist<<<(EE + 255) / 256, 256, 0, stream>>>(ei, deg);
    k_ghist<<<(NN + 255) / 256, 256, 0, stream>>>(batch, gcnt);
    k_scan<<<1, 1024, 0, stream>>>(deg, rows, cur);
    k_gscan<<<1, 64, 0, stream>>>(gcnt, goff);
    k_fill<<<(EE + 255) / 256, 256, 0, stream>>>(ei, ea, cur, csrc, cdst, cea);

    const int nblk64 = (NN * 64 + 255) / 256;   // 6250
    const int eblk   = (EE * 8 + 255) / 256;    // 12500

    // ---- layer 0 (in=3, C=8, concat) ----
    k_prew<<<1, 512, 0, stream>>>(w0, we0, as0, ad0, ae0, 3, 8, Ws, Wd, wev, bnsum, bnss);
    k_proj0<<<nblk64, 256, 0, stream>>>(x3, inbn, ing, inb, w0, Ws, Wd, xs, asrc, adst);
    k_edge<<<eblk, 256, 0, stream>>>(csrc, cdst, cea, asrc, adst, wev, ez);
    k_agg8<<<nblk64, 256, 0, stream>>>(rows, csrc, ez, xs, agg);
    k_bnstats<<<128, 256, 0, stream>>>(agg, b0, bnsum, bnss);
    k_bnapply<<<nblk64, 256, 0, stream>>>(agg, b0, bnsum, bnss, bng0, bnb0, xb, 0);

    // ---- layer 1 (in=64, C=8, concat, residual) ----
    k_prew<<<1, 512, 0, stream>>>(w1, we1, as1, ad1, ae1, 64, 8, Ws, Wd, wev, bnsum, bnss);
    {
        int waves = (NN + 3) / 4;             // M=4
        int blocks = (waves + 3) / 4;         // 4 waves/block
        k_proj<64, 4><<<blocks, 256, 0, stream>>>(xb, w1, Ws, Wd, xs, asrc, adst);
    }
    k_edge<<<eblk, 256, 0, stream>>>(csrc, cdst, cea, asrc, adst, wev, ez);
    k_agg8<<<nblk64, 256, 0, stream>>>(rows, csrc, ez, xs, agg);
    k_bnstats<<<128, 256, 0, stream>>>(agg, b1, bnsum, bnss);
    k_bnapply<<<nblk64, 256, 0, stream>>>(agg, b1, bnsum, bnss, bng1, bnb1, xb, 1);

    // ---- layer 2 (in=64, C=64, mean over heads, residual) ----
    k_prew<<<1, 512, 0, stream>>>(w2, we2, as2, ad2, ae2, 64, 64, Ws, Wd, wev, bnsum, bnss);
    k_attn<<<(NN * 16 + 255) / 256, 256, 0, stream>>>(xb, Ws, Wd, asrc, adst);
    k_edge<<<eblk, 256, 0, stream>>>(csrc, cdst, cea, asrc, adst, wev, ez);
    k_agg2<<<nblk64, 256, 0, stream>>>(rows, csrc, ez, xb, xs);
    {
        int waves = (NN + 7) / 8;             // M=8
        int blocks = (waves + 3) / 4;
        k_out2<8><<<blocks, 256, 0, stream>>>(xs, w2, agg);
    }
    k_bnstats<<<128, 256, 0, stream>>>(agg, b2, bnsum, bnss);
    k_bnapply<<<nblk64, 256, 0, stream>>>(agg, b2, bnsum, bnss, bng2, bnb2, xb, 1);

    // ---- pooling + MLP head ----
    k_pool<<<GG, 256, 0, stream>>>(xb, goff, pmean, pmax);
    k_mlp<<<GG, 128, 0, stream>>>(pmean, pmax, fc1w, fc1b, fc2w, fc2b,
                                  fgw, fgb, fbw, fbb, (float*)d_out);
}

// Round 2
// 713.830 us; speedup vs baseline: 1.1592x; 1.1592x over previous
//
#include <hip/hip_runtime.h>
#include <math.h>

#define NN 25000
#define EE 400000
#define GG 64

// ---- workspace layout (element offsets, all 16B-aligned) ----
static const int O_INBN = 0;        // 8 floats: sum x, sum x^2 (zeroed)
static const int O_GCNT = 8;        // 64 ints (zeroed)
static const int O_DEG  = 72;       // 25000 ints (zeroed)
static const int ZERO_END = 25072;  // memset [0, ZERO_END) floats
static const int O_ROWS = 25072;    // 25001 ints
static const int O_CUR  = 50080;    // 25000 ints
static const int O_GOFF = 75080;    // 65 ints
static const int O_WS   = 75152;    // 512 f
static const int O_WD   = 75664;    // 512 f
static const int O_WE   = 76176;    // 8 f
static const int O_BNSUM= 76184;    // 64 f
static const int O_BNSS = 76248;    // 64 f
static const int O_PMEAN= 76312;    // 4096 f
static const int O_PMAX = 80408;    // 4096 f
static const int O_CSRC = 84504;    // 400000 int
static const int O_CDST = 484504;   // 400000 int
static const int O_CEA  = 884504;   // 400000 f
static const int O_EZ   = 1284504;  // 3.2M f
static const int O_XS   = 4484504;  // 12.8M f (xs for layers 0/1; z for layer 2)
static const int O_ASRC = 17284504; // 200000 f
static const int O_ADST = 17484504; // 200000 f
static const int O_AGG  = 17684504; // 1.6M f
static const int O_X    = 19284504; // 1.6M f
static const int O_BSW  = 20884504; // 16384 f (= 32768 bf16, swizzled B for layer-2 GEMM)

using f32x4 = __attribute__((ext_vector_type(4))) float;
using sh8   = __attribute__((ext_vector_type(8))) short;  // 8 bf16 (4 VGPRs)

__device__ inline short f2bf(float f) {
    unsigned u = __float_as_uint(f);
    unsigned r = (u + 0x7FFFu + ((u >> 16) & 1u)) >> 16;   // RNE to bf16
    return (short)r;
}

// ---------------- input BN stats ----------------
__global__ void k_instats(const float* __restrict__ x, float* __restrict__ sums) {
    int t = threadIdx.x;
    int gid = blockIdx.x * blockDim.x + t;
    float s[3] = {0,0,0}, q[3] = {0,0,0};
    for (int n = gid; n < NN; n += gridDim.x * blockDim.x) {
#pragma unroll
        for (int i = 0; i < 3; i++) { float v = x[n*3+i]; s[i] += v; q[i] += v*v; }
    }
    __shared__ float sd[256*6];
#pragma unroll
    for (int i = 0; i < 3; i++) { sd[t*6+i] = s[i]; sd[t*6+3+i] = q[i]; }
    __syncthreads();
    for (int off = 128; off > 0; off >>= 1) {
        if (t < off) {
#pragma unroll
            for (int i = 0; i < 6; i++) sd[t*6+i] += sd[(t+off)*6+i];
        }
        __syncthreads();
    }
    if (t < 6) atomicAdd(&sums[t], sd[t]);
}

// ---------------- CSR build ----------------
__global__ void k_hist(const int* __restrict__ ei, int* __restrict__ deg) {
    int e = blockIdx.x * 256 + threadIdx.x;
    if (e < EE) atomicAdd(&deg[ei[EE + e]], 1);
}

__global__ void k_scan(const int* __restrict__ deg, int* __restrict__ rows, int* __restrict__ cur) {
    const int C = 25; // 1024*25 >= 25000
    int t = threadIdx.x;
    int base = t * C;
    int mysum = 0;
    for (int k = 0; k < C; k++) { int i = base + k; if (i < NN) mysum += deg[i]; }
    __shared__ int sd[1024];
    sd[t] = mysum; __syncthreads();
    for (int off = 1; off < 1024; off <<= 1) {
        int v = (t >= off) ? sd[t - off] : 0;
        __syncthreads();
        sd[t] += v;
        __syncthreads();
    }
    int run = sd[t] - mysum;
    for (int k = 0; k < C; k++) {
        int i = base + k;
        if (i < NN) { int v = deg[i]; rows[i] = run; cur[i] = run; run += v; }
    }
    if (t == 0) rows[NN] = EE;
}

__global__ void k_fill(const int* __restrict__ ei, const float* __restrict__ ea,
                       int* __restrict__ cur, int* __restrict__ csrc,
                       int* __restrict__ cdst, float* __restrict__ cea) {
    int e = blockIdx.x * 256 + threadIdx.x;
    if (e >= EE) return;
    int s = ei[e], d = ei[EE + e];
    int pos = atomicAdd(&cur[d], 1);
    csrc[pos] = s; cdst[pos] = d; cea[pos] = ea[e];
}

__global__ void k_ghist(const int* __restrict__ batch, int* __restrict__ gcnt) {
    int n = blockIdx.x * 256 + threadIdx.x;
    if (n < NN) atomicAdd(&gcnt[batch[n]], 1);
}

__global__ void k_gscan(const int* __restrict__ gcnt, int* __restrict__ goff) {
    if (threadIdx.x == 0) {
        int run = 0;
        for (int g = 0; g < GG; g++) { goff[g] = run; run += gcnt[g]; }
        goff[GG] = run;
    }
}

// ---------------- per-layer precompute: Ws, Wd, we; zero bn stats ----------------
__global__ void k_prew(const float* __restrict__ W, const float* __restrict__ Wep,
                       const float* __restrict__ as_, const float* __restrict__ ad_,
                       const float* __restrict__ ae_, int INF, int CC,
                       float* __restrict__ Ws, float* __restrict__ Wd, float* __restrict__ wev,
                       float* __restrict__ bnsum, float* __restrict__ bnss) {
    int t = threadIdx.x; // 512 threads
    int HC = 8 * CC;
    if (t < INF * 8) {
        int i = t >> 3, h = t & 7;
        float s = 0.f, d = 0.f;
        for (int c = 0; c < CC; c++) {
            float w = W[i*HC + h*CC + c];
            s += w * as_[h*CC + c];
            d += w * ad_[h*CC + c];
        }
        Ws[i*8 + h] = s; Wd[i*8 + h] = d;
    }
    if (t < 8) {
        float s = 0.f;
        for (int c = 0; c < CC; c++) s += Wep[t*CC + c] * ae_[t*CC + c];
        wev[t] = s;
    }
    if (t < 64) { bnsum[t] = 0.f; bnss[t] = 0.f; }
}

// ---------------- layer-2 B matrix pre-swizzle into MFMA fragment order ----------------
// B[k = h*64+i][c] = w2[i*512 + h*64 + c];  Bsw[kb][nt][lane][j] = B[kb*32 + kpat][nt*16 + (lane&15)]
__global__ void k_bswz(const float* __restrict__ w2, short* __restrict__ bsw) {
    int idx = blockIdx.x * 256 + threadIdx.x;   // 32768 total
    int j  = idx & 7;
    int l  = (idx >> 3) & 63;
    int nt = (idx >> 9) & 3;
    int kb = idx >> 11;
    int k = kb*32 + (l >> 4)*4 + (j & 3) + 16*(j >> 2);
    int c = nt*16 + (l & 15);
    int h = k >> 6, i = k & 63;
    bsw[idx] = f2bf(w2[i*512 + h*64 + c]);
}

// ---------------- layer-0 projection (input BN fused, in=3) ----------------
__global__ void k_proj0(const float* __restrict__ x, const float* __restrict__ sums,
                        const float* __restrict__ g, const float* __restrict__ b,
                        const float* __restrict__ W0,
                        const float* __restrict__ Ws, const float* __restrict__ Wd,
                        float* __restrict__ xs, float* __restrict__ asrc, float* __restrict__ adst) {
    int idx = blockIdx.x * 256 + threadIdx.x;
    if (idx >= NN * 64) return;
    int n = idx >> 6, j = idx & 63;
    float xn[3];
#pragma unroll
    for (int i = 0; i < 3; i++) {
        float m = sums[i] * (1.0f / NN);
        float v = sums[3+i] * (1.0f / NN) - m*m;
        xn[i] = (x[n*3+i] - m) * rsqrtf(v + 1e-5f) * g[i] + b[i];
    }
    float a = 0.f;
#pragma unroll
    for (int i = 0; i < 3; i++) a += xn[i] * W0[i*64 + j];
    xs[n*64 + j] = a;
    if (j < 16) {
        const float* WA = (j < 8) ? Ws : Wd;
        int h = j & 7;
        float s = 0.f;
#pragma unroll
        for (int i = 0; i < 3; i++) s += xn[i] * WA[i*8 + h];
        if (j < 8) asrc[n*8 + h] = s; else adst[n*8 + h] = s;
    }
}

// ---------------- generic projection (in=64), wave per M nodes ----------------
template<int HC, int M>
__global__ void k_proj(const float* __restrict__ x, const float* __restrict__ W,
                       const float* __restrict__ Ws, const float* __restrict__ Wd,
                       float* __restrict__ xs, float* __restrict__ asrc, float* __restrict__ adst) {
    const int JB = HC / 64;
    int lane = threadIdx.x & 63;
    int wid = (blockIdx.x * blockDim.x + threadIdx.x) >> 6;
    int n0 = wid * M;
    if (n0 >= NN) return;
    float xl[M];
#pragma unroll
    for (int m = 0; m < M; m++) { int n = n0 + m; xl[m] = (n < NN) ? x[n*64 + lane] : 0.f; }
    float acc[JB][M];
#pragma unroll
    for (int jb = 0; jb < JB; jb++)
#pragma unroll
        for (int m = 0; m < M; m++) acc[jb][m] = 0.f;
    float accA[M];
#pragma unroll
    for (int m = 0; m < M; m++) accA[m] = 0.f;
    int al = lane & 7;
    const float* WA = (lane & 8) ? Wd : Ws;
    for (int i = 0; i < 64; i++) {
        float wa = WA[i*8 + al];
        float wv[JB];
#pragma unroll
        for (int jb = 0; jb < JB; jb++) wv[jb] = W[i*HC + jb*64 + lane];
#pragma unroll
        for (int m = 0; m < M; m++) {
            float xi = __shfl(xl[m], i);
            accA[m] += xi * wa;
#pragma unroll
            for (int jb = 0; jb < JB; jb++) acc[jb][m] += xi * wv[jb];
        }
    }
#pragma unroll
    for (int m = 0; m < M; m++) {
        int n = n0 + m;
        if (n >= NN) break;
#pragma unroll
        for (int jb = 0; jb < JB; jb++) xs[n*HC + jb*64 + lane] = acc[jb][m];
        if (lane < 8) asrc[n*8 + lane] = accA[m];
        else if (lane < 16) adst[n*8 + (lane - 8)] = accA[m];
    }
}

// ---------------- layer-2 attention-only projection ----------------
__global__ void k_attn(const float* __restrict__ x, const float* __restrict__ Ws,
                       const float* __restrict__ Wd,
                       float* __restrict__ asrc, float* __restrict__ adst) {
    int idx = blockIdx.x * 256 + threadIdx.x;
    if (idx >= NN * 16) return;
    int n = idx >> 4, r = idx & 15, h = r & 7;
    const float* WA = (r < 8) ? Ws : Wd;
    const float4* xr = (const float4*)(x + n*64);
    float s = 0.f;
#pragma unroll
    for (int i = 0; i < 16; i++) {
        float4 v = xr[i];
        s += v.x * WA[(4*i+0)*8 + h] + v.y * WA[(4*i+1)*8 + h]
           + v.z * WA[(4*i+2)*8 + h] + v.w * WA[(4*i+3)*8 + h];
    }
    if (r < 8) asrc[n*8 + h] = s; else adst[n*8 + h] = s;
}

// ---------------- edge logits -> exp (CSR order) ----------------
__global__ void k_edge(const int* __restrict__ csrc, const int* __restrict__ cdst,
                       const float* __restrict__ cea,
                       const float* __restrict__ asrc, const float* __restrict__ adst,
                       const float* __restrict__ wev, float* __restrict__ ez) {
    int t = blockIdx.x * 256 + threadIdx.x;
    if (t >= EE * 8) return;
    int pos = t >> 3, h = t & 7;
    int s = csrc[pos], d = cdst[pos];
    float l = asrc[s*8 + h] + adst[d*8 + h] + cea[pos] * wev[h];
    l = fmaxf(l, 0.2f * l);      // leaky_relu(0.2)
    ez[t] = __expf(l);
}

// ---------------- aggregation, C=8 (layers 0,1): wave per node ----------------
__global__ void k_agg8(const int* __restrict__ rows, const int* __restrict__ csrc,
                       const float* __restrict__ ez, const float* __restrict__ xs,
                       float* __restrict__ agg) {
    int lane = threadIdx.x & 63;
    int d = (blockIdx.x * blockDim.x + threadIdx.x) >> 6;
    if (d >= NN) return;
    int h = lane >> 3;
    int rs = rows[d], re = rows[d+1];
    float acc = 0.f, den = 0.f;
    for (int p = rs; p < re; p++) {
        int s = csrc[p];
        float e = ez[p*8 + h];
        den += e;
        acc += e * xs[s*64 + lane];
    }
    agg[d*64 + lane] = acc / fmaxf(den, 1e-16f);
}

// ---------------- layer-2 aggregation of raw x into z[n,h,64] ----------------
__global__ void k_agg2(const int* __restrict__ rows, const int* __restrict__ csrc,
                       const float* __restrict__ ez, const float* __restrict__ x,
                       float* __restrict__ z) {
    int lane = threadIdx.x & 63;
    int d = (blockIdx.x * blockDim.x + threadIdx.x) >> 6;
    if (d >= NN) return;
    int rs = rows[d], re = rows[d+1];
    float acc[8] = {0,0,0,0,0,0,0,0};
    int hl = lane & 7;
    float den = 0.f;
    for (int p = rs; p < re; p++) {
        int s = csrc[p];
        float4 e0 = *(const float4*)(ez + p*8);
        float4 e1 = *(const float4*)(ez + p*8 + 4);
        float xv = x[s*64 + lane];
        acc[0] += e0.x * xv; acc[1] += e0.y * xv; acc[2] += e0.z * xv; acc[3] += e0.w * xv;
        acc[4] += e1.x * xv; acc[5] += e1.y * xv; acc[6] += e1.z * xv; acc[7] += e1.w * xv;
        den += ez[p*8 + hl];
    }
#pragma unroll
    for (int h = 0; h < 8; h++) {
        float dh = __shfl(den, h);   // lane h holds den for head h
        z[d*512 + h*64 + lane] = acc[h] / fmaxf(dh, 1e-16f);
    }
}

// ---------------- layer-2 output projection via MFMA ----------------
// agg[25000x64] = (1/8) * z[25000x512] @ B[512x64], bf16 inputs, fp32 accum.
// Wave computes 16 rows x 64 cols = 4 tiles of 16x16 (mfma_f32_16x16x32_bf16, 16 K-steps).
__global__ void k_out2m(const float* __restrict__ z, const short* __restrict__ bsw,
                        float* __restrict__ agg) {
    int l = threadIdx.x & 63;
    int wid = (blockIdx.x * blockDim.x + threadIdx.x) >> 6;
    int n0 = wid * 16;
    if (n0 >= NN) return;
    int ra = n0 + (l & 15);
    if (ra > NN - 1) ra = NN - 1;          // clamp A-row (D row depends only on same A row)
    const float* zr = z + (size_t)ra * 512 + (l >> 4) * 4;
    const sh8* Bs = (const sh8*)bsw;

    f32x4 acc0 = {0,0,0,0}, acc1 = {0,0,0,0}, acc2 = {0,0,0,0}, acc3 = {0,0,0,0};
    for (int kb = 0; kb < 16; kb++) {
        float4 a0 = *(const float4*)(zr + kb*32);
        float4 a1 = *(const float4*)(zr + kb*32 + 16);
        sh8 af;
        af[0] = f2bf(a0.x); af[1] = f2bf(a0.y); af[2] = f2bf(a0.z); af[3] = f2bf(a0.w);
        af[4] = f2bf(a1.x); af[5] = f2bf(a1.y); af[6] = f2bf(a1.z); af[7] = f2bf(a1.w);
        sh8 b0 = Bs[(kb*4 + 0)*64 + l];
        sh8 b1 = Bs[(kb*4 + 1)*64 + l];
        sh8 b2 = Bs[(kb*4 + 2)*64 + l];
        sh8 b3 = Bs[(kb*4 + 3)*64 + l];
        acc0 = __builtin_amdgcn_mfma_f32_16x16x32_bf16(af, b0, acc0, 0, 0, 0);
        acc1 = __builtin_amdgcn_mfma_f32_16x16x32_bf16(af, b1, acc1, 0, 0, 0);
        acc2 = __builtin_amdgcn_mfma_f32_16x16x32_bf16(af, b2, acc2, 0, 0, 0);
        acc3 = __builtin_amdgcn_mfma_f32_16x16x32_bf16(af, b3, acc3, 0, 0, 0);
    }
    // D layout: row = (l>>4)*4 + r, col = nt*16 + (l&15)
    int rbase = n0 + (l >> 4) * 4;
    int cbase = l & 15;
#pragma unroll
    for (int r = 0; r < 4; r++) {
        int n = rbase + r;
        if (n >= NN) break;
        float* ag = agg + (size_t)n * 64 + cbase;
        ag[0]  = acc0[r] * 0.125f;
        ag[16] = acc1[r] * 0.125f;
        ag[32] = acc2[r] * 0.125f;
        ag[48] = acc3[r] * 0.125f;
    }
}

// ---------------- BN stats over nodes (64 channels) ----------------
__global__ void k_bnstats(const float* __restrict__ agg, const float* __restrict__ bias,
                          float* __restrict__ bnsum, float* __restrict__ bnss) {
    int t = threadIdx.x;
    int c = t & 63;
    int r0 = blockIdx.x * 4 + (t >> 6);
    float s = 0.f, q = 0.f;
    float bc = bias[c];
    for (int n = r0; n < NN; n += gridDim.x * 4) {
        float y = agg[n*64 + c] + bc;
        s += y; q += y*y;
    }
    __shared__ float sd[512];
    sd[t] = s; sd[256 + t] = q;
    __syncthreads();
    if (t < 128) { sd[t] += sd[t+128]; sd[256+t] += sd[256+t+128]; }
    __syncthreads();
    if (t < 64) {
        atomicAdd(&bnsum[c], sd[t] + sd[t+64]);
        atomicAdd(&bnss[c],  sd[256+t] + sd[256+t+64]);
    }
}

// ---------------- BN apply + ELU (+ residual) ----------------
__global__ void k_bnapply(const float* __restrict__ agg, const float* __restrict__ bias,
                          const float* __restrict__ bnsum, const float* __restrict__ bnss,
                          const float* __restrict__ gam, const float* __restrict__ bet,
                          float* __restrict__ x, int residual) {
    int idx = blockIdx.x * 256 + threadIdx.x;
    if (idx >= NN * 64) return;
    int c = idx & 63;
    float m = bnsum[c] * (1.0f / NN);
    float v = bnss[c] * (1.0f / NN) - m*m;
    float y = agg[idx] + bias[c];
    float o = (y - m) * rsqrtf(v + 1e-5f) * gam[c] + bet[c];
    float e = (o > 0.f) ? o : (__expf(o) - 1.0f);
    x[idx] = residual ? (x[idx] + e) : e;
}

// ---------------- per-graph dual pooling ----------------
__global__ void k_pool(const float* __restrict__ x, const int* __restrict__ goff,
                       float* __restrict__ pmean, float* __restrict__ pmax) {
    int g = blockIdx.x;
    int t = threadIdx.x;
    int c = t & 63, r = t >> 6;
    int st = goff[g], en = goff[g+1];
    float s = 0.f, mx = -INFINITY;
    for (int n = st + r; n < en; n += 4) {
        float v = x[n*64 + c];
        s += v; mx = fmaxf(mx, v);
    }
    __shared__ float sd[512];
    sd[t] = s; sd[256 + t] = mx;
    __syncthreads();
    if (t < 128) { sd[t] += sd[t+128]; sd[256+t] = fmaxf(sd[256+t], sd[256+t+128]); }
    __syncthreads();
    if (t < 64) {
        float cnt = (float)(en - st);
        pmean[g*64 + c] = (sd[t] + sd[t+64]) / fmaxf(cnt, 1.0f);
        pmax[g*64 + c]  = fmaxf(sd[256+t], sd[256+t+64]);
    }
}

// ---------------- MLP head ----------------
__global__ void k_mlp(const float* __restrict__ pmean, const float* __restrict__ pmax,
                      const float* __restrict__ fc1w, const float* __restrict__ fc1b,
                      const float* __restrict__ fc2w, const float* __restrict__ fc2b,
                      const float* __restrict__ fgw, const float* __restrict__ fgb,
                      const float* __restrict__ fbw, const float* __restrict__ fbb,
                      float* __restrict__ out) {
    int g = blockIdx.x, t = threadIdx.x; // 128 threads
    __shared__ float sg[128], s1[128], s2[64];
    sg[t] = (t < 64) ? pmean[g*64 + t] : pmax[g*64 + (t - 64)];
    __syncthreads();
    float a = fc1b[t];
    for (int i = 0; i < 128; i++) a += sg[i] * fc1w[i*128 + t];
    a = (a > 0.f) ? a : (__expf(a) - 1.f);
    s1[t] = a;
    __syncthreads();
    if (t < 64) {
        float b = fc2b[t];
        for (int i = 0; i < 128; i++) b += s1[i] * fc2w[i*64 + t];
        s2[t] = (b > 0.f) ? b : (__expf(b) - 1.f);
    }
    __syncthreads();
    if (t == 0) {
        float ga = fgb[0], be = fbb[0];
        for (int i = 0; i < 64; i++) { ga += s2[i] * fgw[i]; be += s2[i] * fbw[i]; }
        out[g*2 + 0] = ga;
        out[g*2 + 1] = be;
    }
}

extern "C" void kernel_launch(void* const* d_in, const int* in_sizes, int n_in,
                              void* d_out, int out_size, void* d_ws, size_t ws_size,
                              hipStream_t stream) {
    (void)in_sizes; (void)n_in; (void)out_size; (void)ws_size;
    const float* x3    = (const float*)d_in[0];
    const int*   ei    = (const int*)d_in[1];
    const float* ea    = (const float*)d_in[2];
    const int*   batch = (const int*)d_in[3];
    const float* ing   = (const float*)d_in[4];
    const float* inb   = (const float*)d_in[5];
    const float* w0    = (const float*)d_in[6];
    const float* we0   = (const float*)d_in[7];
    const float* as0   = (const float*)d_in[8];
    const float* ad0   = (const float*)d_in[9];
    const float* ae0   = (const float*)d_in[10];
    const float* b0    = (const float*)d_in[11];
    const float* bng0  = (const float*)d_in[12];
    const float* bnb0  = (const float*)d_in[13];
    const float* w1    = (const float*)d_in[14];
    const float* we1   = (const float*)d_in[15];
    const float* as1   = (const float*)d_in[16];
    const float* ad1   = (const float*)d_in[17];
    const float* ae1   = (const float*)d_in[18];
    const float* b1    = (const float*)d_in[19];
    const float* bng1  = (const float*)d_in[20];
    const float* bnb1  = (const float*)d_in[21];
    const float* w2    = (const float*)d_in[22];
    const float* we2   = (const float*)d_in[23];
    const float* as2   = (const float*)d_in[24];
    const float* ad2   = (const float*)d_in[25];
    const float* ae2   = (const float*)d_in[26];
    const float* b2    = (const float*)d_in[27];
    const float* bng2  = (const float*)d_in[28];
    const float* bnb2  = (const float*)d_in[29];
    const float* fc1w  = (const float*)d_in[30];
    const float* fc1b  = (const float*)d_in[31];
    const float* fc2w  = (const float*)d_in[32];
    const float* fc2b  = (const float*)d_in[33];
    const float* fgw   = (const float*)d_in[34];
    const float* fgb   = (const float*)d_in[35];
    const float* fbw   = (const float*)d_in[36];
    const float* fbb   = (const float*)d_in[37];

    float* fws = (float*)d_ws;
    int*   iws = (int*)d_ws;
    float* inbn  = fws + O_INBN;
    int*   gcnt  = iws + O_GCNT;
    int*   deg   = iws + O_DEG;
    int*   rows  = iws + O_ROWS;
    int*   cur   = iws + O_CUR;
    int*   goff  = iws + O_GOFF;
    float* Ws    = fws + O_WS;
    float* Wd    = fws + O_WD;
    float* wev   = fws + O_WE;
    float* bnsum = fws + O_BNSUM;
    float* bnss  = fws + O_BNSS;
    float* pmean = fws + O_PMEAN;
    float* pmax  = fws + O_PMAX;
    int*   csrc  = iws + O_CSRC;
    int*   cdst  = iws + O_CDST;
    float* cea   = fws + O_CEA;
    float* ez    = fws + O_EZ;
    float* xs    = fws + O_XS;    // z for layer 2
    float* asrc  = fws + O_ASRC;
    float* adst  = fws + O_ADST;
    float* agg   = fws + O_AGG;
    float* xb    = fws + O_X;
    short* bsw   = (short*)(fws + O_BSW);

    hipMemsetAsync(d_ws, 0, (size_t)ZERO_END * sizeof(float), stream);

    k_instats<<<128, 256, 0, stream>>>(x3, inbn);
    k_hist<<<(EE + 255) / 256, 256, 0, stream>>>(ei, deg);
    k_ghist<<<(NN + 255) / 256, 256, 0, stream>>>(batch, gcnt);
    k_scan<<<1, 1024, 0, stream>>>(deg, rows, cur);
    k_gscan<<<1, 64, 0, stream>>>(gcnt, goff);
    k_fill<<<(EE + 255) / 256, 256, 0, stream>>>(ei, ea, cur, csrc, cdst, cea);

    const int nblk64 = (NN * 64 + 255) / 256;   // 6250
    const int eblk   = (EE * 8 + 255) / 256;    // 12500

    // ---- layer 0 (in=3, C=8, concat) ----
    k_prew<<<1, 512, 0, stream>>>(w0, we0, as0, ad0, ae0, 3, 8, Ws, Wd, wev, bnsum, bnss);
    k_proj0<<<nblk64, 256, 0, stream>>>(x3, inbn, ing, inb, w0, Ws, Wd, xs, asrc, adst);
    k_edge<<<eblk, 256, 0, stream>>>(csrc, cdst, cea, asrc, adst, wev, ez);
    k_agg8<<<nblk64, 256, 0, stream>>>(rows, csrc, ez, xs, agg);
    k_bnstats<<<128, 256, 0, stream>>>(agg, b0, bnsum, bnss);
    k_bnapply<<<nblk64, 256, 0, stream>>>(agg, b0, bnsum, bnss, bng0, bnb0, xb, 0);

    // ---- layer 1 (in=64, C=8, concat, residual) ----
    k_prew<<<1, 512, 0, stream>>>(w1, we1, as1, ad1, ae1, 64, 8, Ws, Wd, wev, bnsum, bnss);
    {
        int waves = (NN + 3) / 4;             // M=4
        int blocks = (waves + 3) / 4;         // 4 waves/block
        k_proj<64, 4><<<blocks, 256, 0, stream>>>(xb, w1, Ws, Wd, xs, asrc, adst);
    }
    k_edge<<<eblk, 256, 0, stream>>>(csrc, cdst, cea, asrc, adst, wev, ez);
    k_agg8<<<nblk64, 256, 0, stream>>>(rows, csrc, ez, xs, agg);
    k_bnstats<<<128, 256, 0, stream>>>(agg, b1, bnsum, bnss);
    k_bnapply<<<nblk64, 256, 0, stream>>>(agg, b1, bnsum, bnss, bng1, bnb1, xb, 1);

    // ---- layer 2 (in=64, C=64, mean over heads, residual) ----
    k_prew<<<1, 512, 0, stream>>>(w2, we2, as2, ad2, ae2, 64, 64, Ws, Wd, wev, bnsum, bnss);
    k_bswz<<<128, 256, 0, stream>>>(w2, bsw);
    k_attn<<<(NN * 16 + 255) / 256, 256, 0, stream>>>(xb, Ws, Wd, asrc, adst);
    k_edge<<<eblk, 256, 0, stream>>>(csrc, cdst, cea, asrc, adst, wev, ez);
    k_agg2<<<nblk64, 256, 0, stream>>>(rows, csrc, ez, xb, xs);
    {
        int waves = (NN + 15) / 16;           // 1563 waves
        int blocks = (waves + 3) / 4;         // 4 waves/block
        k_out2m<<<blocks, 256, 0, stream>>>(xs, bsw, agg);
    }
    k_bnstats<<<128, 256, 0, stream>>>(agg, b2, bnsum, bnss);
    k_bnapply<<<nblk64, 256, 0, stream>>>(agg, b2, bnsum, bnss, bng2, bnb2, xb, 1);

    // ---- pooling + MLP head ----
    k_pool<<<GG, 256, 0, stream>>>(xb, goff, pmean, pmax);
    k_mlp<<<GG, 128, 0, stream>>>(pmean, pmax, fc1w, fc1b, fc2w, fc2b,
                                  fgw, fgb, fbw, fbb, (float*)d_out);
}

// Round 3
// 586.939 us; speedup vs baseline: 1.4098x; 1.2162x over previous
//
#include <hip/hip_runtime.h>
#include <math.h>

#define NN 25000
#define EE 400000
#define GG 64

// ---- workspace layout (element offsets, all 16B-aligned) ----
static const int O_INBN = 0;        // 8 floats: sum x, sum x^2 (zeroed)
static const int O_GCNT = 8;        // 64 ints (unused now)
static const int O_DEG  = 72;       // 25000 ints (zeroed)
static const int ZERO_END = 25072;  // memset [0, ZERO_END) floats
static const int O_ROWS = 25072;    // 25001 ints
static const int O_CUR  = 50080;    // 25000 ints
static const int O_GOFF = 75080;    // 65 ints
static const int O_WS   = 75152;    // 512 f
static const int O_WD   = 75664;    // 512 f
static const int O_WE   = 76176;    // 8 f
static const int O_BNSUM= 76184;    // 64 f
static const int O_BNSS = 76248;    // 64 f
static const int O_PMEAN= 76312;    // 4096 f
static const int O_PMAX = 80408;    // 4096 f
static const int O_CSRC = 84504;    // 400000 int
static const int O_CDST = 484504;   // 400000 int (unused now)
static const int O_CEA  = 884504;   // 400000 f
static const int O_EZ   = 1284504;  // (unused now)
static const int O_XS   = 4484504;  // 12.8M f (xs for layers 0/1; z for layer 2)
static const int O_ASRC = 17284504; // 200000 f
static const int O_ADST = 17484504; // 200000 f
static const int O_AGG  = 17684504; // 1.6M f
static const int O_X    = 19284504; // 1.6M f
static const int O_BSW  = 20884504; // 16384 f (= 32768 bf16, swizzled B for layer-2 GEMM)

using f32x4 = __attribute__((ext_vector_type(4))) float;
using sh8   = __attribute__((ext_vector_type(8))) short;  // 8 bf16 (4 VGPRs)

__device__ inline short f2bf(float f) {
    unsigned u = __float_as_uint(f);
    unsigned r = (u + 0x7FFFu + ((u >> 16) & 1u)) >> 16;   // RNE to bf16
    return (short)r;
}

// ---------------- input BN stats ----------------
__global__ void k_instats(const float* __restrict__ x, float* __restrict__ sums) {
    int t = threadIdx.x;
    int gid = blockIdx.x * blockDim.x + t;
    float s[3] = {0,0,0}, q[3] = {0,0,0};
    for (int n = gid; n < NN; n += gridDim.x * blockDim.x) {
#pragma unroll
        for (int i = 0; i < 3; i++) { float v = x[n*3+i]; s[i] += v; q[i] += v*v; }
    }
    __shared__ float sd[256*6];
#pragma unroll
    for (int i = 0; i < 3; i++) { sd[t*6+i] = s[i]; sd[t*6+3+i] = q[i]; }
    __syncthreads();
    for (int off = 128; off > 0; off >>= 1) {
        if (t < off) {
#pragma unroll
            for (int i = 0; i < 6; i++) sd[t*6+i] += sd[(t+off)*6+i];
        }
        __syncthreads();
    }
    if (t < 6) atomicAdd(&sums[t], sd[t]);
}

// ---------------- CSR build ----------------
__global__ void k_hist(const int* __restrict__ ei, int* __restrict__ deg) {
    int e = blockIdx.x * 256 + threadIdx.x;
    if (e < EE) atomicAdd(&deg[ei[EE + e]], 1);
}

__global__ void k_scan(const int* __restrict__ deg, int* __restrict__ rows, int* __restrict__ cur) {
    const int C = 25; // 1024*25 >= 25000
    int t = threadIdx.x;
    int base = t * C;
    int mysum = 0;
    for (int k = 0; k < C; k++) { int i = base + k; if (i < NN) mysum += deg[i]; }
    __shared__ int sd[1024];
    sd[t] = mysum; __syncthreads();
    for (int off = 1; off < 1024; off <<= 1) {
        int v = (t >= off) ? sd[t - off] : 0;
        __syncthreads();
        sd[t] += v;
        __syncthreads();
    }
    int run = sd[t] - mysum;
    for (int k = 0; k < C; k++) {
        int i = base + k;
        if (i < NN) { int v = deg[i]; rows[i] = run; cur[i] = run; run += v; }
    }
    if (t == 0) rows[NN] = EE;
}

__global__ void k_fill(const int* __restrict__ ei, const float* __restrict__ ea,
                       int* __restrict__ cur, int* __restrict__ csrc,
                       float* __restrict__ cea) {
    int e = blockIdx.x * 256 + threadIdx.x;
    if (e >= EE) return;
    int s = ei[e], d = ei[EE + e];
    int pos = atomicAdd(&cur[d], 1);
    csrc[pos] = s; cea[pos] = ea[e];
}

// batch is sorted: graph offsets via binary search (replaces atomic histogram)
__global__ void k_goff(const int* __restrict__ batch, int* __restrict__ goff) {
    int g = threadIdx.x;
    if (g > GG) return;
    int lo = 0, hi = NN;
    while (lo < hi) { int mid = (lo + hi) >> 1; if (batch[mid] < g) lo = mid + 1; else hi = mid; }
    goff[g] = lo;
}

// ---------------- per-layer precompute: Ws, Wd, we; zero bn stats ----------------
__global__ void k_prew(const float* __restrict__ W, const float* __restrict__ Wep,
                       const float* __restrict__ as_, const float* __restrict__ ad_,
                       const float* __restrict__ ae_, int INF, int CC,
                       float* __restrict__ Ws, float* __restrict__ Wd, float* __restrict__ wev,
                       float* __restrict__ bnsum, float* __restrict__ bnss) {
    int t = threadIdx.x; // 512 threads
    int HC = 8 * CC;
    if (t < INF * 8) {
        int i = t >> 3, h = t & 7;
        float s = 0.f, d = 0.f;
        for (int c = 0; c < CC; c++) {
            float w = W[i*HC + h*CC + c];
            s += w * as_[h*CC + c];
            d += w * ad_[h*CC + c];
        }
        Ws[i*8 + h] = s; Wd[i*8 + h] = d;
    }
    if (t < 8) {
        float s = 0.f;
        for (int c = 0; c < CC; c++) s += Wep[t*CC + c] * ae_[t*CC + c];
        wev[t] = s;
    }
    if (t < 64) { bnsum[t] = 0.f; bnss[t] = 0.f; }
}

// ---------------- layer-2 B matrix pre-swizzle into MFMA fragment order ----------------
__global__ void k_bswz(const float* __restrict__ w2, short* __restrict__ bsw) {
    int idx = blockIdx.x * 256 + threadIdx.x;   // 32768 total
    int j  = idx & 7;
    int l  = (idx >> 3) & 63;
    int nt = (idx >> 9) & 3;
    int kb = idx >> 11;
    int k = kb*32 + (l >> 4)*4 + (j & 3) + 16*(j >> 2);
    int c = nt*16 + (l & 15);
    int h = k >> 6, i = k & 63;
    bsw[idx] = f2bf(w2[i*512 + h*64 + c]);
}

// ---------------- layer-0 projection (input BN fused, in=3) ----------------
__global__ void k_proj0(const float* __restrict__ x, const float* __restrict__ sums,
                        const float* __restrict__ g, const float* __restrict__ b,
                        const float* __restrict__ W0,
                        const float* __restrict__ Ws, const float* __restrict__ Wd,
                        float* __restrict__ xs, float* __restrict__ asrc, float* __restrict__ adst) {
    int idx = blockIdx.x * 256 + threadIdx.x;
    if (idx >= NN * 64) return;
    int n = idx >> 6, j = idx & 63;
    float xn[3];
#pragma unroll
    for (int i = 0; i < 3; i++) {
        float m = sums[i] * (1.0f / NN);
        float v = sums[3+i] * (1.0f / NN) - m*m;
        xn[i] = (x[n*3+i] - m) * rsqrtf(v + 1e-5f) * g[i] + b[i];
    }
    float a = 0.f;
#pragma unroll
    for (int i = 0; i < 3; i++) a += xn[i] * W0[i*64 + j];
    xs[n*64 + j] = a;
    if (j < 16) {
        const float* WA = (j < 8) ? Ws : Wd;
        int h = j & 7;
        float s = 0.f;
#pragma unroll
        for (int i = 0; i < 3; i++) s += xn[i] * WA[i*8 + h];
        if (j < 8) asrc[n*8 + h] = s; else adst[n*8 + h] = s;
    }
}

// ---------------- generic projection (in=64), wave per M nodes ----------------
template<int HC, int M>
__global__ void k_proj(const float* __restrict__ x, const float* __restrict__ W,
                       const float* __restrict__ Ws, const float* __restrict__ Wd,
                       float* __restrict__ xs, float* __restrict__ asrc, float* __restrict__ adst) {
    const int JB = HC / 64;
    int lane = threadIdx.x & 63;
    int wid = (blockIdx.x * blockDim.x + threadIdx.x) >> 6;
    int n0 = wid * M;
    if (n0 >= NN) return;
    float xl[M];
#pragma unroll
    for (int m = 0; m < M; m++) { int n = n0 + m; xl[m] = (n < NN) ? x[n*64 + lane] : 0.f; }
    float acc[JB][M];
#pragma unroll
    for (int jb = 0; jb < JB; jb++)
#pragma unroll
        for (int m = 0; m < M; m++) acc[jb][m] = 0.f;
    float accA[M];
#pragma unroll
    for (int m = 0; m < M; m++) accA[m] = 0.f;
    int al = lane & 7;
    const float* WA = (lane & 8) ? Wd : Ws;
    for (int i = 0; i < 64; i++) {
        float wa = WA[i*8 + al];
        float wv[JB];
#pragma unroll
        for (int jb = 0; jb < JB; jb++) wv[jb] = W[i*HC + jb*64 + lane];
#pragma unroll
        for (int m = 0; m < M; m++) {
            float xi = __shfl(xl[m], i);
            accA[m] += xi * wa;
#pragma unroll
            for (int jb = 0; jb < JB; jb++) acc[jb][m] += xi * wv[jb];
        }
    }
#pragma unroll
    for (int m = 0; m < M; m++) {
        int n = n0 + m;
        if (n >= NN) break;
#pragma unroll
        for (int jb = 0; jb < JB; jb++) xs[n*HC + jb*64 + lane] = acc[jb][m];
        if (lane < 8) asrc[n*8 + lane] = accA[m];
        else if (lane < 16) adst[n*8 + (lane - 8)] = accA[m];
    }
}

// ---------------- layer-2 attention-only projection ----------------
__global__ void k_attn(const float* __restrict__ x, const float* __restrict__ Ws,
                       const float* __restrict__ Wd,
                       float* __restrict__ asrc, float* __restrict__ adst) {
    int idx = blockIdx.x * 256 + threadIdx.x;
    if (idx >= NN * 16) return;
    int n = idx >> 4, r = idx & 15, h = r & 7;
    const float* WA = (r < 8) ? Ws : Wd;
    const float4* xr = (const float4*)(x + n*64);
    float s = 0.f;
#pragma unroll
    for (int i = 0; i < 16; i++) {
        float4 v = xr[i];
        s += v.x * WA[(4*i+0)*8 + h] + v.y * WA[(4*i+1)*8 + h]
           + v.z * WA[(4*i+2)*8 + h] + v.w * WA[(4*i+3)*8 + h];
    }
    if (r < 8) asrc[n*8 + h] = s; else adst[n*8 + h] = s;
}

// ---------------- fused edge-softmax + aggregation, C=8 (layers 0,1) ----------------
__global__ void k_agg8f(const int* __restrict__ rows, const int* __restrict__ csrc,
                        const float* __restrict__ cea,
                        const float* __restrict__ asrc, const float* __restrict__ adst,
                        const float* __restrict__ wev,
                        const float* __restrict__ xs, float* __restrict__ agg) {
    int lane = threadIdx.x & 63;
    int d = (blockIdx.x * blockDim.x + threadIdx.x) >> 6;
    if (d >= NN) return;
    int h = lane >> 3;
    float adh = adst[d*8 + h];
    float wh  = wev[h];
    int rs = rows[d], re = rows[d+1];
    float acc = 0.f, den = 0.f;
    for (int p = rs; p < re; p++) {
        int s = csrc[p];
        float l = asrc[s*8 + h] + adh + cea[p] * wh;
        l = fmaxf(l, 0.2f * l);          // leaky_relu(0.2)
        float e = __expf(l);
        den += e;
        acc += e * xs[s*64 + lane];
    }
    agg[d*64 + lane] = acc / fmaxf(den, 1e-16f);
}

// ---------------- fused layer-2: edge-softmax + aggregation of raw x into z[n,h,64] ----------------
__global__ void k_agg2f(const int* __restrict__ rows, const int* __restrict__ csrc,
                        const float* __restrict__ cea,
                        const float* __restrict__ asrc, const float* __restrict__ adst,
                        const float* __restrict__ wev,
                        const float* __restrict__ x, float* __restrict__ z) {
    int lane = threadIdx.x & 63;
    int d = (blockIdx.x * blockDim.x + threadIdx.x) >> 6;
    if (d >= NN) return;
    int hl = lane & 7;
    float adh = adst[d*8 + hl];
    float wh  = wev[hl];
    int rs = rows[d], re = rows[d+1];
    float acc[8] = {0,0,0,0,0,0,0,0};
    float den = 0.f;
    for (int p = rs; p < re; p++) {
        int s = csrc[p];
        float l = asrc[s*8 + hl] + adh + cea[p] * wh;
        l = fmaxf(l, 0.2f * l);
        float e = __expf(l);               // lane holds head (lane&7)
        den += e;
        float xv = x[s*64 + lane];
#pragma unroll
        for (int hh = 0; hh < 8; hh++)
            acc[hh] += __shfl(e, hh) * xv; // lanes 0..7 hold heads 0..7
    }
#pragma unroll
    for (int hh = 0; hh < 8; hh++) {
        float dh = __shfl(den, hh);
        z[d*512 + hh*64 + lane] = acc[hh] / fmaxf(dh, 1e-16f);
    }
}

// ---------------- layer-2 output projection via MFMA ----------------
__global__ void k_out2m(const float* __restrict__ z, const short* __restrict__ bsw,
                        float* __restrict__ agg) {
    int l = threadIdx.x & 63;
    int wid = (blockIdx.x * blockDim.x + threadIdx.x) >> 6;
    int n0 = wid * 16;
    if (n0 >= NN) return;
    int ra = n0 + (l & 15);
    if (ra > NN - 1) ra = NN - 1;          // clamp A-row
    const float* zr = z + (size_t)ra * 512 + (l >> 4) * 4;
    const sh8* Bs = (const sh8*)bsw;

    f32x4 acc0 = {0,0,0,0}, acc1 = {0,0,0,0}, acc2 = {0,0,0,0}, acc3 = {0,0,0,0};
    for (int kb = 0; kb < 16; kb++) {
        float4 a0 = *(const float4*)(zr + kb*32);
        float4 a1 = *(const float4*)(zr + kb*32 + 16);
        sh8 af;
        af[0] = f2bf(a0.x); af[1] = f2bf(a0.y); af[2] = f2bf(a0.z); af[3] = f2bf(a0.w);
        af[4] = f2bf(a1.x); af[5] = f2bf(a1.y); af[6] = f2bf(a1.z); af[7] = f2bf(a1.w);
        sh8 b0 = Bs[(kb*4 + 0)*64 + l];
        sh8 b1 = Bs[(kb*4 + 1)*64 + l];
        sh8 b2 = Bs[(kb*4 + 2)*64 + l];
        sh8 b3 = Bs[(kb*4 + 3)*64 + l];
        acc0 = __builtin_amdgcn_mfma_f32_16x16x32_bf16(af, b0, acc0, 0, 0, 0);
        acc1 = __builtin_amdgcn_mfma_f32_16x16x32_bf16(af, b1, acc1, 0, 0, 0);
        acc2 = __builtin_amdgcn_mfma_f32_16x16x32_bf16(af, b2, acc2, 0, 0, 0);
        acc3 = __builtin_amdgcn_mfma_f32_16x16x32_bf16(af, b3, acc3, 0, 0, 0);
    }
    int rbase = n0 + (l >> 4) * 4;
    int cbase = l & 15;
#pragma unroll
    for (int r = 0; r < 4; r++) {
        int n = rbase + r;
        if (n >= NN) break;
        float* ag = agg + (size_t)n * 64 + cbase;
        ag[0]  = acc0[r] * 0.125f;
        ag[16] = acc1[r] * 0.125f;
        ag[32] = acc2[r] * 0.125f;
        ag[48] = acc3[r] * 0.125f;
    }
}

// ---------------- BN stats over nodes (64 channels) ----------------
__global__ void k_bnstats(const float* __restrict__ agg, const float* __restrict__ bias,
                          float* __restrict__ bnsum, float* __restrict__ bnss) {
    int t = threadIdx.x;
    int c = t & 63;
    int r0 = blockIdx.x * 4 + (t >> 6);
    float s = 0.f, q = 0.f;
    float bc = bias[c];
    for (int n = r0; n < NN; n += gridDim.x * 4) {
        float y = agg[n*64 + c] + bc;
        s += y; q += y*y;
    }
    __shared__ float sd[512];
    sd[t] = s; sd[256 + t] = q;
    __syncthreads();
    if (t < 128) { sd[t] += sd[t+128]; sd[256+t] += sd[256+t+128]; }
    __syncthreads();
    if (t < 64) {
        atomicAdd(&bnsum[c], sd[t] + sd[t+64]);
        atomicAdd(&bnss[c],  sd[256+t] + sd[256+t+64]);
    }
}

// ---------------- BN apply + ELU (+ residual) ----------------
__global__ void k_bnapply(const float* __restrict__ agg, const float* __restrict__ bias,
                          const float* __restrict__ bnsum, const float* __restrict__ bnss,
                          const float* __restrict__ gam, const float* __restrict__ bet,
                          float* __restrict__ x, int residual) {
    int idx = blockIdx.x * 256 + threadIdx.x;
    if (idx >= NN * 64) return;
    int c = idx & 63;
    float m = bnsum[c] * (1.0f / NN);
    float v = bnss[c] * (1.0f / NN) - m*m;
    float y = agg[idx] + bias[c];
    float o = (y - m) * rsqrtf(v + 1e-5f) * gam[c] + bet[c];
    float e = (o > 0.f) ? o : (__expf(o) - 1.0f);
    x[idx] = residual ? (x[idx] + e) : e;
}

// ---------------- per-graph dual pooling ----------------
__global__ void k_pool(const float* __restrict__ x, const int* __restrict__ goff,
                       float* __restrict__ pmean, float* __restrict__ pmax) {
    int g = blockIdx.x;
    int t = threadIdx.x;
    int c = t & 63, r = t >> 6;
    int st = goff[g], en = goff[g+1];
    float s = 0.f, mx = -INFINITY;
    for (int n = st + r; n < en; n += 4) {
        float v = x[n*64 + c];
        s += v; mx = fmaxf(mx, v);
    }
    __shared__ float sd[512];
    sd[t] = s; sd[256 + t] = mx;
    __syncthreads();
    if (t < 128) { sd[t] += sd[t+128]; sd[256+t] = fmaxf(sd[256+t], sd[256+t+128]); }
    __syncthreads();
    if (t < 64) {
        float cnt = (float)(en - st);
        pmean[g*64 + c] = (sd[t] + sd[t+64]) / fmaxf(cnt, 1.0f);
        pmax[g*64 + c]  = fmaxf(sd[256+t], sd[256+t+64]);
    }
}

// ---------------- MLP head ----------------
__global__ void k_mlp(const float* __restrict__ pmean, const float* __restrict__ pmax,
                      const float* __restrict__ fc1w, const float* __restrict__ fc1b,
                      const float* __restrict__ fc2w, const float* __restrict__ fc2b,
                      const float* __restrict__ fgw, const float* __restrict__ fgb,
                      const float* __restrict__ fbw, const float* __restrict__ fbb,
                      float* __restrict__ out) {
    int g = blockIdx.x, t = threadIdx.x; // 128 threads
    __shared__ float sg[128], s1[128], s2[64];
    sg[t] = (t < 64) ? pmean[g*64 + t] : pmax[g*64 + (t - 64)];
    __syncthreads();
    float a = fc1b[t];
    for (int i = 0; i < 128; i++) a += sg[i] * fc1w[i*128 + t];
    a = (a > 0.f) ? a : (__expf(a) - 1.f);
    s1[t] = a;
    __syncthreads();
    if (t < 64) {
        float b = fc2b[t];
        for (int i = 0; i < 128; i++) b += s1[i] * fc2w[i*64 + t];
        s2[t] = (b > 0.f) ? b : (__expf(b) - 1.f);
    }
    __syncthreads();
    if (t == 0) {
        float ga = fgb[0], be = fbb[0];
        for (int i = 0; i < 64; i++) { ga += s2[i] * fgw[i]; be += s2[i] * fbw[i]; }
        out[g*2 + 0] = ga;
        out[g*2 + 1] = be;
    }
}

extern "C" void kernel_launch(void* const* d_in, const int* in_sizes, int n_in,
                              void* d_out, int out_size, void* d_ws, size_t ws_size,
                              hipStream_t stream) {
    (void)in_sizes; (void)n_in; (void)out_size; (void)ws_size;
    const float* x3    = (const float*)d_in[0];
    const int*   ei    = (const int*)d_in[1];
    const float* ea    = (const float*)d_in[2];
    const int*   batch = (const int*)d_in[3];
    const float* ing   = (const float*)d_in[4];
    const float* inb   = (const float*)d_in[5];
    const float* w0    = (const float*)d_in[6];
    const float* we0   = (const float*)d_in[7];
    const float* as0   = (const float*)d_in[8];
    const float* ad0   = (const float*)d_in[9];
    const float* ae0   = (const float*)d_in[10];
    const float* b0    = (const float*)d_in[11];
    const float* bng0  = (const float*)d_in[12];
    const float* bnb0  = (const float*)d_in[13];
    const float* w1    = (const float*)d_in[14];
    const float* we1   = (const float*)d_in[15];
    const float* as1   = (const float*)d_in[16];
    const float* ad1   = (const float*)d_in[17];
    const float* ae1   = (const float*)d_in[18];
    const float* b1    = (const float*)d_in[19];
    const float* bng1  = (const float*)d_in[20];
    const float* bnb1  = (const float*)d_in[21];
    const float* w2    = (const float*)d_in[22];
    const float* we2   = (const float*)d_in[23];
    const float* as2   = (const float*)d_in[24];
    const float* ad2   = (const float*)d_in[25];
    const float* ae2   = (const float*)d_in[26];
    const float* b2    = (const float*)d_in[27];
    const float* bng2  = (const float*)d_in[28];
    const float* bnb2  = (const float*)d_in[29];
    const float* fc1w  = (const float*)d_in[30];
    const float* fc1b  = (const float*)d_in[31];
    const float* fc2w  = (const float*)d_in[32];
    const float* fc2b  = (const float*)d_in[33];
    const float* fgw   = (const float*)d_in[34];
    const float* fgb   = (const float*)d_in[35];
    const float* fbw   = (const float*)d_in[36];
    const float* fbb   = (const float*)d_in[37];

    float* fws = (float*)d_ws;
    int*   iws = (int*)d_ws;
    float* inbn  = fws + O_INBN;
    int*   deg   = iws + O_DEG;
    int*   rows  = iws + O_ROWS;
    int*   cur   = iws + O_CUR;
    int*   goff  = iws + O_GOFF;
    float* Ws    = fws + O_WS;
    float* Wd    = fws + O_WD;
    float* wev   = fws + O_WE;
    float* bnsum = fws + O_BNSUM;
    float* bnss  = fws + O_BNSS;
    float* pmean = fws + O_PMEAN;
    float* pmax  = fws + O_PMAX;
    int*   csrc  = iws + O_CSRC;
    float* cea   = fws + O_CEA;
    float* xs    = fws + O_XS;    // z for layer 2
    float* asrc  = fws + O_ASRC;
    float* adst  = fws + O_ADST;
    float* agg   = fws + O_AGG;
    float* xb    = fws + O_X;
    short* bsw   = (short*)(fws + O_BSW);

    hipMemsetAsync(d_ws, 0, (size_t)ZERO_END * sizeof(float), stream);

    k_instats<<<128, 256, 0, stream>>>(x3, inbn);
    k_hist<<<(EE + 255) / 256, 256, 0, stream>>>(ei, deg);
    k_goff<<<1, 128, 0, stream>>>(batch, goff);
    k_scan<<<1, 1024, 0, stream>>>(deg, rows, cur);
    k_fill<<<(EE + 255) / 256, 256, 0, stream>>>(ei, ea, cur, csrc, cea);

    const int nblk64 = (NN * 64 + 255) / 256;   // 6250

    // ---- layer 0 (in=3, C=8, concat) ----
    k_prew<<<1, 512, 0, stream>>>(w0, we0, as0, ad0, ae0, 3, 8, Ws, Wd, wev, bnsum, bnss);
    k_proj0<<<nblk64, 256, 0, stream>>>(x3, inbn, ing, inb, w0, Ws, Wd, xs, asrc, adst);
    k_agg8f<<<nblk64, 256, 0, stream>>>(rows, csrc, cea, asrc, adst, wev, xs, agg);
    k_bnstats<<<128, 256, 0, stream>>>(agg, b0, bnsum, bnss);
    k_bnapply<<<nblk64, 256, 0, stream>>>(agg, b0, bnsum, bnss, bng0, bnb0, xb, 0);

    // ---- layer 1 (in=64, C=8, concat, residual) ----
    k_prew<<<1, 512, 0, stream>>>(w1, we1, as1, ad1, ae1, 64, 8, Ws, Wd, wev, bnsum, bnss);
    {
        int waves = (NN + 3) / 4;             // M=4
        int blocks = (waves + 3) / 4;         // 4 waves/block
        k_proj<64, 4><<<blocks, 256, 0, stream>>>(xb, w1, Ws, Wd, xs, asrc, adst);
    }
    k_agg8f<<<nblk64, 256, 0, stream>>>(rows, csrc, cea, asrc, adst, wev, xs, agg);
    k_bnstats<<<128, 256, 0, stream>>>(agg, b1, bnsum, bnss);
    k_bnapply<<<nblk64, 256, 0, stream>>>(agg, b1, bnsum, bnss, bng1, bnb1, xb, 1);

    // ---- layer 2 (in=64, C=64, mean over heads, residual) ----
    k_prew<<<1, 512, 0, stream>>>(w2, we2, as2, ad2, ae2, 64, 64, Ws, Wd, wev, bnsum, bnss);
    k_bswz<<<128, 256, 0, stream>>>(w2, bsw);
    k_attn<<<(NN * 16 + 255) / 256, 256, 0, stream>>>(xb, Ws, Wd, asrc, adst);
    k_agg2f<<<nblk64, 256, 0, stream>>>(rows, csrc, cea, asrc, adst, wev, xb, xs);
    {
        int waves = (NN + 15) / 16;           // 1563 waves
        int blocks = (waves + 3) / 4;         // 4 waves/block
        k_out2m<<<blocks, 256, 0, stream>>>(xs, bsw, agg);
    }
    k_bnstats<<<128, 256, 0, stream>>>(agg, b2, bnsum, bnss);
    k_bnapply<<<nblk64, 256, 0, stream>>>(agg, b2, bnsum, bnss, bng2, bnb2, xb, 1);

    // ---- pooling + MLP head ----
    k_pool<<<GG, 256, 0, stream>>>(xb, goff, pmean, pmax);
    k_mlp<<<GG, 128, 0, stream>>>(pmean, pmax, fc1w, fc1b, fc2w, fc2b,
                                  fgw, fgb, fbw, fbb, (float*)d_out);
}

// Round 4
// 553.397 us; speedup vs baseline: 1.4952x; 1.0606x over previous
//
#include <hip/hip_runtime.h>
#include <math.h>

#define NN 25000
#define EE 400000
#define GG 64

// ---- workspace layout (element offsets, 16B-aligned) ----
static const int O_DEG   = 0;        // 25000 ints (zeroed by memset)
static const int ZERO_END= 25000;
static const int O_ROWS  = 25008;    // 25001 ints
static const int O_CUR   = 50016;    // 25000 ints
static const int O_GOFF  = 75016;    // 65 ints
static const int O_IPART = 75088;    // 16*6 f
static const int O_INBN  = 75184;    // 6 f (finalized input-BN sums)
static const int O_WS    = 75192;    // 3*512 f
static const int O_WD    = 76728;    // 3*512 f
static const int O_WE    = 78264;    // 3*8 f
static const int O_BPART = 78288;    // 128*128 f (BN partials)
static const int O_AB    = 94672;    // 128 f (BN scale[64], shift[64])
static const int O_BSW   = 94800;    // 16384 f = 32768 bf16 (swizzled W2)
static const int O_CSRC  = 111184;   // 400000 int
static const int O_CEA   = 511184;   // 400000 f
static const int O_XS    = 911184;   // 1.6M f (projected feats, layers 0/1)
static const int O_ASRC  = 2511184;  // 200000 f
static const int O_ADST  = 2711184;  // 200000 f
static const int O_AGG   = 2911184;  // 1.6M f
static const int O_X     = 4511184;  // 1.6M f

using f32x4 = __attribute__((ext_vector_type(4))) float;
using sh8   = __attribute__((ext_vector_type(8))) short;  // 8 bf16

__device__ inline short f2bf(float f) {
    unsigned u = __float_as_uint(f);
    unsigned r = (u + 0x7FFFu + ((u >> 16) & 1u)) >> 16;   // RNE to bf16
    return (short)r;
}

// ============ mega setup kernel: hist | instats | goff | prew x3 | bswz ============
__global__ void k_pre(const int* __restrict__ ei, const int* __restrict__ batch,
                      const float* __restrict__ x3,
                      const float* w0, const float* we0, const float* as0, const float* ad0, const float* ae0,
                      const float* w1, const float* we1, const float* as1, const float* ad1, const float* ae1,
                      const float* w2, const float* we2, const float* as2, const float* ad2, const float* ae2,
                      int* __restrict__ deg, int* __restrict__ goff, float* __restrict__ ipart,
                      float* __restrict__ Ws, float* __restrict__ Wd, float* __restrict__ wev,
                      short* __restrict__ bsw) {
    __shared__ float sd[1536];
    int b = blockIdx.x, t = threadIdx.x;
    if (b < 1563) {                       // edge histogram
        int e = b * 256 + t;
        if (e < EE) atomicAdd(&deg[ei[EE + e]], 1);
    } else if (b < 1579) {                // input-BN partial stats (16 blocks)
        int ib = b - 1563;
        float s[3] = {0,0,0}, q[3] = {0,0,0};
        for (int n = ib * 256 + t; n < NN; n += 16 * 256) {
#pragma unroll
            for (int i = 0; i < 3; i++) { float v = x3[n*3+i]; s[i] += v; q[i] += v*v; }
        }
#pragma unroll
        for (int i = 0; i < 3; i++) { sd[t*6+i] = s[i]; sd[t*6+3+i] = q[i]; }
        __syncthreads();
        for (int off = 128; off > 0; off >>= 1) {
            if (t < off) {
#pragma unroll
                for (int i = 0; i < 6; i++) sd[t*6+i] += sd[(t+off)*6+i];
            }
            __syncthreads();
        }
        if (t < 6) ipart[ib*6 + t] = sd[t];
    } else if (b == 1579) {               // graph offsets: batch is sorted -> binary search
        if (t <= GG) {
            int g = t, lo = 0, hi = NN;
            while (lo < hi) { int mid = (lo + hi) >> 1; if (batch[mid] < g) lo = mid + 1; else hi = mid; }
            goff[g] = lo;
        }
    } else if (b < 1583) {                // per-layer attention weight fold
        int L = b - 1580;
        const float *W, *Wep, *as_, *ad_, *ae_; int INF, CC;
        if (L == 0)      { W = w0; Wep = we0; as_ = as0; ad_ = ad0; ae_ = ae0; INF = 3;  CC = 8;  }
        else if (L == 1) { W = w1; Wep = we1; as_ = as1; ad_ = ad1; ae_ = ae1; INF = 64; CC = 8;  }
        else             { W = w2; Wep = we2; as_ = as2; ad_ = ad2; ae_ = ae2; INF = 64; CC = 64; }
        int HC = 8 * CC;
        for (int tt = t; tt < INF * 8; tt += 256) {
            int i = tt >> 3, h = tt & 7;
            float s = 0.f, d = 0.f;
            for (int c = 0; c < CC; c++) {
                float w = W[i*HC + h*CC + c];
                s += w * as_[h*CC + c];
                d += w * ad_[h*CC + c];
            }
            Ws[L*512 + i*8 + h] = s; Wd[L*512 + i*8 + h] = d;
        }
        if (t < 8) {
            float s = 0.f;
            for (int c = 0; c < CC; c++) s += Wep[t*CC + c] * ae_[t*CC + c];
            wev[L*8 + t] = s;
        }
    } else {                              // W2 swizzle into MFMA B-fragment order (128 blocks)
        int idx = (b - 1583) * 256 + t;   // < 32768
        int j  = idx & 7;
        int l  = (idx >> 3) & 63;
        int nt = (idx >> 9) & 3;
        int kb = idx >> 11;
        int k = kb*32 + (l >> 4)*4 + (j & 3) + 16*(j >> 2);
        int c = nt*16 + (l & 15);
        int h = k >> 6, i = k & 63;
        bsw[idx] = f2bf(w2[i*512 + h*64 + c]);
    }
}

// ============ degree scan -> CSR rows (+ finalize input-BN stats) ============
__global__ void k_scan(const int* __restrict__ deg, const float* __restrict__ ipart,
                       int* __restrict__ rows, int* __restrict__ cur, float* __restrict__ inbn) {
    const int C = 25; // 1024*25 >= 25000
    int t = threadIdx.x;
    if (t < 6) { float s = 0.f; for (int b = 0; b < 16; b++) s += ipart[b*6 + t]; inbn[t] = s; }
    int base = t * C;
    int mysum = 0;
    for (int k = 0; k < C; k++) { int i = base + k; if (i < NN) mysum += deg[i]; }
    __shared__ int sd[1024];
    sd[t] = mysum; __syncthreads();
    for (int off = 1; off < 1024; off <<= 1) {
        int v = (t >= off) ? sd[t - off] : 0;
        __syncthreads();
        sd[t] += v;
        __syncthreads();
    }
    int run = sd[t] - mysum;
    for (int k = 0; k < C; k++) {
        int i = base + k;
        if (i < NN) { int v = deg[i]; rows[i] = run; cur[i] = run; run += v; }
    }
    if (t == 0) rows[NN] = EE;
}

__global__ void k_fill(const int* __restrict__ ei, const float* __restrict__ ea,
                       int* __restrict__ cur, int* __restrict__ csrc,
                       float* __restrict__ cea) {
    int e = blockIdx.x * 256 + threadIdx.x;
    if (e >= EE) return;
    int s = ei[e], d = ei[EE + e];
    int pos = atomicAdd(&cur[d], 1);
    csrc[pos] = s; cea[pos] = ea[e];
}

// ============ layer-0 projection (input BN fused, in=3) ============
__global__ void k_proj0(const float* __restrict__ x, const float* __restrict__ sums,
                        const float* __restrict__ g, const float* __restrict__ b,
                        const float* __restrict__ W0,
                        const float* __restrict__ Ws, const float* __restrict__ Wd,
                        float* __restrict__ xs, float* __restrict__ asrc, float* __restrict__ adst) {
    int idx = blockIdx.x * 256 + threadIdx.x;
    if (idx >= NN * 64) return;
    int n = idx >> 6, j = idx & 63;
    float xn[3];
#pragma unroll
    for (int i = 0; i < 3; i++) {
        float m = sums[i] * (1.0f / NN);
        float v = sums[3+i] * (1.0f / NN) - m*m;
        xn[i] = (x[n*3+i] - m) * rsqrtf(v + 1e-5f) * g[i] + b[i];
    }
    float a = 0.f;
#pragma unroll
    for (int i = 0; i < 3; i++) a += xn[i] * W0[i*64 + j];
    xs[n*64 + j] = a;
    if (j < 16) {
        const float* WA = (j < 8) ? Ws : Wd;
        int h = j & 7;
        float s = 0.f;
#pragma unroll
        for (int i = 0; i < 3; i++) s += xn[i] * WA[i*8 + h];
        if (j < 8) asrc[n*8 + h] = s; else adst[n*8 + h] = s;
    }
}

// ============ layer-1 projection with fused BN0-apply+ELU (in=64, wave/4 nodes) ============
template<int M>
__global__ void k_projbn(const float* __restrict__ agg, const float* __restrict__ ab,
                         const float* __restrict__ W,
                         const float* __restrict__ Ws, const float* __restrict__ Wd,
                         float* __restrict__ xb, float* __restrict__ xs,
                         float* __restrict__ asrc, float* __restrict__ adst) {
    int lane = threadIdx.x & 63;
    int wid = (blockIdx.x * blockDim.x + threadIdx.x) >> 6;
    int n0 = wid * M;
    if (n0 >= NN) return;
    float a = ab[lane], sh = ab[64 + lane];
    float xl[M];
#pragma unroll
    for (int m = 0; m < M; m++) {
        int n = n0 + m;
        if (n < NN) {
            float o = agg[n*64 + lane] * a + sh;
            o = (o > 0.f) ? o : (__expf(o) - 1.0f);   // ELU, no residual (layer 0)
            xl[m] = o;
            xb[n*64 + lane] = o;
        } else xl[m] = 0.f;
    }
    float acc[M], accA[M];
#pragma unroll
    for (int m = 0; m < M; m++) { acc[m] = 0.f; accA[m] = 0.f; }
    int al = lane & 7;
    const float* WA = (lane & 8) ? Wd : Ws;
    for (int i = 0; i < 64; i++) {
        float wa = WA[i*8 + al];
        float wv = W[i*64 + lane];
#pragma unroll
        for (int m = 0; m < M; m++) {
            float xi = __shfl(xl[m], i);
            accA[m] += xi * wa;
            acc[m]  += xi * wv;
        }
    }
#pragma unroll
    for (int m = 0; m < M; m++) {
        int n = n0 + m;
        if (n >= NN) break;
        xs[n*64 + lane] = acc[m];
        if (lane < 8) asrc[n*8 + lane] = accA[m];
        else if (lane < 16) adst[n*8 + (lane - 8)] = accA[m];
    }
}

// ============ layer-2 attention logits ============
__global__ void k_attn(const float* __restrict__ x, const float* __restrict__ Ws,
                       const float* __restrict__ Wd,
                       float* __restrict__ asrc, float* __restrict__ adst) {
    int idx = blockIdx.x * 256 + threadIdx.x;
    if (idx >= NN * 16) return;
    int n = idx >> 4, r = idx & 15, h = r & 7;
    const float* WA = (r < 8) ? Ws : Wd;
    const float4* xr = (const float4*)(x + n*64);
    float s = 0.f;
#pragma unroll
    for (int i = 0; i < 16; i++) {
        float4 v = xr[i];
        s += v.x * WA[(4*i+0)*8 + h] + v.y * WA[(4*i+1)*8 + h]
           + v.z * WA[(4*i+2)*8 + h] + v.w * WA[(4*i+3)*8 + h];
    }
    if (r < 8) asrc[n*8 + h] = s; else adst[n*8 + h] = s;
}

// ============ fused edge-softmax + aggregation, C=8 (layers 0,1) ============
__global__ void k_agg8f(const int* __restrict__ rows, const int* __restrict__ csrc,
                        const float* __restrict__ cea,
                        const float* __restrict__ asrc, const float* __restrict__ adst,
                        const float* __restrict__ wev,
                        const float* __restrict__ xs, float* __restrict__ agg) {
    int lane = threadIdx.x & 63;
    int d = (blockIdx.x * blockDim.x + threadIdx.x) >> 6;
    if (d >= NN) return;
    int h = lane >> 3;
    float adh = adst[d*8 + h];
    float wh  = wev[h];
    int rs = rows[d], re = rows[d+1];
    float acc = 0.f, den = 0.f;
    for (int p = rs; p < re; p++) {
        int s = csrc[p];
        float l = asrc[s*8 + h] + adh + cea[p] * wh;
        l = fmaxf(l, 0.2f * l);
        float e = __expf(l);
        den += e;
        acc += e * xs[s*64 + lane];
    }
    agg[d*64 + lane] = acc / fmaxf(den, 1e-16f);
}

// ============ layer-2 fused: edge-softmax + aggregate + MFMA projection ============
// Block = 4 waves = 16 nodes. Lane l aggregates head l>>3, features (l&7)*8..+7.
// z written bf16 into LDS in MFMA A-fragment order; each wave MFMAs one 16x16 col tile.
__global__ __launch_bounds__(256) void k_l2f(
        const int* __restrict__ rows, const int* __restrict__ csrc,
        const float* __restrict__ cea,
        const float* __restrict__ asrc, const float* __restrict__ adst,
        const float* __restrict__ wev,
        const float* __restrict__ x, const short* __restrict__ bsw,
        float* __restrict__ agg) {
    __shared__ short zl[16 * 520];     // 16 kb-planes x 65 slots x 8 shorts (padded)
    int t = threadIdx.x, lane = t & 63, wv = t >> 6;
    int blk = blockIdx.x;
    int h = lane >> 3;
    float wh = wev[h];
    const float4* x4 = (const float4*)x;
    int fo   = (lane & 7) * 2;
    int kb_w = lane >> 2;
    int qd0  = 2 * (lane & 1);
    int jhi  = 4 * ((lane >> 1) & 1);
    for (int q = 0; q < 4; q++) {
        int r = wv * 4 + q;
        int d = blk * 16 + r;
        float acc[8] = {0,0,0,0,0,0,0,0};
        float den = 0.f;
        if (d < NN) {
            float adh = adst[d*8 + h];
            int rs = rows[d], re = rows[d+1];
            for (int p = rs; p < re; p++) {
                int s = csrc[p];
                float l = asrc[s*8 + h] + adh + cea[p] * wh;
                l = fmaxf(l, 0.2f * l);
                float e = __expf(l);
                den += e;
                float4 v0 = x4[s*16 + fo];
                float4 v1 = x4[s*16 + fo + 1];
                acc[0] += e * v0.x; acc[1] += e * v0.y; acc[2] += e * v0.z; acc[3] += e * v0.w;
                acc[4] += e * v1.x; acc[5] += e * v1.y; acc[6] += e * v1.z; acc[7] += e * v1.w;
            }
        }
        float inv = 1.0f / fmaxf(den, 1e-16f);
        short4 lo, hi;
        lo.x = f2bf(acc[0]*inv); lo.y = f2bf(acc[1]*inv);
        lo.z = f2bf(acc[2]*inv); lo.w = f2bf(acc[3]*inv);
        hi.x = f2bf(acc[4]*inv); hi.y = f2bf(acc[5]*inv);
        hi.z = f2bf(acc[6]*inv); hi.w = f2bf(acc[7]*inv);
        *(short4*)&zl[kb_w*520 + (r + 16*qd0)*8 + jhi]       = lo;
        *(short4*)&zl[kb_w*520 + (r + 16*(qd0+1))*8 + jhi]   = hi;
    }
    __syncthreads();
    const sh8* Bs = (const sh8*)bsw;
    f32x4 acc = {0,0,0,0};
    for (int kb = 0; kb < 16; kb++) {
        sh8 a = *(const sh8*)&zl[kb*520 + lane*8];
        sh8 bf = Bs[(kb*4 + wv)*64 + lane];
        acc = __builtin_amdgcn_mfma_f32_16x16x32_bf16(a, bf, acc, 0, 0, 0);
    }
    int row = blk*16 + (lane >> 4) * 4;
    int col = wv*16 + (lane & 15);
#pragma unroll
    for (int rr = 0; rr < 4; rr++) {
        int n = row + rr;
        if (n < NN) agg[(size_t)n*64 + col] = acc[rr] * 0.125f;
    }
}

// ============ BN stats partials (no atomics; bias cancels in training-mode BN) ============
__global__ void k_bnstats(const float* __restrict__ agg, float* __restrict__ part) {
    int t = threadIdx.x;
    int c = t & 63;
    int r0 = blockIdx.x * 4 + (t >> 6);
    float s = 0.f, q = 0.f;
    for (int n = r0; n < NN; n += gridDim.x * 4) {
        float y = agg[n*64 + c];
        s += y; q += y*y;
    }
    __shared__ float sd[512];
    sd[t] = s; sd[256 + t] = q;
    __syncthreads();
    if (t < 128) { sd[t] += sd[t+128]; sd[256+t] += sd[256+t+128]; }
    __syncthreads();
    if (t < 64) {
        part[blockIdx.x*128 + t]      = sd[t] + sd[t+64];
        part[blockIdx.x*128 + 64 + t] = sd[256+t] + sd[256+t+64];
    }
}

// ============ BN finalize: per-channel scale/shift ============
__global__ void k_bnfin(const float* __restrict__ part, const float* __restrict__ gam,
                        const float* __restrict__ bet, float* __restrict__ ab) {
    int c = threadIdx.x;
    if (c >= 64) return;
    float s = 0.f, q = 0.f;
    for (int b = 0; b < 128; b++) { s += part[b*128 + c]; q += part[b*128 + 64 + c]; }
    float m = s * (1.0f / NN);
    float v = q * (1.0f / NN) - m*m;
    float a = gam[c] * rsqrtf(v + 1e-5f);
    ab[c] = a;
    ab[64 + c] = bet[c] - m * a;
}

// ============ BN apply + ELU + residual (layer 1 only) ============
__global__ void k_bnapply(const float* __restrict__ agg, const float* __restrict__ ab,
                          float* __restrict__ x) {
    int idx = blockIdx.x * 256 + threadIdx.x;
    if (idx >= NN * 64) return;
    int c = idx & 63;
    float o = agg[idx] * ab[c] + ab[64 + c];
    o = (o > 0.f) ? o : (__expf(o) - 1.0f);
    x[idx] += o;
}

// ============ fused: BN2-apply + residual + dual pooling + MLP head ============
__global__ void k_poolmlp(const float* __restrict__ xb, const float* __restrict__ agg,
                          const float* __restrict__ ab, const int* __restrict__ goff,
                          const float* __restrict__ fc1w, const float* __restrict__ fc1b,
                          const float* __restrict__ fc2w, const float* __restrict__ fc2b,
                          const float* __restrict__ fgw, const float* __restrict__ fgb,
                          const float* __restrict__ fbw, const float* __restrict__ fbb,
                          float* __restrict__ out) {
    int g = blockIdx.x, t = threadIdx.x;      // 256 threads
    int c = t & 63, r = t >> 6;
    float a = ab[c], sh = ab[64 + c];
    int st = goff[g], en = goff[g+1];
    float s = 0.f, mx = -INFINITY;
    for (int n = st + r; n < en; n += 4) {
        float o = agg[n*64 + c] * a + sh;
        o = (o > 0.f) ? o : (__expf(o) - 1.0f);
        float v = xb[n*64 + c] + o;
        s += v; mx = fmaxf(mx, v);
    }
    __shared__ float sd[512];
    __shared__ float sg[128], s1[128], s2[64];
    sd[t] = s; sd[256 + t] = mx;
    __syncthreads();
    if (t < 128) { sd[t] += sd[t+128]; sd[256+t] = fmaxf(sd[256+t], sd[256+t+128]); }
    __syncthreads();
    if (t < 64) {
        float cnt = (float)(en - st);
        sg[t]      = (sd[t] + sd[t+64]) / fmaxf(cnt, 1.0f);
        sg[64 + t] = fmaxf(sd[256+t], sd[256+t+64]);
    }
    __syncthreads();
    if (t < 128) {
        float av = fc1b[t];
        for (int i = 0; i < 128; i++) av += sg[i] * fc1w[i*128 + t];
        s1[t] = (av > 0.f) ? av : (__expf(av) - 1.f);
    }
    __syncthreads();
    if (t < 64) {
        float bv = fc2b[t];
        for (int i = 0; i < 128; i++) bv += s1[i] * fc2w[i*64 + t];
        s2[t] = (bv > 0.f) ? bv : (__expf(bv) - 1.f);
    }
    __syncthreads();
    if (t == 0) {
        float ga = fgb[0], be = fbb[0];
        for (int i = 0; i < 64; i++) { ga += s2[i] * fgw[i]; be += s2[i] * fbw[i]; }
        out[g*2 + 0] = ga;
        out[g*2 + 1] = be;
    }
}

extern "C" void kernel_launch(void* const* d_in, const int* in_sizes, int n_in,
                              void* d_out, int out_size, void* d_ws, size_t ws_size,
                              hipStream_t stream) {
    (void)in_sizes; (void)n_in; (void)out_size; (void)ws_size;
    const float* x3    = (const float*)d_in[0];
    const int*   ei    = (const int*)d_in[1];
    const float* ea    = (const float*)d_in[2];
    const int*   batch = (const int*)d_in[3];
    const float* ing   = (const float*)d_in[4];
    const float* inb   = (const float*)d_in[5];
    const float* w0    = (const float*)d_in[6];
    const float* we0   = (const float*)d_in[7];
    const float* as0   = (const float*)d_in[8];
    const float* ad0   = (const float*)d_in[9];
    const float* ae0   = (const float*)d_in[10];
    const float* bng0  = (const float*)d_in[12];
    const float* bnb0  = (const float*)d_in[13];
    const float* w1    = (const float*)d_in[14];
    const float* we1   = (const float*)d_in[15];
    const float* as1   = (const float*)d_in[16];
    const float* ad1   = (const float*)d_in[17];
    const float* ae1   = (const float*)d_in[18];
    const float* bng1  = (const float*)d_in[20];
    const float* bnb1  = (const float*)d_in[21];
    const float* w2    = (const float*)d_in[22];
    const float* we2   = (const float*)d_in[23];
    const float* as2   = (const float*)d_in[24];
    const float* ad2   = (const float*)d_in[25];
    const float* ae2   = (const float*)d_in[26];
    const float* bng2  = (const float*)d_in[28];
    const float* bnb2  = (const float*)d_in[29];
    const float* fc1w  = (const float*)d_in[30];
    const float* fc1b  = (const float*)d_in[31];
    const float* fc2w  = (const float*)d_in[32];
    const float* fc2b  = (const float*)d_in[33];
    const float* fgw   = (const float*)d_in[34];
    const float* fgb   = (const float*)d_in[35];
    const float* fbw   = (const float*)d_in[36];
    const float* fbb   = (const float*)d_in[37];

    float* fws = (float*)d_ws;
    int*   iws = (int*)d_ws;
    int*   deg   = iws + O_DEG;
    int*   rows  = iws + O_ROWS;
    int*   cur   = iws + O_CUR;
    int*   goff  = iws + O_GOFF;
    float* ipart = fws + O_IPART;
    float* inbn  = fws + O_INBN;
    float* Ws    = fws + O_WS;
    float* Wd    = fws + O_WD;
    float* wev   = fws + O_WE;
    float* bpart = fws + O_BPART;
    float* ab    = fws + O_AB;
    short* bsw   = (short*)(fws + O_BSW);
    int*   csrc  = iws + O_CSRC;
    float* cea   = fws + O_CEA;
    float* xs    = fws + O_XS;
    float* asrc  = fws + O_ASRC;
    float* adst  = fws + O_ADST;
    float* agg   = fws + O_AGG;
    float* xb    = fws + O_X;

    hipMemsetAsync(d_ws, 0, (size_t)ZERO_END * sizeof(int), stream);

    // setup: hist + instats + goff + prew x3 + bswz, one launch
    k_pre<<<1711, 256, 0, stream>>>(ei, batch, x3,
                                    w0, we0, as0, ad0, ae0,
                                    w1, we1, as1, ad1, ae1,
                                    w2, we2, as2, ad2, ae2,
                                    deg, goff, ipart, Ws, Wd, wev, bsw);
    k_scan<<<1, 1024, 0, stream>>>(deg, ipart, rows, cur, inbn);
    k_fill<<<(EE + 255) / 256, 256, 0, stream>>>(ei, ea, cur, csrc, cea);

    const int nblk64 = (NN * 64 + 255) / 256;   // 6250

    // ---- layer 0 ----
    k_proj0<<<nblk64, 256, 0, stream>>>(x3, inbn, ing, inb, w0, Ws, Wd, xs, asrc, adst);
    k_agg8f<<<nblk64, 256, 0, stream>>>(rows, csrc, cea, asrc, adst, wev, xs, agg);
    k_bnstats<<<128, 256, 0, stream>>>(agg, bpart);
    k_bnfin<<<1, 64, 0, stream>>>(bpart, bng0, bnb0, ab);

    // ---- layer 1 (BN0-apply fused into projection) ----
    {
        int waves = (NN + 3) / 4;
        int blocks = (waves + 3) / 4;
        k_projbn<4><<<blocks, 256, 0, stream>>>(agg, ab, w1, Ws + 512, Wd + 512,
                                                xb, xs, asrc, adst);
    }
    k_agg8f<<<nblk64, 256, 0, stream>>>(rows, csrc, cea, asrc, adst, wev + 8, xs, agg);
    k_bnstats<<<128, 256, 0, stream>>>(agg, bpart);
    k_bnfin<<<1, 64, 0, stream>>>(bpart, bng1, bnb1, ab);
    k_bnapply<<<nblk64, 256, 0, stream>>>(agg, ab, xb);

    // ---- layer 2 (fused aggregation + MFMA projection) ----
    k_attn<<<(NN * 16 + 255) / 256, 256, 0, stream>>>(xb, Ws + 1024, Wd + 1024, asrc, adst);
    k_l2f<<<(NN + 15) / 16, 256, 0, stream>>>(rows, csrc, cea, asrc, adst, wev + 16,
                                              xb, bsw, agg);
    k_bnstats<<<128, 256, 0, stream>>>(agg, bpart);
    k_bnfin<<<1, 64, 0, stream>>>(bpart, bng2, bnb2, ab);

    // ---- BN2-apply + residual + pooling + MLP head, one launch ----
    k_poolmlp<<<GG, 256, 0, stream>>>(xb, agg, ab, goff, fc1w, fc1b, fc2w, fc2b,
                                      fgw, fgb, fbw, fbb, (float*)d_out);
}

// Round 9
// 466.384 us; speedup vs baseline: 1.7742x; 1.1866x over previous
//
#include <hip/hip_runtime.h>
#include <math.h>

#define NN 25000
#define EE 400000
#define GG 64

// ---- workspace layout (element offsets, 16B-aligned) ----
static const int O_DEG   = 0;        // 25000 ints (zeroed by memset)
static const int ZERO_END= 25000;
static const int O_ROWS  = 25008;    // 25001 ints
static const int O_CUR   = 50016;    // 25000 ints
static const int O_GOFF  = 75016;    // 65 ints
static const int O_IPART = 75088;    // 16*6 f
static const int O_INBN  = 75184;    // 6 f
static const int O_WS    = 75192;    // 3*512 f
static const int O_WD    = 76728;    // 3*512 f
static const int O_WE    = 78264;    // 3*8 f
static const int O_BPART = 78288;    // 128*128 f
static const int O_AB    = 94672;    // 128 f
static const int O_BSW   = 94800;    // 16384 f = 32768 bf16 (swizzled W2)
static const int O_CSRC  = 111184;   // 400000 int
static const int O_CEA   = 511184;   // 400000 f
static const int O_XS    = 911184;   // 1.6M f
static const int O_ASRC  = 2511184;  // 200000 f
static const int O_ADST  = 2711184;  // 200000 f
static const int O_AGG   = 2911184;  // 1.6M f
static const int O_X     = 4511184;  // 1.6M f
static const int O_BSWC  = 6111184;  // 2560 f = 5120 bf16 (layer-1 cat [W1|Ws1|Wd1])
static const int O_BSWA  = 6113744;  // 512 f = 1024 bf16 (layer-2 [Ws2|Wd2])

using f32x4 = __attribute__((ext_vector_type(4))) float;
using sh8   = __attribute__((ext_vector_type(8))) short;  // 8 bf16

__device__ inline short f2bf(float f) {
    unsigned u = __float_as_uint(f);
    unsigned r = (u + 0x7FFFu + ((u >> 16) & 1u)) >> 16;   // RNE to bf16
    return (short)r;
}

// ============ mega setup: hist | instats | goff | prew x3 | bswz | bswc | bswa ============
__global__ void k_pre(const int* __restrict__ ei, const int* __restrict__ batch,
                      const float* __restrict__ x3,
                      const float* w0, const float* we0, const float* as0, const float* ad0, const float* ae0,
                      const float* w1, const float* we1, const float* as1, const float* ad1, const float* ae1,
                      const float* w2, const float* we2, const float* as2, const float* ad2, const float* ae2,
                      int* __restrict__ deg, int* __restrict__ goff, float* __restrict__ ipart,
                      float* __restrict__ Ws, float* __restrict__ Wd, float* __restrict__ wev,
                      short* __restrict__ bsw, short* __restrict__ bswc, short* __restrict__ bswa) {
    __shared__ float sd[1536];
    int b = blockIdx.x, t = threadIdx.x;
    if (b < 1563) {                       // edge histogram
        int e = b * 256 + t;
        if (e < EE) atomicAdd(&deg[ei[EE + e]], 1);
    } else if (b < 1579) {                // input-BN partial stats
        int ib = b - 1563;
        float s[3] = {0,0,0}, q[3] = {0,0,0};
        for (int n = ib * 256 + t; n < NN; n += 16 * 256) {
#pragma unroll
            for (int i = 0; i < 3; i++) { float v = x3[n*3+i]; s[i] += v; q[i] += v*v; }
        }
#pragma unroll
        for (int i = 0; i < 3; i++) { sd[t*6+i] = s[i]; sd[t*6+3+i] = q[i]; }
        __syncthreads();
        for (int off = 128; off > 0; off >>= 1) {
            if (t < off) {
#pragma unroll
                for (int i = 0; i < 6; i++) sd[t*6+i] += sd[(t+off)*6+i];
            }
            __syncthreads();
        }
        if (t < 6) ipart[ib*6 + t] = sd[t];
    } else if (b == 1579) {               // graph offsets (batch sorted)
        if (t <= GG) {
            int g = t, lo = 0, hi = NN;
            while (lo < hi) { int mid = (lo + hi) >> 1; if (batch[mid] < g) lo = mid + 1; else hi = mid; }
            goff[g] = lo;
        }
    } else if (b < 1583) {                // per-layer attention weight fold (Ws/Wd/wev)
        int L = b - 1580;
        const float *W, *Wep, *as_, *ad_, *ae_; int INF, CC;
        if (L == 0)      { W = w0; Wep = we0; as_ = as0; ad_ = ad0; ae_ = ae0; INF = 3;  CC = 8;  }
        else if (L == 1) { W = w1; Wep = we1; as_ = as1; ad_ = ad1; ae_ = ae1; INF = 64; CC = 8;  }
        else             { W = w2; Wep = we2; as_ = as2; ad_ = ad2; ae_ = ae2; INF = 64; CC = 64; }
        int HC = 8 * CC;
        for (int tt = t; tt < INF * 8; tt += 256) {
            int i = tt >> 3, h = tt & 7;
            float s = 0.f, d = 0.f;
            for (int c = 0; c < CC; c++) {
                float w = W[i*HC + h*CC + c];
                s += w * as_[h*CC + c];
                d += w * ad_[h*CC + c];
            }
            Ws[L*512 + i*8 + h] = s; Wd[L*512 + i*8 + h] = d;
        }
        if (t < 8) {
            float s = 0.f;
            for (int c = 0; c < CC; c++) s += Wep[t*CC + c] * ae_[t*CC + c];
            wev[L*8 + t] = s;
        }
    } else if (b < 1711) {                // W2 swizzle (MFMA B-frag order)
        int idx = (b - 1583) * 256 + t;   // < 32768
        int j  = idx & 7;
        int l  = (idx >> 3) & 63;
        int nt = (idx >> 9) & 3;
        int kb = idx >> 11;
        int k = kb*32 + (l >> 4)*4 + (j & 3) + 16*(j >> 2);
        int c = nt*16 + (l & 15);
        int h = k >> 6, i = k & 63;
        bsw[idx] = f2bf(w2[i*512 + h*64 + c]);
    } else if (b < 1731) {                // layer-1 cat [W1 | Ws1 | Wd1] swizzle (5 tiles, K=64)
        int idx = (b - 1711) * 256 + t;   // < 5120
        int j  = idx & 7;
        int l  = (idx >> 3) & 63;
        int r2 = idx >> 9;                // 0..9
        int nt = r2 % 5, kb = r2 / 5;
        int k = kb*32 + (l >> 4)*4 + (j & 3) + 16*(j >> 2);
        int c = nt*16 + (l & 15);
        float val;
        if (c < 64) val = w1[k*64 + c];
        else {
            int h = (c - 64) & 7;
            const float* aa = (c < 72) ? as1 : ad1;
            float s = 0.f;
            for (int cc = 0; cc < 8; cc++) s += w1[k*64 + h*8 + cc] * aa[h*8 + cc];
            val = s;
        }
        bswc[idx] = f2bf(val);
    } else {                              // layer-2 [Ws2 | Wd2] swizzle (1 tile, K=64)
        int idx = (b - 1731) * 256 + t;   // < 1024
        int j  = idx & 7;
        int l  = (idx >> 3) & 63;
        int kb = idx >> 9;                // 0..1
        int k = kb*32 + (l >> 4)*4 + (j & 3) + 16*(j >> 2);
        int c = l & 15;
        int h = c & 7;
        const float* aa = (c < 8) ? as2 : ad2;
        float s = 0.f;
        for (int cc = 0; cc < 64; cc++) s += w2[k*512 + h*64 + cc] * aa[h*64 + cc];
        bswa[idx] = f2bf(s);
    }
}

// ============ degree scan -> CSR rows (+ finalize input-BN stats) ============
__global__ void k_scan(const int* __restrict__ deg, const float* __restrict__ ipart,
                       int* __restrict__ rows, int* __restrict__ cur, float* __restrict__ inbn) {
    const int C = 25;
    int t = threadIdx.x;
    if (t < 6) { float s = 0.f; for (int b = 0; b < 16; b++) s += ipart[b*6 + t]; inbn[t] = s; }
    int base = t * C;
    int mysum = 0;
    for (int k = 0; k < C; k++) { int i = base + k; if (i < NN) mysum += deg[i]; }
    __shared__ int sd[1024];
    sd[t] = mysum; __syncthreads();
    for (int off = 1; off < 1024; off <<= 1) {
        int v = (t >= off) ? sd[t - off] : 0;
        __syncthreads();
        sd[t] += v;
        __syncthreads();
    }
    int run = sd[t] - mysum;
    for (int k = 0; k < C; k++) {
        int i = base + k;
        if (i < NN) { int v = deg[i]; rows[i] = run; cur[i] = run; run += v; }
    }
    if (t == 0) rows[NN] = EE;
}

__global__ void k_fill(const int* __restrict__ ei, const float* __restrict__ ea,
                       int* __restrict__ cur, int* __restrict__ csrc,
                       float* __restrict__ cea) {
    int e = blockIdx.x * 256 + threadIdx.x;
    if (e >= EE) return;
    int s = ei[e], d = ei[EE + e];
    int pos = atomicAdd(&cur[d], 1);
    csrc[pos] = s; cea[pos] = ea[e];
}

// ============ layer-0 projection (input BN fused, in=3) ============
__global__ void k_proj0(const float* __restrict__ x, const float* __restrict__ sums,
                        const float* __restrict__ g, const float* __restrict__ b,
                        const float* __restrict__ W0,
                        const float* __restrict__ Ws, const float* __restrict__ Wd,
                        float* __restrict__ xs, float* __restrict__ asrc, float* __restrict__ adst) {
    int idx = blockIdx.x * 256 + threadIdx.x;
    if (idx >= NN * 64) return;
    int n = idx >> 6, j = idx & 63;
    float xn[3];
#pragma unroll
    for (int i = 0; i < 3; i++) {
        float m = sums[i] * (1.0f / NN);
        float v = sums[3+i] * (1.0f / NN) - m*m;
        xn[i] = (x[n*3+i] - m) * rsqrtf(v + 1e-5f) * g[i] + b[i];
    }
    float a = 0.f;
#pragma unroll
    for (int i = 0; i < 3; i++) a += xn[i] * W0[i*64 + j];
    xs[n*64 + j] = a;
    if (j < 16) {
        const float* WA = (j < 8) ? Ws : Wd;
        int h = j & 7;
        float s = 0.f;
#pragma unroll
        for (int i = 0; i < 3; i++) s += xn[i] * WA[i*8 + h];
        if (j < 8) asrc[n*8 + h] = s; else adst[n*8 + h] = s;
    }
}

// ============ fused edge-softmax + aggregation, C=8 (layers 0,1), chunked+4x ============
__global__ void k_agg8f(const int* __restrict__ rows, const int* __restrict__ csrc,
                        const float* __restrict__ cea,
                        const float* __restrict__ asrc, const float* __restrict__ adst,
                        const float* __restrict__ wev,
                        const float* __restrict__ xs, float* __restrict__ agg) {
    int lane = threadIdx.x & 63;
    int d = (blockIdx.x * blockDim.x + threadIdx.x) >> 6;
    if (d >= NN) return;
    int h = lane >> 3;
    float adh = adst[d*8 + h];
    float wh  = wev[h];
    int rs = rows[d], re = rows[d+1];
    float acc = 0.f, den = 0.f;
    for (int c0 = rs; c0 < re; c0 += 64) {
        int cnt = re - c0; if (cnt > 64) cnt = 64;
        int ii = c0 + (lane < cnt ? lane : 0);
        int es = csrc[ii];
        float ef = cea[ii];
        int j = 0;
        for (; j + 3 < cnt; j += 4) {
            int s0 = __shfl(es, j),   s1 = __shfl(es, j+1);
            int s2 = __shfl(es, j+2), s3 = __shfl(es, j+3);
            float a0 = __shfl(ef, j),   a1 = __shfl(ef, j+1);
            float a2 = __shfl(ef, j+2), a3 = __shfl(ef, j+3);
            float l0 = asrc[s0*8+h], l1 = asrc[s1*8+h];
            float l2 = asrc[s2*8+h], l3 = asrc[s3*8+h];
            float x0 = xs[s0*64+lane], x1 = xs[s1*64+lane];
            float x2 = xs[s2*64+lane], x3 = xs[s3*64+lane];
            l0 += adh + a0*wh; l1 += adh + a1*wh;
            l2 += adh + a2*wh; l3 += adh + a3*wh;
            l0 = fmaxf(l0, 0.2f*l0); l1 = fmaxf(l1, 0.2f*l1);
            l2 = fmaxf(l2, 0.2f*l2); l3 = fmaxf(l3, 0.2f*l3);
            float e0 = __expf(l0), e1 = __expf(l1), e2 = __expf(l2), e3 = __expf(l3);
            den += (e0 + e1) + (e2 + e3);
            acc += e0*x0; acc += e1*x1; acc += e2*x2; acc += e3*x3;
        }
        for (; j < cnt; j++) {
            int s = __shfl(es, j);
            float a = __shfl(ef, j);
            float l = asrc[s*8+h] + adh + a*wh;
            l = fmaxf(l, 0.2f*l);
            float e = __expf(l);
            den += e;
            acc += e * xs[s*64+lane];
        }
    }
    agg[d*64 + lane] = acc / fmaxf(den, 1e-16f);
}

// ============ layer-1 projection via MFMA: [xb | asrc | adst] = elu(bn(agg)) @ [W1|Ws1|Wd1] ============
__global__ void k_proj1m(const float* __restrict__ agg, const float* __restrict__ ab,
                         const short* __restrict__ bswc,
                         float* __restrict__ xb, float* __restrict__ xs,
                         float* __restrict__ asrc, float* __restrict__ adst) {
    int l = threadIdx.x & 63;
    int wid = (blockIdx.x * blockDim.x + threadIdx.x) >> 6;
    int n0 = wid * 16;
    if (n0 >= NN) return;
    int ra = n0 + (l & 15); if (ra > NN-1) ra = NN-1;
    int kq = (l >> 4) * 4;
    const sh8* Bs = (const sh8*)bswc;
    sh8 af0, af1;
#pragma unroll
    for (int kb = 0; kb < 2; kb++) {
        int c0 = kb*32 + kq;
        float4 a0 = *(const float4*)&agg[ra*64 + c0];
        float4 a1 = *(const float4*)&agg[ra*64 + c0 + 16];
        float4 sc0 = *(const float4*)&ab[c0];
        float4 sh0 = *(const float4*)&ab[64 + c0];
        float4 sc1 = *(const float4*)&ab[c0 + 16];
        float4 sh1 = *(const float4*)&ab[64 + c0 + 16];
        float o[8];
        o[0] = a0.x*sc0.x + sh0.x; o[1] = a0.y*sc0.y + sh0.y;
        o[2] = a0.z*sc0.z + sh0.z; o[3] = a0.w*sc0.w + sh0.w;
        o[4] = a1.x*sc1.x + sh1.x; o[5] = a1.y*sc1.y + sh1.y;
        o[6] = a1.z*sc1.z + sh1.z; o[7] = a1.w*sc1.w + sh1.w;
#pragma unroll
        for (int u = 0; u < 8; u++) o[u] = (o[u] > 0.f) ? o[u] : (__expf(o[u]) - 1.f);
        float4 w0v = {o[0],o[1],o[2],o[3]}, w1v = {o[4],o[5],o[6],o[7]};
        *(float4*)&xb[ra*64 + c0]      = w0v;
        *(float4*)&xb[ra*64 + c0 + 16] = w1v;
        sh8 af;
#pragma unroll
        for (int u = 0; u < 8; u++) af[u] = f2bf(o[u]);
        if (kb == 0) af0 = af; else af1 = af;
    }
    f32x4 acc[5];
#pragma unroll
    for (int nt = 0; nt < 5; nt++) acc[nt] = (f32x4){0,0,0,0};
#pragma unroll
    for (int nt = 0; nt < 5; nt++) {
        acc[nt] = __builtin_amdgcn_mfma_f32_16x16x32_bf16(af0, Bs[nt*64 + l], acc[nt], 0, 0, 0);
        acc[nt] = __builtin_amdgcn_mfma_f32_16x16x32_bf16(af1, Bs[(5+nt)*64 + l], acc[nt], 0, 0, 0);
    }
    int rbase = n0 + (l >> 4) * 4, cb = l & 15;
#pragma unroll
    for (int r = 0; r < 4; r++) {
        int n = rbase + r;
        if (n >= NN) break;
#pragma unroll
        for (int nt = 0; nt < 4; nt++) xs[n*64 + nt*16 + cb] = acc[nt][r];
        if (cb < 8) asrc[n*8 + cb] = acc[4][r];
        else        adst[n*8 + (cb-8)] = acc[4][r];
    }
}

// ============ fused BN1-apply + residual + layer-2 attention logits (MFMA) ============
__global__ void k_bnattn(const float* __restrict__ agg, const float* __restrict__ ab,
                         const short* __restrict__ bswa,
                         float* __restrict__ xb,
                         float* __restrict__ asrc, float* __restrict__ adst) {
    int l = threadIdx.x & 63;
    int wid = (blockIdx.x * blockDim.x + threadIdx.x) >> 6;
    int n0 = wid * 16;
    if (n0 >= NN) return;
    int ra = n0 + (l & 15); if (ra > NN-1) ra = NN-1;
    int kq = (l >> 4) * 4;
    const sh8* Bs = (const sh8*)bswa;
    sh8 af0, af1;
#pragma unroll
    for (int kb = 0; kb < 2; kb++) {
        int c0 = kb*32 + kq;
        float4 a0 = *(const float4*)&agg[ra*64 + c0];
        float4 a1 = *(const float4*)&agg[ra*64 + c0 + 16];
        float4 x0 = *(const float4*)&xb[ra*64 + c0];
        float4 x1 = *(const float4*)&xb[ra*64 + c0 + 16];
        float4 sc0 = *(const float4*)&ab[c0];
        float4 sh0 = *(const float4*)&ab[64 + c0];
        float4 sc1 = *(const float4*)&ab[c0 + 16];
        float4 sh1 = *(const float4*)&ab[64 + c0 + 16];
        float o[8];
        o[0] = a0.x*sc0.x + sh0.x; o[1] = a0.y*sc0.y + sh0.y;
        o[2] = a0.z*sc0.z + sh0.z; o[3] = a0.w*sc0.w + sh0.w;
        o[4] = a1.x*sc1.x + sh1.x; o[5] = a1.y*sc1.y + sh1.y;
        o[6] = a1.z*sc1.z + sh1.z; o[7] = a1.w*sc1.w + sh1.w;
#pragma unroll
        for (int u = 0; u < 8; u++) o[u] = (o[u] > 0.f) ? o[u] : (__expf(o[u]) - 1.f);
        o[0] += x0.x; o[1] += x0.y; o[2] += x0.z; o[3] += x0.w;
        o[4] += x1.x; o[5] += x1.y; o[6] += x1.z; o[7] += x1.w;
        float4 w0v = {o[0],o[1],o[2],o[3]}, w1v = {o[4],o[5],o[6],o[7]};
        *(float4*)&xb[ra*64 + c0]      = w0v;
        *(float4*)&xb[ra*64 + c0 + 16] = w1v;
        sh8 af;
#pragma unroll
        for (int u = 0; u < 8; u++) af[u] = f2bf(o[u]);
        if (kb == 0) af0 = af; else af1 = af;
    }
    f32x4 acc = {0,0,0,0};
    acc = __builtin_amdgcn_mfma_f32_16x16x32_bf16(af0, Bs[l],      acc, 0, 0, 0);
    acc = __builtin_amdgcn_mfma_f32_16x16x32_bf16(af1, Bs[64 + l], acc, 0, 0, 0);
    int rbase = n0 + (l >> 4) * 4, cb = l & 15;
#pragma unroll
    for (int r = 0; r < 4; r++) {
        int n = rbase + r;
        if (n >= NN) break;
        if (cb < 8) asrc[n*8 + cb] = acc[r];
        else        adst[n*8 + (cb-8)] = acc[r];
    }
}

// ============ layer-2 fused: edge-softmax + aggregate + MFMA projection (chunked+2x) ============
__global__ __launch_bounds__(256) void k_l2f(
        const int* __restrict__ rows, const int* __restrict__ csrc,
        const float* __restrict__ cea,
        const float* __restrict__ asrc, const float* __restrict__ adst,
        const float* __restrict__ wev,
        const float* __restrict__ x, const short* __restrict__ bsw,
        float* __restrict__ agg) {
    __shared__ short zl[16 * 520];
    int t = threadIdx.x, lane = t & 63, wv = t >> 6;
    int blk = blockIdx.x;
    int h = lane >> 3;
    float wh = wev[h];
    const float4* x4 = (const float4*)x;
    int fo   = (lane & 7) * 2;
    int kb_w = lane >> 2;
    int qd0  = 2 * (lane & 1);
    int jhi  = 4 * ((lane >> 1) & 1);
    for (int q = 0; q < 4; q++) {
        int r = wv * 4 + q;
        int d = blk * 16 + r;
        float acc[8] = {0,0,0,0,0,0,0,0};
        float den = 0.f;
        if (d < NN) {
            float adh = adst[d*8 + h];
            int rs = rows[d], re = rows[d+1];
            for (int c0 = rs; c0 < re; c0 += 64) {
                int cnt = re - c0; if (cnt > 64) cnt = 64;
                int ii = c0 + (lane < cnt ? lane : 0);
                int es = csrc[ii];
                float ef = cea[ii];
                int j = 0;
                for (; j + 1 < cnt; j += 2) {
                    int s0 = __shfl(es, j), s1 = __shfl(es, j+1);
                    float a0 = __shfl(ef, j), a1 = __shfl(ef, j+1);
                    float l0 = asrc[s0*8+h], l1 = asrc[s1*8+h];
                    float4 u0 = x4[s0*16 + fo], u1 = x4[s0*16 + fo + 1];
                    float4 v0 = x4[s1*16 + fo], v1 = x4[s1*16 + fo + 1];
                    l0 += adh + a0*wh; l1 += adh + a1*wh;
                    l0 = fmaxf(l0, 0.2f*l0); l1 = fmaxf(l1, 0.2f*l1);
                    float e0 = __expf(l0), e1 = __expf(l1);
                    den += e0 + e1;
                    acc[0] += e0*u0.x + e1*v0.x;
                    acc[1] += e0*u0.y + e1*v0.y;
                    acc[2] += e0*u0.z + e1*v0.z;
                    acc[3] += e0*u0.w + e1*v0.w;
                    acc[4] += e0*u1.x + e1*v1.x;
                    acc[5] += e0*u1.y + e1*v1.y;
                    acc[6] += e0*u1.z + e1*v1.z;
                    acc[7] += e0*u1.w + e1*v1.w;
                }
                if (j < cnt) {
                    int s = __shfl(es, j);
                    float a = __shfl(ef, j);
                    float l = asrc[s*8+h] + adh + a*wh;
                    l = fmaxf(l, 0.2f*l);
                    float e = __expf(l);
                    den += e;
                    float4 u0 = x4[s*16 + fo], u1 = x4[s*16 + fo + 1];
                    acc[0] += e*u0.x; acc[1] += e*u0.y; acc[2] += e*u0.z; acc[3] += e*u0.w;
                    acc[4] += e*u1.x; acc[5] += e*u1.y; acc[6] += e*u1.z; acc[7] += e*u1.w;
                }
            }
        }
        float inv = 1.0f / fmaxf(den, 1e-16f);
        short4 lo, hi;
        lo.x = f2bf(acc[0]*inv); lo.y = f2bf(acc[1]*inv);
        lo.z = f2bf(acc[2]*inv); lo.w = f2bf(acc[3]*inv);
        hi.x = f2bf(acc[4]*inv); hi.y = f2bf(acc[5]*inv);
        hi.z = f2bf(acc[6]*inv); hi.w = f2bf(acc[7]*inv);
        *(short4*)&zl[kb_w*520 + (r + 16*qd0)*8 + jhi]     = lo;
        *(short4*)&zl[kb_w*520 + (r + 16*(qd0+1))*8 + jhi] = hi;
    }
    __syncthreads();
    const sh8* Bs = (const sh8*)bsw;
    f32x4 acc = {0,0,0,0};
    for (int kb = 0; kb < 16; kb++) {
        sh8 a = *(const sh8*)&zl[kb*520 + lane*8];
        sh8 bf = Bs[(kb*4 + wv)*64 + lane];
        acc = __builtin_amdgcn_mfma_f32_16x16x32_bf16(a, bf, acc, 0, 0, 0);
    }
    int row = blk*16 + (lane >> 4) * 4;
    int col = wv*16 + (lane & 15);
#pragma unroll
    for (int rr = 0; rr < 4; rr++) {
        int n = row + rr;
        if (n < NN) agg[(size_t)n*64 + col] = acc[rr] * 0.125f;
    }
}

// ============ BN stats partials (bias cancels in training-mode BN) ============
__global__ void k_bnstats(const float* __restrict__ agg, float* __restrict__ part) {
    int t = threadIdx.x;
    int c = t & 63;
    int r0 = blockIdx.x * 4 + (t >> 6);
    float s = 0.f, q = 0.f;
    for (int n = r0; n < NN; n += gridDim.x * 4) {
        float y = agg[n*64 + c];
        s += y; q += y*y;
    }
    __shared__ float sd[512];
    sd[t] = s; sd[256 + t] = q;
    __syncthreads();
    if (t < 128) { sd[t] += sd[t+128]; sd[256+t] += sd[256+t+128]; }
    __syncthreads();
    if (t < 64) {
        part[blockIdx.x*128 + t]      = sd[t] + sd[t+64];
        part[blockIdx.x*128 + 64 + t] = sd[256+t] + sd[256+t+64];
    }
}

// ============ BN finalize ============
__global__ void k_bnfin(const float* __restrict__ part, const float* __restrict__ gam,
                        const float* __restrict__ bet, float* __restrict__ ab) {
    int c = threadIdx.x;
    if (c >= 64) return;
    float s = 0.f, q = 0.f;
    for (int b = 0; b < 128; b++) { s += part[b*128 + c]; q += part[b*128 + 64 + c]; }
    float m = s * (1.0f / NN);
    float v = q * (1.0f / NN) - m*m;
    float a = gam[c] * rsqrtf(v + 1e-5f);
    ab[c] = a;
    ab[64 + c] = bet[c] - m * a;
}

// ============ fused: BN2-apply + residual + dual pooling + MLP head ============
__global__ void k_poolmlp(const float* __restrict__ xb, const float* __restrict__ agg,
                          const float* __restrict__ ab, const int* __restrict__ goff,
                          const float* __restrict__ fc1w, const float* __restrict__ fc1b,
                          const float* __restrict__ fc2w, const float* __restrict__ fc2b,
                          const float* __restrict__ fgw, const float* __restrict__ fgb,
                          const float* __restrict__ fbw, const float* __restrict__ fbb,
                          float* __restrict__ out) {
    int g = blockIdx.x, t = threadIdx.x;
    int c = t & 63, r = t >> 6;
    float a = ab[c], sh = ab[64 + c];
    int st = goff[g], en = goff[g+1];
    float s = 0.f, mx = -INFINITY;
    for (int n = st + r; n < en; n += 4) {
        float o = agg[n*64 + c] * a + sh;
        o = (o > 0.f) ? o : (__expf(o) - 1.0f);
        float v = xb[n*64 + c] + o;
        s += v; mx = fmaxf(mx, v);
    }
    __shared__ float sd[512];
    __shared__ float sg[128], s1[128], s2[64];
    sd[t] = s; sd[256 + t] = mx;
    __syncthreads();
    if (t < 128) { sd[t] += sd[t+128]; sd[256+t] = fmaxf(sd[256+t], sd[256+t+128]); }
    __syncthreads();
    if (t < 64) {
        float cnt = (float)(en - st);
        sg[t]      = (sd[t] + sd[t+64]) / fmaxf(cnt, 1.0f);
        sg[64 + t] = fmaxf(sd[256+t], sd[256+t+64]);
    }
    __syncthreads();
    if (t < 128) {
        float av = fc1b[t];
        for (int i = 0; i < 128; i++) av += sg[i] * fc1w[i*128 + t];
        s1[t] = (av > 0.f) ? av : (__expf(av) - 1.f);
    }
    __syncthreads();
    if (t < 64) {
        float bv = fc2b[t];
        for (int i = 0; i < 128; i++) bv += s1[i] * fc2w[i*64 + t];
        s2[t] = (bv > 0.f) ? bv : (__expf(bv) - 1.f);
    }
    __syncthreads();
    if (t == 0) {
        float ga = fgb[0], be = fbb[0];
        for (int i = 0; i < 64; i++) { ga += s2[i] * fgw[i]; be += s2[i] * fbw[i]; }
        out[g*2 + 0] = ga;
        out[g*2 + 1] = be;
    }
}

extern "C" void kernel_launch(void* const* d_in, const int* in_sizes, int n_in,
                              void* d_out, int out_size, void* d_ws, size_t ws_size,
                              hipStream_t stream) {
    (void)in_sizes; (void)n_in; (void)out_size; (void)ws_size;
    const float* x3    = (const float*)d_in[0];
    const int*   ei    = (const int*)d_in[1];
    const float* ea    = (const float*)d_in[2];
    const int*   batch = (const int*)d_in[3];
    const float* ing   = (const float*)d_in[4];
    const float* inb   = (const float*)d_in[5];
    const float* w0    = (const float*)d_in[6];
    const float* we0   = (const float*)d_in[7];
    const float* as0   = (const float*)d_in[8];
    const float* ad0   = (const float*)d_in[9];
    const float* ae0   = (const float*)d_in[10];
    const float* bng0  = (const float*)d_in[12];
    const float* bnb0  = (const float*)d_in[13];
    const float* w1    = (const float*)d_in[14];
    const float* we1   = (const float*)d_in[15];
    const float* as1   = (const float*)d_in[16];
    const float* ad1   = (const float*)d_in[17];
    const float* ae1   = (const float*)d_in[18];
    const float* bng1  = (const float*)d_in[20];
    const float* bnb1  = (const float*)d_in[21];
    const float* w2    = (const float*)d_in[22];
    const float* we2   = (const float*)d_in[23];
    const float* as2   = (const float*)d_in[24];
    const float* ad2   = (const float*)d_in[25];
    const float* ae2   = (const float*)d_in[26];
    const float* bng2  = (const float*)d_in[28];
    const float* bnb2  = (const float*)d_in[29];
    const float* fc1w  = (const float*)d_in[30];
    const float* fc1b  = (const float*)d_in[31];
    const float* fc2w  = (const float*)d_in[32];
    const float* fc2b  = (const float*)d_in[33];
    const float* fgw   = (const float*)d_in[34];
    const float* fgb   = (const float*)d_in[35];
    const float* fbw   = (const float*)d_in[36];
    const float* fbb   = (const float*)d_in[37];

    float* fws = (float*)d_ws;
    int*   iws = (int*)d_ws;
    int*   deg   = iws + O_DEG;
    int*   rows  = iws + O_ROWS;
    int*   cur   = iws + O_CUR;
    int*   goff  = iws + O_GOFF;
    float* ipart = fws + O_IPART;
    float* inbn  = fws + O_INBN;
    float* Ws    = fws + O_WS;
    float* Wd    = fws + O_WD;
    float* wev   = fws + O_WE;
    float* bpart = fws + O_BPART;
    float* ab    = fws + O_AB;
    short* bsw   = (short*)(fws + O_BSW);
    int*   csrc  = iws + O_CSRC;
    float* cea   = fws + O_CEA;
    float* xs    = fws + O_XS;
    float* asrc  = fws + O_ASRC;
    float* adst  = fws + O_ADST;
    float* agg   = fws + O_AGG;
    float* xb    = fws + O_X;
    short* bswc  = (short*)(fws + O_BSWC);
    short* bswa  = (short*)(fws + O_BSWA);

    hipMemsetAsync(d_ws, 0, (size_t)ZERO_END * sizeof(int), stream);

    k_pre<<<1735, 256, 0, stream>>>(ei, batch, x3,
                                    w0, we0, as0, ad0, ae0,
                                    w1, we1, as1, ad1, ae1,
                                    w2, we2, as2, ad2, ae2,
                                    deg, goff, ipart, Ws, Wd, wev, bsw, bswc, bswa);
    k_scan<<<1, 1024, 0, stream>>>(deg, ipart, rows, cur, inbn);
    k_fill<<<(EE + 255) / 256, 256, 0, stream>>>(ei, ea, cur, csrc, cea);

    const int nblk64 = (NN * 64 + 255) / 256;   // 6250
    const int wblk16 = ((NN + 15) / 16 + 3) / 4; // 391 blocks of 4 waves (16 nodes/wave)

    // ---- layer 0 ----
    k_proj0<<<nblk64, 256, 0, stream>>>(x3, inbn, ing, inb, w0, Ws, Wd, xs, asrc, adst);
    k_agg8f<<<nblk64, 256, 0, stream>>>(rows, csrc, cea, asrc, adst, wev, xs, agg);
    k_bnstats<<<128, 256, 0, stream>>>(agg, bpart);
    k_bnfin<<<1, 64, 0, stream>>>(bpart, bng0, bnb0, ab);

    // ---- layer 1 (BN0-apply + xb + projection + logits via MFMA) ----
    k_proj1m<<<wblk16, 256, 0, stream>>>(agg, ab, bswc, xb, xs, asrc, adst);
    k_agg8f<<<nblk64, 256, 0, stream>>>(rows, csrc, cea, asrc, adst, wev + 8, xs, agg);
    k_bnstats<<<128, 256, 0, stream>>>(agg, bpart);
    k_bnfin<<<1, 64, 0, stream>>>(bpart, bng1, bnb1, ab);

    // ---- layer 2 (BN1-apply + residual + logits fused; then fused agg+MFMA) ----
    k_bnattn<<<wblk16, 256, 0, stream>>>(agg, ab, bswa, xb, asrc, adst);
    k_l2f<<<(NN + 15) / 16, 256, 0, stream>>>(rows, csrc, cea, asrc, adst, wev + 16,
                                              xb, bsw, agg);
    k_bnstats<<<128, 256, 0, stream>>>(agg, bpart);
    k_bnfin<<<1, 64, 0, stream>>>(bpart, bng2, bnb2, ab);

    // ---- BN2-apply + residual + pooling + MLP head ----
    k_poolmlp<<<GG, 256, 0, stream>>>(xb, agg, ab, goff, fc1w, fc1b, fc2w, fc2b,
                                      fgw, fgb, fbw, fbb, (float*)d_out);
}

// Round 10
// 419.759 us; speedup vs baseline: 1.9713x; 1.1111x over previous
//
#include <hip/hip_runtime.h>
#include <math.h>

#define NN 25000
#define EE 400000
#define GG 64

// ---- workspace layout (element offsets, 16B-aligned) ----
static const int O_DEG   = 0;        // 25000 ints (zeroed by memset)
static const int ZERO_END= 25000;
static const int O_ROWS  = 25008;    // 25001 ints
static const int O_CUR   = 50016;    // 25000 ints
static const int O_GOFF  = 75016;    // 65 ints
static const int O_IPART = 75088;    // 16*6 f
static const int O_INBN  = 75184;    // 6 f
static const int O_WS    = 75192;    // 3*512 f
static const int O_WD    = 76728;    // 3*512 f
static const int O_WE    = 78264;    // 3*8 f
static const int O_BPART = 78288;    // 128*128 f
static const int O_AB    = 94672;    // 128 f
static const int O_BSW   = 94800;    // 16384 f = 32768 bf16 (swizzled W2)
static const int O_CSRC  = 111184;   // 400000 int
static const int O_CEA   = 511184;   // 400000 f
static const int O_XS    = 911184;   // 1.6M f
static const int O_ASRC  = 2511184;  // 200000 f
static const int O_ADST  = 2711184;  // 200000 f
static const int O_AGG   = 2911184;  // 1.6M f
static const int O_X     = 4511184;  // 1.6M f
static const int O_BSWC  = 6111184;  // 2560 f = 5120 bf16 (layer-1 cat [W1|Ws1|Wd1])
static const int O_BSWA  = 6113744;  // 512 f = 1024 bf16 (layer-2 [Ws2|Wd2])
static const int O_BSUM  = 6114256;  // 98 ints (scan block sums)
static const int O_BOFF  = 6114360;  // 98 ints (scan block offsets)

using f32x4 = __attribute__((ext_vector_type(4))) float;
using sh8   = __attribute__((ext_vector_type(8))) short;  // 8 bf16

__device__ inline short f2bf(float f) {
    unsigned u = __float_as_uint(f);
    unsigned r = (u + 0x7FFFu + ((u >> 16) & 1u)) >> 16;   // RNE to bf16
    return (short)r;
}

// ============ mega setup: hist | instats | goff | prew x3 | bswz | bswc | bswa ============
__global__ void k_pre(const int* __restrict__ ei, const int* __restrict__ batch,
                      const float* __restrict__ x3,
                      const float* w0, const float* we0, const float* as0, const float* ad0, const float* ae0,
                      const float* w1, const float* we1, const float* as1, const float* ad1, const float* ae1,
                      const float* w2, const float* we2, const float* as2, const float* ad2, const float* ae2,
                      int* __restrict__ deg, int* __restrict__ goff, float* __restrict__ ipart,
                      float* __restrict__ Ws, float* __restrict__ Wd, float* __restrict__ wev,
                      short* __restrict__ bsw, short* __restrict__ bswc, short* __restrict__ bswa) {
    __shared__ float sd[1536];
    int b = blockIdx.x, t = threadIdx.x;
    if (b < 1563) {                       // edge histogram
        int e = b * 256 + t;
        if (e < EE) atomicAdd(&deg[ei[EE + e]], 1);
    } else if (b < 1579) {                // input-BN partial stats
        int ib = b - 1563;
        float s[3] = {0,0,0}, q[3] = {0,0,0};
        for (int n = ib * 256 + t; n < NN; n += 16 * 256) {
#pragma unroll
            for (int i = 0; i < 3; i++) { float v = x3[n*3+i]; s[i] += v; q[i] += v*v; }
        }
#pragma unroll
        for (int i = 0; i < 3; i++) { sd[t*6+i] = s[i]; sd[t*6+3+i] = q[i]; }
        __syncthreads();
        for (int off = 128; off > 0; off >>= 1) {
            if (t < off) {
#pragma unroll
                for (int i = 0; i < 6; i++) sd[t*6+i] += sd[(t+off)*6+i];
            }
            __syncthreads();
        }
        if (t < 6) ipart[ib*6 + t] = sd[t];
    } else if (b == 1579) {               // graph offsets (batch sorted)
        if (t <= GG) {
            int g = t, lo = 0, hi = NN;
            while (lo < hi) { int mid = (lo + hi) >> 1; if (batch[mid] < g) lo = mid + 1; else hi = mid; }
            goff[g] = lo;
        }
    } else if (b < 1583) {                // per-layer attention weight fold (Ws/Wd/wev)
        int L = b - 1580;
        const float *W, *Wep, *as_, *ad_, *ae_; int INF, CC;
        if (L == 0)      { W = w0; Wep = we0; as_ = as0; ad_ = ad0; ae_ = ae0; INF = 3;  CC = 8;  }
        else if (L == 1) { W = w1; Wep = we1; as_ = as1; ad_ = ad1; ae_ = ae1; INF = 64; CC = 8;  }
        else             { W = w2; Wep = we2; as_ = as2; ad_ = ad2; ae_ = ae2; INF = 64; CC = 64; }
        int HC = 8 * CC;
        for (int tt = t; tt < INF * 8; tt += 256) {
            int i = tt >> 3, h = tt & 7;
            float s = 0.f, d = 0.f;
            for (int c = 0; c < CC; c++) {
                float w = W[i*HC + h*CC + c];
                s += w * as_[h*CC + c];
                d += w * ad_[h*CC + c];
            }
            Ws[L*512 + i*8 + h] = s; Wd[L*512 + i*8 + h] = d;
        }
        if (t < 8) {
            float s = 0.f;
            for (int c = 0; c < CC; c++) s += Wep[t*CC + c] * ae_[t*CC + c];
            wev[L*8 + t] = s;
        }
    } else if (b < 1711) {                // W2 swizzle (MFMA B-frag order)
        int idx = (b - 1583) * 256 + t;   // < 32768
        int j  = idx & 7;
        int l  = (idx >> 3) & 63;
        int nt = (idx >> 9) & 3;
        int kb = idx >> 11;
        int k = kb*32 + (l >> 4)*4 + (j & 3) + 16*(j >> 2);
        int c = nt*16 + (l & 15);
        int h = k >> 6, i = k & 63;
        bsw[idx] = f2bf(w2[i*512 + h*64 + c]);
    } else if (b < 1731) {                // layer-1 cat [W1 | Ws1 | Wd1] swizzle (5 tiles, K=64)
        int idx = (b - 1711) * 256 + t;   // < 5120
        int j  = idx & 7;
        int l  = (idx >> 3) & 63;
        int r2 = idx >> 9;                // 0..9
        int nt = r2 % 5, kb = r2 / 5;
        int k = kb*32 + (l >> 4)*4 + (j & 3) + 16*(j >> 2);
        int c = nt*16 + (l & 15);
        float val;
        if (c < 64) val = w1[k*64 + c];
        else {
            int h = (c - 64) & 7;
            const float* aa = (c < 72) ? as1 : ad1;
            float s = 0.f;
            for (int cc = 0; cc < 8; cc++) s += w1[k*64 + h*8 + cc] * aa[h*8 + cc];
            val = s;
        }
        bswc[idx] = f2bf(val);
    } else {                              // layer-2 [Ws2 | Wd2] swizzle (1 tile, K=64)
        int idx = (b - 1731) * 256 + t;   // < 1024
        int j  = idx & 7;
        int l  = (idx >> 3) & 63;
        int kb = idx >> 9;                // 0..1
        int k = kb*32 + (l >> 4)*4 + (j & 3) + 16*(j >> 2);
        int c = l & 15;
        int h = c & 7;
        const float* aa = (c < 8) ? as2 : ad2;
        float s = 0.f;
        for (int cc = 0; cc < 64; cc++) s += w2[k*512 + h*64 + cc] * aa[h*64 + cc];
        bswa[idx] = f2bf(s);
    }
}

// ============ hierarchical degree scan (3 stages, replaces 1-block k_scan) ============
// Stage 1: per-block exclusive scan of 256 elements -> rows (local), bsum[blk]
__global__ void k_scan1(const int* __restrict__ deg, int* __restrict__ rows,
                        int* __restrict__ bsum) {
    int t = threadIdx.x, b = blockIdx.x;
    int i = b * 256 + t;
    int v = (i < NN) ? deg[i] : 0;
    __shared__ int sd[256];
    sd[t] = v; __syncthreads();
    for (int off = 1; off < 256; off <<= 1) {
        int x = (t >= off) ? sd[t - off] : 0;
        __syncthreads();
        sd[t] += x;
        __syncthreads();
    }
    if (i < NN) rows[i] = sd[t] - v;     // exclusive local scan
    if (t == 255) bsum[b] = sd[255];
}

// Stage 2: exclusive scan of 98 block sums (+ finalize input-BN stats)
__global__ void k_scan2(const int* __restrict__ bsum, int* __restrict__ boff,
                        const float* __restrict__ ipart, float* __restrict__ inbn) {
    int t = threadIdx.x;
    if (t == 0) {
        int run = 0;
        for (int b = 0; b < 98; b++) { int v = bsum[b]; boff[b] = run; run += v; }
    }
    if (t < 6) { float s = 0.f; for (int b = 0; b < 16; b++) s += ipart[b*6 + t]; inbn[t] = s; }
}

// Stage 3: add block offsets -> final rows/cur
__global__ void k_scan3(const int* __restrict__ boff, int* __restrict__ rows,
                        int* __restrict__ cur) {
    int t = threadIdx.x, b = blockIdx.x;
    int i = b * 256 + t;
    if (i < NN) {
        int r = rows[i] + boff[b];
        rows[i] = r;
        cur[i] = r;
    }
    if (b == 0 && t == 0) rows[NN] = EE;
}

__global__ void k_fill(const int* __restrict__ ei, const float* __restrict__ ea,
                       int* __restrict__ cur, int* __restrict__ csrc,
                       float* __restrict__ cea) {
    int e = blockIdx.x * 256 + threadIdx.x;
    if (e >= EE) return;
    int s = ei[e], d = ei[EE + e];
    int pos = atomicAdd(&cur[d], 1);
    csrc[pos] = s; cea[pos] = ea[e];
}

// ============ layer-0 projection (input BN fused, in=3) ============
__global__ void k_proj0(const float* __restrict__ x, const float* __restrict__ sums,
                        const float* __restrict__ g, const float* __restrict__ b,
                        const float* __restrict__ W0,
                        const float* __restrict__ Ws, const float* __restrict__ Wd,
                        float* __restrict__ xs, float* __restrict__ asrc, float* __restrict__ adst) {
    int idx = blockIdx.x * 256 + threadIdx.x;
    if (idx >= NN * 64) return;
    int n = idx >> 6, j = idx & 63;
    float xn[3];
#pragma unroll
    for (int i = 0; i < 3; i++) {
        float m = sums[i] * (1.0f / NN);
        float v = sums[3+i] * (1.0f / NN) - m*m;
        xn[i] = (x[n*3+i] - m) * rsqrtf(v + 1e-5f) * g[i] + b[i];
    }
    float a = 0.f;
#pragma unroll
    for (int i = 0; i < 3; i++) a += xn[i] * W0[i*64 + j];
    xs[n*64 + j] = a;
    if (j < 16) {
        const float* WA = (j < 8) ? Ws : Wd;
        int h = j & 7;
        float s = 0.f;
#pragma unroll
        for (int i = 0; i < 3; i++) s += xn[i] * WA[i*8 + h];
        if (j < 8) asrc[n*8 + h] = s; else adst[n*8 + h] = s;
    }
}

// ============ fused edge-softmax + aggregation, C=8 (layers 0,1), chunked+4x ============
__global__ void k_agg8f(const int* __restrict__ rows, const int* __restrict__ csrc,
                        const float* __restrict__ cea,
                        const float* __restrict__ asrc, const float* __restrict__ adst,
                        const float* __restrict__ wev,
                        const float* __restrict__ xs, float* __restrict__ agg) {
    int lane = threadIdx.x & 63;
    int d = (blockIdx.x * blockDim.x + threadIdx.x) >> 6;
    if (d >= NN) return;
    int h = lane >> 3;
    float adh = adst[d*8 + h];
    float wh  = wev[h];
    int rs = rows[d], re = rows[d+1];
    float acc = 0.f, den = 0.f;
    for (int c0 = rs; c0 < re; c0 += 64) {
        int cnt = re - c0; if (cnt > 64) cnt = 64;
        int ii = c0 + (lane < cnt ? lane : 0);
        int es = csrc[ii];
        float ef = cea[ii];
        int j = 0;
        for (; j + 3 < cnt; j += 4) {
            int s0 = __shfl(es, j),   s1 = __shfl(es, j+1);
            int s2 = __shfl(es, j+2), s3 = __shfl(es, j+3);
            float a0 = __shfl(ef, j),   a1 = __shfl(ef, j+1);
            float a2 = __shfl(ef, j+2), a3 = __shfl(ef, j+3);
            float l0 = asrc[s0*8+h], l1 = asrc[s1*8+h];
            float l2 = asrc[s2*8+h], l3 = asrc[s3*8+h];
            float x0 = xs[s0*64+lane], x1 = xs[s1*64+lane];
            float x2 = xs[s2*64+lane], x3 = xs[s3*64+lane];
            l0 += adh + a0*wh; l1 += adh + a1*wh;
            l2 += adh + a2*wh; l3 += adh + a3*wh;
            l0 = fmaxf(l0, 0.2f*l0); l1 = fmaxf(l1, 0.2f*l1);
            l2 = fmaxf(l2, 0.2f*l2); l3 = fmaxf(l3, 0.2f*l3);
            float e0 = __expf(l0), e1 = __expf(l1), e2 = __expf(l2), e3 = __expf(l3);
            den += (e0 + e1) + (e2 + e3);
            acc += e0*x0; acc += e1*x1; acc += e2*x2; acc += e3*x3;
        }
        for (; j < cnt; j++) {
            int s = __shfl(es, j);
            float a = __shfl(ef, j);
            float l = asrc[s*8+h] + adh + a*wh;
            l = fmaxf(l, 0.2f*l);
            float e = __expf(l);
            den += e;
            acc += e * xs[s*64+lane];
        }
    }
    agg[d*64 + lane] = acc / fmaxf(den, 1e-16f);
}

// ============ layer-1 projection via MFMA: [xb | asrc | adst] = elu(bn(agg)) @ [W1|Ws1|Wd1] ============
__global__ void k_proj1m(const float* __restrict__ agg, const float* __restrict__ ab,
                         const short* __restrict__ bswc,
                         float* __restrict__ xb, float* __restrict__ xs,
                         float* __restrict__ asrc, float* __restrict__ adst) {
    int l = threadIdx.x & 63;
    int wid = (blockIdx.x * blockDim.x + threadIdx.x) >> 6;
    int n0 = wid * 16;
    if (n0 >= NN) return;
    int ra = n0 + (l & 15); if (ra > NN-1) ra = NN-1;
    int kq = (l >> 4) * 4;
    const sh8* Bs = (const sh8*)bswc;
    sh8 af0, af1;
#pragma unroll
    for (int kb = 0; kb < 2; kb++) {
        int c0 = kb*32 + kq;
        float4 a0 = *(const float4*)&agg[ra*64 + c0];
        float4 a1 = *(const float4*)&agg[ra*64 + c0 + 16];
        float4 sc0 = *(const float4*)&ab[c0];
        float4 sh0 = *(const float4*)&ab[64 + c0];
        float4 sc1 = *(const float4*)&ab[c0 + 16];
        float4 sh1 = *(const float4*)&ab[64 + c0 + 16];
        float o[8];
        o[0] = a0.x*sc0.x + sh0.x; o[1] = a0.y*sc0.y + sh0.y;
        o[2] = a0.z*sc0.z + sh0.z; o[3] = a0.w*sc0.w + sh0.w;
        o[4] = a1.x*sc1.x + sh1.x; o[5] = a1.y*sc1.y + sh1.y;
        o[6] = a1.z*sc1.z + sh1.z; o[7] = a1.w*sc1.w + sh1.w;
#pragma unroll
        for (int u = 0; u < 8; u++) o[u] = (o[u] > 0.f) ? o[u] : (__expf(o[u]) - 1.f);
        float4 w0v = {o[0],o[1],o[2],o[3]}, w1v = {o[4],o[5],o[6],o[7]};
        *(float4*)&xb[ra*64 + c0]      = w0v;
        *(float4*)&xb[ra*64 + c0 + 16] = w1v;
        sh8 af;
#pragma unroll
        for (int u = 0; u < 8; u++) af[u] = f2bf(o[u]);
        if (kb == 0) af0 = af; else af1 = af;
    }
    f32x4 acc[5];
#pragma unroll
    for (int nt = 0; nt < 5; nt++) acc[nt] = (f32x4){0,0,0,0};
#pragma unroll
    for (int nt = 0; nt < 5; nt++) {
        acc[nt] = __builtin_amdgcn_mfma_f32_16x16x32_bf16(af0, Bs[nt*64 + l], acc[nt], 0, 0, 0);
        acc[nt] = __builtin_amdgcn_mfma_f32_16x16x32_bf16(af1, Bs[(5+nt)*64 + l], acc[nt], 0, 0, 0);
    }
    int rbase = n0 + (l >> 4) * 4, cb = l & 15;
#pragma unroll
    for (int r = 0; r < 4; r++) {
        int n = rbase + r;
        if (n >= NN) break;
#pragma unroll
        for (int nt = 0; nt < 4; nt++) xs[n*64 + nt*16 + cb] = acc[nt][r];
        if (cb < 8) asrc[n*8 + cb] = acc[4][r];
        else        adst[n*8 + (cb-8)] = acc[4][r];
    }
}

// ============ fused BN1-apply + residual + layer-2 attention logits (MFMA) ============
__global__ void k_bnattn(const float* __restrict__ agg, const float* __restrict__ ab,
                         const short* __restrict__ bswa,
                         float* __restrict__ xb,
                         float* __restrict__ asrc, float* __restrict__ adst) {
    int l = threadIdx.x & 63;
    int wid = (blockIdx.x * blockDim.x + threadIdx.x) >> 6;
    int n0 = wid * 16;
    if (n0 >= NN) return;
    int ra = n0 + (l & 15); if (ra > NN-1) ra = NN-1;
    int kq = (l >> 4) * 4;
    const sh8* Bs = (const sh8*)bswa;
    sh8 af0, af1;
#pragma unroll
    for (int kb = 0; kb < 2; kb++) {
        int c0 = kb*32 + kq;
        float4 a0 = *(const float4*)&agg[ra*64 + c0];
        float4 a1 = *(const float4*)&agg[ra*64 + c0 + 16];
        float4 x0 = *(const float4*)&xb[ra*64 + c0];
        float4 x1 = *(const float4*)&xb[ra*64 + c0 + 16];
        float4 sc0 = *(const float4*)&ab[c0];
        float4 sh0 = *(const float4*)&ab[64 + c0];
        float4 sc1 = *(const float4*)&ab[c0 + 16];
        float4 sh1 = *(const float4*)&ab[64 + c0 + 16];
        float o[8];
        o[0] = a0.x*sc0.x + sh0.x; o[1] = a0.y*sc0.y + sh0.y;
        o[2] = a0.z*sc0.z + sh0.z; o[3] = a0.w*sc0.w + sh0.w;
        o[4] = a1.x*sc1.x + sh1.x; o[5] = a1.y*sc1.y + sh1.y;
        o[6] = a1.z*sc1.z + sh1.z; o[7] = a1.w*sc1.w + sh1.w;
#pragma unroll
        for (int u = 0; u < 8; u++) o[u] = (o[u] > 0.f) ? o[u] : (__expf(o[u]) - 1.f);
        o[0] += x0.x; o[1] += x0.y; o[2] += x0.z; o[3] += x0.w;
        o[4] += x1.x; o[5] += x1.y; o[6] += x1.z; o[7] += x1.w;
        float4 w0v = {o[0],o[1],o[2],o[3]}, w1v = {o[4],o[5],o[6],o[7]};
        *(float4*)&xb[ra*64 + c0]      = w0v;
        *(float4*)&xb[ra*64 + c0 + 16] = w1v;
        sh8 af;
#pragma unroll
        for (int u = 0; u < 8; u++) af[u] = f2bf(o[u]);
        if (kb == 0) af0 = af; else af1 = af;
    }
    f32x4 acc = {0,0,0,0};
    acc = __builtin_amdgcn_mfma_f32_16x16x32_bf16(af0, Bs[l],      acc, 0, 0, 0);
    acc = __builtin_amdgcn_mfma_f32_16x16x32_bf16(af1, Bs[64 + l], acc, 0, 0, 0);
    int rbase = n0 + (l >> 4) * 4, cb = l & 15;
#pragma unroll
    for (int r = 0; r < 4; r++) {
        int n = rbase + r;
        if (n >= NN) break;
        if (cb < 8) asrc[n*8 + cb] = acc[r];
        else        adst[n*8 + (cb-8)] = acc[r];
    }
}

// ============ layer-2 fused: edge-softmax + aggregate + MFMA projection (chunked+2x) ============
__global__ __launch_bounds__(256) void k_l2f(
        const int* __restrict__ rows, const int* __restrict__ csrc,
        const float* __restrict__ cea,
        const float* __restrict__ asrc, const float* __restrict__ adst,
        const float* __restrict__ wev,
        const float* __restrict__ x, const short* __restrict__ bsw,
        float* __restrict__ agg) {
    __shared__ short zl[16 * 520];
    int t = threadIdx.x, lane = t & 63, wv = t >> 6;
    int blk = blockIdx.x;
    int h = lane >> 3;
    float wh = wev[h];
    const float4* x4 = (const float4*)x;
    int fo   = (lane & 7) * 2;
    int kb_w = lane >> 2;
    int qd0  = 2 * (lane & 1);
    int jhi  = 4 * ((lane >> 1) & 1);
    for (int q = 0; q < 4; q++) {
        int r = wv * 4 + q;
        int d = blk * 16 + r;
        float acc[8] = {0,0,0,0,0,0,0,0};
        float den = 0.f;
        if (d < NN) {
            float adh = adst[d*8 + h];
            int rs = rows[d], re = rows[d+1];
            for (int c0 = rs; c0 < re; c0 += 64) {
                int cnt = re - c0; if (cnt > 64) cnt = 64;
                int ii = c0 + (lane < cnt ? lane : 0);
                int es = csrc[ii];
                float ef = cea[ii];
                int j = 0;
                for (; j + 1 < cnt; j += 2) {
                    int s0 = __shfl(es, j), s1 = __shfl(es, j+1);
                    float a0 = __shfl(ef, j), a1 = __shfl(ef, j+1);
                    float l0 = asrc[s0*8+h], l1 = asrc[s1*8+h];
                    float4 u0 = x4[s0*16 + fo], u1 = x4[s0*16 + fo + 1];
                    float4 v0 = x4[s1*16 + fo], v1 = x4[s1*16 + fo + 1];
                    l0 += adh + a0*wh; l1 += adh + a1*wh;
                    l0 = fmaxf(l0, 0.2f*l0); l1 = fmaxf(l1, 0.2f*l1);
                    float e0 = __expf(l0), e1 = __expf(l1);
                    den += e0 + e1;
                    acc[0] += e0*u0.x + e1*v0.x;
                    acc[1] += e0*u0.y + e1*v0.y;
                    acc[2] += e0*u0.z + e1*v0.z;
                    acc[3] += e0*u0.w + e1*v0.w;
                    acc[4] += e0*u1.x + e1*v1.x;
                    acc[5] += e0*u1.y + e1*v1.y;
                    acc[6] += e0*u1.z + e1*v1.z;
                    acc[7] += e0*u1.w + e1*v1.w;
                }
                if (j < cnt) {
                    int s = __shfl(es, j);
                    float a = __shfl(ef, j);
                    float l = asrc[s*8+h] + adh + a*wh;
                    l = fmaxf(l, 0.2f*l);
                    float e = __expf(l);
                    den += e;
                    float4 u0 = x4[s*16 + fo], u1 = x4[s*16 + fo + 1];
                    acc[0] += e*u0.x; acc[1] += e*u0.y; acc[2] += e*u0.z; acc[3] += e*u0.w;
                    acc[4] += e*u1.x; acc[5] += e*u1.y; acc[6] += e*u1.z; acc[7] += e*u1.w;
                }
            }
        }
        float inv = 1.0f / fmaxf(den, 1e-16f);
        short4 lo, hi;
        lo.x = f2bf(acc[0]*inv); lo.y = f2bf(acc[1]*inv);
        lo.z = f2bf(acc[2]*inv); lo.w = f2bf(acc[3]*inv);
        hi.x = f2bf(acc[4]*inv); hi.y = f2bf(acc[5]*inv);
        hi.z = f2bf(acc[6]*inv); hi.w = f2bf(acc[7]*inv);
        *(short4*)&zl[kb_w*520 + (r + 16*qd0)*8 + jhi]     = lo;
        *(short4*)&zl[kb_w*520 + (r + 16*(qd0+1))*8 + jhi] = hi;
    }
    __syncthreads();
    const sh8* Bs = (const sh8*)bsw;
    f32x4 acc = {0,0,0,0};
    for (int kb = 0; kb < 16; kb++) {
        sh8 a = *(const sh8*)&zl[kb*520 + lane*8];
        sh8 bf = Bs[(kb*4 + wv)*64 + lane];
        acc = __builtin_amdgcn_mfma_f32_16x16x32_bf16(a, bf, acc, 0, 0, 0);
    }
    int row = blk*16 + (lane >> 4) * 4;
    int col = wv*16 + (lane & 15);
#pragma unroll
    for (int rr = 0; rr < 4; rr++) {
        int n = row + rr;
        if (n < NN) agg[(size_t)n*64 + col] = acc[rr] * 0.125f;
    }
}

// ============ BN stats partials (bias cancels in training-mode BN) ============
__global__ void k_bnstats(const float* __restrict__ agg, float* __restrict__ part) {
    int t = threadIdx.x;
    int c = t & 63;
    int r0 = blockIdx.x * 4 + (t >> 6);
    float s = 0.f, q = 0.f;
    for (int n = r0; n < NN; n += gridDim.x * 4) {
        float y = agg[n*64 + c];
        s += y; q += y*y;
    }
    __shared__ float sd[512];
    sd[t] = s; sd[256 + t] = q;
    __syncthreads();
    if (t < 128) { sd[t] += sd[t+128]; sd[256+t] += sd[256+t+128]; }
    __syncthreads();
    if (t < 64) {
        part[blockIdx.x*128 + t]      = sd[t] + sd[t+64];
        part[blockIdx.x*128 + 64 + t] = sd[256+t] + sd[256+t+64];
    }
}

// ============ BN finalize ============
__global__ void k_bnfin(const float* __restrict__ part, const float* __restrict__ gam,
                        const float* __restrict__ bet, float* __restrict__ ab) {
    int c = threadIdx.x;
    if (c >= 64) return;
    float s = 0.f, q = 0.f;
    for (int b = 0; b < 128; b++) { s += part[b*128 + c]; q += part[b*128 + 64 + c]; }
    float m = s * (1.0f / NN);
    float v = q * (1.0f / NN) - m*m;
    float a = gam[c] * rsqrtf(v + 1e-5f);
    ab[c] = a;
    ab[64 + c] = bet[c] - m * a;
}

// ============ fused: BN2-apply + residual + dual pooling + MLP head ============
__global__ void k_poolmlp(const float* __restrict__ xb, const float* __restrict__ agg,
                          const float* __restrict__ ab, const int* __restrict__ goff,
                          const float* __restrict__ fc1w, const float* __restrict__ fc1b,
                          const float* __restrict__ fc2w, const float* __restrict__ fc2b,
                          const float* __restrict__ fgw, const float* __restrict__ fgb,
                          const float* __restrict__ fbw, const float* __restrict__ fbb,
                          float* __restrict__ out) {
    int g = blockIdx.x, t = threadIdx.x;
    int c = t & 63, r = t >> 6;
    float a = ab[c], sh = ab[64 + c];
    int st = goff[g], en = goff[g+1];
    float s = 0.f, mx = -INFINITY;
    for (int n = st + r; n < en; n += 4) {
        float o = agg[n*64 + c] * a + sh;
        o = (o > 0.f) ? o : (__expf(o) - 1.0f);
        float v = xb[n*64 + c] + o;
        s += v; mx = fmaxf(mx, v);
    }
    __shared__ float sd[512];
    __shared__ float sg[128], s1[128], s2[64];
    sd[t] = s; sd[256 + t] = mx;
    __syncthreads();
    if (t < 128) { sd[t] += sd[t+128]; sd[256+t] = fmaxf(sd[256+t], sd[256+t+128]); }
    __syncthreads();
    if (t < 64) {
        float cnt = (float)(en - st);
        sg[t]      = (sd[t] + sd[t+64]) / fmaxf(cnt, 1.0f);
        sg[64 + t] = fmaxf(sd[256+t], sd[256+t+64]);
    }
    __syncthreads();
    if (t < 128) {
        float av = fc1b[t];
        for (int i = 0; i < 128; i++) av += sg[i] * fc1w[i*128 + t];
        s1[t] = (av > 0.f) ? av : (__expf(av) - 1.f);
    }
    __syncthreads();
    if (t < 64) {
        float bv = fc2b[t];
        for (int i = 0; i < 128; i++) bv += s1[i] * fc2w[i*64 + t];
        s2[t] = (bv > 0.f) ? bv : (__expf(bv) - 1.f);
    }
    __syncthreads();
    if (t == 0) {
        float ga = fgb[0], be = fbb[0];
        for (int i = 0; i < 64; i++) { ga += s2[i] * fgw[i]; be += s2[i] * fbw[i]; }
        out[g*2 + 0] = ga;
        out[g*2 + 1] = be;
    }
}

extern "C" void kernel_launch(void* const* d_in, const int* in_sizes, int n_in,
                              void* d_out, int out_size, void* d_ws, size_t ws_size,
                              hipStream_t stream) {
    (void)in_sizes; (void)n_in; (void)out_size; (void)ws_size;
    const float* x3    = (const float*)d_in[0];
    const int*   ei    = (const int*)d_in[1];
    const float* ea    = (const float*)d_in[2];
    const int*   batch = (const int*)d_in[3];
    const float* ing   = (const float*)d_in[4];
    const float* inb   = (const float*)d_in[5];
    const float* w0    = (const float*)d_in[6];
    const float* we0   = (const float*)d_in[7];
    const float* as0   = (const float*)d_in[8];
    const float* ad0   = (const float*)d_in[9];
    const float* ae0   = (const float*)d_in[10];
    const float* bng0  = (const float*)d_in[12];
    const float* bnb0  = (const float*)d_in[13];
    const float* w1    = (const float*)d_in[14];
    const float* we1   = (const float*)d_in[15];
    const float* as1   = (const float*)d_in[16];
    const float* ad1   = (const float*)d_in[17];
    const float* ae1   = (const float*)d_in[18];
    const float* bng1  = (const float*)d_in[20];
    const float* bnb1  = (const float*)d_in[21];
    const float* w2    = (const float*)d_in[22];
    const float* we2   = (const float*)d_in[23];
    const float* as2   = (const float*)d_in[24];
    const float* ad2   = (const float*)d_in[25];
    const float* ae2   = (const float*)d_in[26];
    const float* bng2  = (const float*)d_in[28];
    const float* bnb2  = (const float*)d_in[29];
    const float* fc1w  = (const float*)d_in[30];
    const float* fc1b  = (const float*)d_in[31];
    const float* fc2w  = (const float*)d_in[32];
    const float* fc2b  = (const float*)d_in[33];
    const float* fgw   = (const float*)d_in[34];
    const float* fgb   = (const float*)d_in[35];
    const float* fbw   = (const float*)d_in[36];
    const float* fbb   = (const float*)d_in[37];

    float* fws = (float*)d_ws;
    int*   iws = (int*)d_ws;
    int*   deg   = iws + O_DEG;
    int*   rows  = iws + O_ROWS;
    int*   cur   = iws + O_CUR;
    int*   goff  = iws + O_GOFF;
    float* ipart = fws + O_IPART;
    float* inbn  = fws + O_INBN;
    float* Ws    = fws + O_WS;
    float* Wd    = fws + O_WD;
    float* wev   = fws + O_WE;
    float* bpart = fws + O_BPART;
    float* ab    = fws + O_AB;
    short* bsw   = (short*)(fws + O_BSW);
    int*   csrc  = iws + O_CSRC;
    float* cea   = fws + O_CEA;
    float* xs    = fws + O_XS;
    float* asrc  = fws + O_ASRC;
    float* adst  = fws + O_ADST;
    float* agg   = fws + O_AGG;
    float* xb    = fws + O_X;
    short* bswc  = (short*)(fws + O_BSWC);
    short* bswa  = (short*)(fws + O_BSWA);
    int*   bsum  = iws + O_BSUM;
    int*   boff  = iws + O_BOFF;

    hipMemsetAsync(d_ws, 0, (size_t)ZERO_END * sizeof(int), stream);

    k_pre<<<1735, 256, 0, stream>>>(ei, batch, x3,
                                    w0, we0, as0, ad0, ae0,
                                    w1, we1, as1, ad1, ae1,
                                    w2, we2, as2, ad2, ae2,
                                    deg, goff, ipart, Ws, Wd, wev, bsw, bswc, bswa);
    k_scan1<<<98, 256, 0, stream>>>(deg, rows, bsum);
    k_scan2<<<1, 64, 0, stream>>>(bsum, boff, ipart, inbn);
    k_scan3<<<98, 256, 0, stream>>>(boff, rows, cur);
    k_fill<<<(EE + 255) / 256, 256, 0, stream>>>(ei, ea, cur, csrc, cea);

    const int nblk64 = (NN * 64 + 255) / 256;   // 6250
    const int wblk16 = ((NN + 15) / 16 + 3) / 4; // 391 blocks of 4 waves (16 nodes/wave)

    // ---- layer 0 ----
    k_proj0<<<nblk64, 256, 0, stream>>>(x3, inbn, ing, inb, w0, Ws, Wd, xs, asrc, adst);
    k_agg8f<<<nblk64, 256, 0, stream>>>(rows, csrc, cea, asrc, adst, wev, xs, agg);
    k_bnstats<<<128, 256, 0, stream>>>(agg, bpart);
    k_bnfin<<<1, 64, 0, stream>>>(bpart, bng0, bnb0, ab);

    // ---- layer 1 (BN0-apply + xb + projection + logits via MFMA) ----
    k_proj1m<<<wblk16, 256, 0, stream>>>(agg, ab, bswc, xb, xs, asrc, adst);
    k_agg8f<<<nblk64, 256, 0, stream>>>(rows, csrc, cea, asrc, adst, wev + 8, xs, agg);
    k_bnstats<<<128, 256, 0, stream>>>(agg, bpart);
    k_bnfin<<<1, 64, 0, stream>>>(bpart, bng1, bnb1, ab);

    // ---- layer 2 (BN1-apply + residual + logits fused; then fused agg+MFMA) ----
    k_bnattn<<<wblk16, 256, 0, stream>>>(agg, ab, bswa, xb, asrc, adst);
    k_l2f<<<(NN + 15) / 16, 256, 0, stream>>>(rows, csrc, cea, asrc, adst, wev + 16,
                                              xb, bsw, agg);
    k_bnstats<<<128, 256, 0, stream>>>(agg, bpart);
    k_bnfin<<<1, 64, 0, stream>>>(bpart, bng2, bnb2, ab);

    // ---- BN2-apply + residual + pooling + MLP head ----
    k_poolmlp<<<GG, 256, 0, stream>>>(xb, agg, ab, goff, fc1w, fc1b, fc2w, fc2b,
                                      fgw, fgb, fbw, fbb, (float*)d_out);
}

// Round 11
// 416.459 us; speedup vs baseline: 1.9869x; 1.0079x over previous
//
#include <hip/hip_runtime.h>
#include <math.h>

#define NN 25000
#define EE 400000
#define GG 64
#define NB 64          // CSR-build blocks (private histogram copies)
#define PL 25024       // plane stride (NN padded to 16B)
#define EPB 6250       // edges per build block (EE/NB exact)

// ---- workspace layout (element offsets, 16B-aligned; NO memset needed) ----
static const int O_CNT   = 0;        // NB*PL ints (per-block histograms)
static const int O_ROWS  = 1601536;  // 25008 ints
static const int O_CUR   = 1626544;  // NB*PL ints (per-block cursor bases)
static const int O_GOFF  = 3228080;  // 72 ints
static const int O_IPART = 3228152;  // 96 f
static const int O_INBN  = 3228248;  // 8 f
static const int O_WS    = 3228256;  // 3*512 f
static const int O_WD    = 3229792;  // 3*512 f
static const int O_WE    = 3231328;  // 32 f
static const int O_BPART = 3231360;  // 128*128 f
static const int O_AB    = 3247744;  // 128 f
static const int O_BSW   = 3247872;  // 16384 f = 32768 bf16 (swizzled W2)
static const int O_CSRC  = 3264256;  // 400000 int
static const int O_CEA   = 3664256;  // 400000 f
static const int O_XS    = 4064256;  // 1.6M f
static const int O_ASRC  = 5664256;  // 200000 f
static const int O_ADST  = 5864256;  // 200000 f
static const int O_AGG   = 6064256;  // 1.6M f
static const int O_X     = 7664256;  // 1.6M f
static const int O_BSWC  = 9264256;  // 2560 f = 5120 bf16
static const int O_BSWA  = 9266816;  // 512 f = 1024 bf16
static const int O_BSUM  = 9267328;  // 104 ints
static const int O_BOFF  = 9267432;  // 104 ints

using f32x4 = __attribute__((ext_vector_type(4))) float;
using sh8   = __attribute__((ext_vector_type(8))) short;  // 8 bf16

__device__ inline short f2bf(float f) {
    unsigned u = __float_as_uint(f);
    unsigned r = (u + 0x7FFFu + ((u >> 16) & 1u)) >> 16;   // RNE to bf16
    return (short)r;
}

// ============ setup (no histogram): instats | goff | prew x3 | bswz | bswc | bswa ============
__global__ void k_pre(const int* __restrict__ batch, const float* __restrict__ x3,
                      const float* w0, const float* we0, const float* as0, const float* ad0, const float* ae0,
                      const float* w1, const float* we1, const float* as1, const float* ad1, const float* ae1,
                      const float* w2, const float* we2, const float* as2, const float* ad2, const float* ae2,
                      int* __restrict__ goff, float* __restrict__ ipart,
                      float* __restrict__ Ws, float* __restrict__ Wd, float* __restrict__ wev,
                      short* __restrict__ bsw, short* __restrict__ bswc, short* __restrict__ bswa) {
    __shared__ float sd[1536];
    int b = blockIdx.x, t = threadIdx.x;
    if (b < 16) {                         // input-BN partial stats
        int ib = b;
        float s[3] = {0,0,0}, q[3] = {0,0,0};
        for (int n = ib * 256 + t; n < NN; n += 16 * 256) {
#pragma unroll
            for (int i = 0; i < 3; i++) { float v = x3[n*3+i]; s[i] += v; q[i] += v*v; }
        }
#pragma unroll
        for (int i = 0; i < 3; i++) { sd[t*6+i] = s[i]; sd[t*6+3+i] = q[i]; }
        __syncthreads();
        for (int off = 128; off > 0; off >>= 1) {
            if (t < off) {
#pragma unroll
                for (int i = 0; i < 6; i++) sd[t*6+i] += sd[(t+off)*6+i];
            }
            __syncthreads();
        }
        if (t < 6) ipart[ib*6 + t] = sd[t];
    } else if (b == 16) {                 // graph offsets (batch sorted)
        if (t <= GG) {
            int g = t, lo = 0, hi = NN;
            while (lo < hi) { int mid = (lo + hi) >> 1; if (batch[mid] < g) lo = mid + 1; else hi = mid; }
            goff[g] = lo;
        }
    } else if (b < 20) {                  // per-layer attention weight fold
        int L = b - 17;
        const float *W, *Wep, *as_, *ad_, *ae_; int INF, CC;
        if (L == 0)      { W = w0; Wep = we0; as_ = as0; ad_ = ad0; ae_ = ae0; INF = 3;  CC = 8;  }
        else if (L == 1) { W = w1; Wep = we1; as_ = as1; ad_ = ad1; ae_ = ae1; INF = 64; CC = 8;  }
        else             { W = w2; Wep = we2; as_ = as2; ad_ = ad2; ae_ = ae2; INF = 64; CC = 64; }
        int HC = 8 * CC;
        for (int tt = t; tt < INF * 8; tt += 256) {
            int i = tt >> 3, h = tt & 7;
            float s = 0.f, d = 0.f;
            for (int c = 0; c < CC; c++) {
                float w = W[i*HC + h*CC + c];
                s += w * as_[h*CC + c];
                d += w * ad_[h*CC + c];
            }
            Ws[L*512 + i*8 + h] = s; Wd[L*512 + i*8 + h] = d;
        }
        if (t < 8) {
            float s = 0.f;
            for (int c = 0; c < CC; c++) s += Wep[t*CC + c] * ae_[t*CC + c];
            wev[L*8 + t] = s;
        }
    } else if (b < 148) {                 // W2 swizzle (128 blocks)
        int idx = (b - 20) * 256 + t;     // < 32768
        int j  = idx & 7;
        int l  = (idx >> 3) & 63;
        int nt = (idx >> 9) & 3;
        int kb = idx >> 11;
        int k = kb*32 + (l >> 4)*4 + (j & 3) + 16*(j >> 2);
        int c = nt*16 + (l & 15);
        int h = k >> 6, i = k & 63;
        bsw[idx] = f2bf(w2[i*512 + h*64 + c]);
    } else if (b < 168) {                 // layer-1 cat [W1|Ws1|Wd1] swizzle (20 blocks)
        int idx = (b - 148) * 256 + t;    // < 5120
        int j  = idx & 7;
        int l  = (idx >> 3) & 63;
        int r2 = idx >> 9;                // 0..9
        int nt = r2 % 5, kb = r2 / 5;
        int k = kb*32 + (l >> 4)*4 + (j & 3) + 16*(j >> 2);
        int c = nt*16 + (l & 15);
        float val;
        if (c < 64) val = w1[k*64 + c];
        else {
            int h = (c - 64) & 7;
            const float* aa = (c < 72) ? as1 : ad1;
            float s = 0.f;
            for (int cc = 0; cc < 8; cc++) s += w1[k*64 + h*8 + cc] * aa[h*8 + cc];
            val = s;
        }
        bswc[idx] = f2bf(val);
    } else {                              // layer-2 [Ws2|Wd2] swizzle (4 blocks)
        int idx = (b - 168) * 256 + t;    // < 1024
        int j  = idx & 7;
        int l  = (idx >> 3) & 63;
        int kb = idx >> 9;                // 0..1
        int k = kb*32 + (l >> 4)*4 + (j & 3) + 16*(j >> 2);
        int c = l & 15;
        int h = c & 7;
        const float* aa = (c < 8) ? as2 : ad2;
        float s = 0.f;
        for (int cc = 0; cc < 64; cc++) s += w2[k*512 + h*64 + cc] * aa[h*64 + cc];
        bswa[idx] = f2bf(s);
    }
}

// ============ edge histogram: per-block private LDS histogram, zero global atomics ============
__global__ __launch_bounds__(256) void k_hist(const int* __restrict__ ei, int* __restrict__ cnt) {
    __shared__ int hb[PL];
    int t = threadIdx.x, b = blockIdx.x;
    for (int i = t; i < PL; i += 256) hb[i] = 0;
    __syncthreads();
    int e0 = b * EPB;
    for (int e = e0 + t; e < e0 + EPB; e += 256)
        atomicAdd(&hb[ei[EE + e]], 1);
    __syncthreads();
    for (int i = t; i < NN; i += 256) cnt[b * PL + i] = hb[i];
}

// ============ hierarchical degree scan ============
// Stage 1: per-node total over NB planes, per-block exclusive scan -> rows(local), bsum
__global__ void k_scan1(const int* __restrict__ cnt, int* __restrict__ rows,
                        int* __restrict__ bsum) {
    int t = threadIdx.x, b = blockIdx.x;
    int i = b * 256 + t;
    int v = 0;
    if (i < NN) {
        for (int r = 0; r < NB; r++) v += cnt[r * PL + i];
    }
    __shared__ int sd[256];
    sd[t] = v; __syncthreads();
    for (int off = 1; off < 256; off <<= 1) {
        int x = (t >= off) ? sd[t - off] : 0;
        __syncthreads();
        sd[t] += x;
        __syncthreads();
    }
    if (i < NN) rows[i] = sd[t] - v;     // exclusive local scan
    if (t == 255) bsum[b] = sd[255];
}

// Stage 2: exclusive scan of 98 block sums (+ finalize input-BN stats)
__global__ void k_scan2(const int* __restrict__ bsum, int* __restrict__ boff,
                        const float* __restrict__ ipart, float* __restrict__ inbn) {
    int t = threadIdx.x;
    if (t == 0) {
        int run = 0;
        for (int b = 0; b < 98; b++) { int v = bsum[b]; boff[b] = run; run += v; }
    }
    if (t < 6) { float s = 0.f; for (int b = 0; b < 16; b++) s += ipart[b*6 + t]; inbn[t] = s; }
}

// Stage 3: final rows + per-build-block cursor bases (disjoint slot ranges)
__global__ void k_scan3(const int* __restrict__ boff, const int* __restrict__ cnt,
                        int* __restrict__ rows, int* __restrict__ cur) {
    int t = threadIdx.x, b = blockIdx.x;
    int i = b * 256 + t;
    if (i < NN) {
        int run = rows[i] + boff[b];
        rows[i] = run;
        for (int r = 0; r < NB; r++) {
            cur[r * PL + i] = run;
            run += cnt[r * PL + i];
        }
    }
    if (b == 0 && t == 0) rows[NN] = EE;
}

// ============ CSR fill: LDS cursor per block, zero global atomics ============
__global__ __launch_bounds__(256) void k_fill(const int* __restrict__ ei, const float* __restrict__ ea,
                       const int* __restrict__ cur, int* __restrict__ csrc,
                       float* __restrict__ cea) {
    __shared__ int lc[PL];
    int t = threadIdx.x, b = blockIdx.x;
    for (int i = t; i < NN; i += 256) lc[i] = cur[b * PL + i];
    __syncthreads();
    int e0 = b * EPB;
    for (int e = e0 + t; e < e0 + EPB; e += 256) {
        int s = ei[e], d = ei[EE + e];
        int pos = atomicAdd(&lc[d], 1);
        csrc[pos] = s; cea[pos] = ea[e];
    }
}

// ============ layer-0 projection (input BN fused, in=3) ============
__global__ void k_proj0(const float* __restrict__ x, const float* __restrict__ sums,
                        const float* __restrict__ g, const float* __restrict__ b,
                        const float* __restrict__ W0,
                        const float* __restrict__ Ws, const float* __restrict__ Wd,
                        float* __restrict__ xs, float* __restrict__ asrc, float* __restrict__ adst) {
    int idx = blockIdx.x * 256 + threadIdx.x;
    if (idx >= NN * 64) return;
    int n = idx >> 6, j = idx & 63;
    float xn[3];
#pragma unroll
    for (int i = 0; i < 3; i++) {
        float m = sums[i] * (1.0f / NN);
        float v = sums[3+i] * (1.0f / NN) - m*m;
        xn[i] = (x[n*3+i] - m) * rsqrtf(v + 1e-5f) * g[i] + b[i];
    }
    float a = 0.f;
#pragma unroll
    for (int i = 0; i < 3; i++) a += xn[i] * W0[i*64 + j];
    xs[n*64 + j] = a;
    if (j < 16) {
        const float* WA = (j < 8) ? Ws : Wd;
        int h = j & 7;
        float s = 0.f;
#pragma unroll
        for (int i = 0; i < 3; i++) s += xn[i] * WA[i*8 + h];
        if (j < 8) asrc[n*8 + h] = s; else adst[n*8 + h] = s;
    }
}

// ============ fused edge-softmax + aggregation, C=8 (layers 0,1), chunked+4x ============
__global__ void k_agg8f(const int* __restrict__ rows, const int* __restrict__ csrc,
                        const float* __restrict__ cea,
                        const float* __restrict__ asrc, const float* __restrict__ adst,
                        const float* __restrict__ wev,
                        const float* __restrict__ xs, float* __restrict__ agg) {
    int lane = threadIdx.x & 63;
    int d = (blockIdx.x * blockDim.x + threadIdx.x) >> 6;
    if (d >= NN) return;
    int h = lane >> 3;
    float adh = adst[d*8 + h];
    float wh  = wev[h];
    int rs = rows[d], re = rows[d+1];
    float acc = 0.f, den = 0.f;
    for (int c0 = rs; c0 < re; c0 += 64) {
        int cnt = re - c0; if (cnt > 64) cnt = 64;
        int ii = c0 + (lane < cnt ? lane : 0);
        int es = csrc[ii];
        float ef = cea[ii];
        int j = 0;
        for (; j + 3 < cnt; j += 4) {
            int s0 = __shfl(es, j),   s1 = __shfl(es, j+1);
            int s2 = __shfl(es, j+2), s3 = __shfl(es, j+3);
            float a0 = __shfl(ef, j),   a1 = __shfl(ef, j+1);
            float a2 = __shfl(ef, j+2), a3 = __shfl(ef, j+3);
            float l0 = asrc[s0*8+h], l1 = asrc[s1*8+h];
            float l2 = asrc[s2*8+h], l3 = asrc[s3*8+h];
            float x0 = xs[s0*64+lane], x1 = xs[s1*64+lane];
            float x2 = xs[s2*64+lane], x3 = xs[s3*64+lane];
            l0 += adh + a0*wh; l1 += adh + a1*wh;
            l2 += adh + a2*wh; l3 += adh + a3*wh;
            l0 = fmaxf(l0, 0.2f*l0); l1 = fmaxf(l1, 0.2f*l1);
            l2 = fmaxf(l2, 0.2f*l2); l3 = fmaxf(l3, 0.2f*l3);
            float e0 = __expf(l0), e1 = __expf(l1), e2 = __expf(l2), e3 = __expf(l3);
            den += (e0 + e1) + (e2 + e3);
            acc += e0*x0; acc += e1*x1; acc += e2*x2; acc += e3*x3;
        }
        for (; j < cnt; j++) {
            int s = __shfl(es, j);
            float a = __shfl(ef, j);
            float l = asrc[s*8+h] + adh + a*wh;
            l = fmaxf(l, 0.2f*l);
            float e = __expf(l);
            den += e;
            acc += e * xs[s*64+lane];
        }
    }
    agg[d*64 + lane] = acc / fmaxf(den, 1e-16f);
}

// ============ layer-1 projection via MFMA: [xb | asrc | adst] = elu(bn(agg)) @ [W1|Ws1|Wd1] ============
__global__ void k_proj1m(const float* __restrict__ agg, const float* __restrict__ ab,
                         const short* __restrict__ bswc,
                         float* __restrict__ xb, float* __restrict__ xs,
                         float* __restrict__ asrc, float* __restrict__ adst) {
    int l = threadIdx.x & 63;
    int wid = (blockIdx.x * blockDim.x + threadIdx.x) >> 6;
    int n0 = wid * 16;
    if (n0 >= NN) return;
    int ra = n0 + (l & 15); if (ra > NN-1) ra = NN-1;
    int kq = (l >> 4) * 4;
    const sh8* Bs = (const sh8*)bswc;
    sh8 af0, af1;
#pragma unroll
    for (int kb = 0; kb < 2; kb++) {
        int c0 = kb*32 + kq;
        float4 a0 = *(const float4*)&agg[ra*64 + c0];
        float4 a1 = *(const float4*)&agg[ra*64 + c0 + 16];
        float4 sc0 = *(const float4*)&ab[c0];
        float4 sh0 = *(const float4*)&ab[64 + c0];
        float4 sc1 = *(const float4*)&ab[c0 + 16];
        float4 sh1 = *(const float4*)&ab[64 + c0 + 16];
        float o[8];
        o[0] = a0.x*sc0.x + sh0.x; o[1] = a0.y*sc0.y + sh0.y;
        o[2] = a0.z*sc0.z + sh0.z; o[3] = a0.w*sc0.w + sh0.w;
        o[4] = a1.x*sc1.x + sh1.x; o[5] = a1.y*sc1.y + sh1.y;
        o[6] = a1.z*sc1.z + sh1.z; o[7] = a1.w*sc1.w + sh1.w;
#pragma unroll
        for (int u = 0; u < 8; u++) o[u] = (o[u] > 0.f) ? o[u] : (__expf(o[u]) - 1.f);
        float4 w0v = {o[0],o[1],o[2],o[3]}, w1v = {o[4],o[5],o[6],o[7]};
        *(float4*)&xb[ra*64 + c0]      = w0v;
        *(float4*)&xb[ra*64 + c0 + 16] = w1v;
        sh8 af;
#pragma unroll
        for (int u = 0; u < 8; u++) af[u] = f2bf(o[u]);
        if (kb == 0) af0 = af; else af1 = af;
    }
    f32x4 acc[5];
#pragma unroll
    for (int nt = 0; nt < 5; nt++) acc[nt] = (f32x4){0,0,0,0};
#pragma unroll
    for (int nt = 0; nt < 5; nt++) {
        acc[nt] = __builtin_amdgcn_mfma_f32_16x16x32_bf16(af0, Bs[nt*64 + l], acc[nt], 0, 0, 0);
        acc[nt] = __builtin_amdgcn_mfma_f32_16x16x32_bf16(af1, Bs[(5+nt)*64 + l], acc[nt], 0, 0, 0);
    }
    int rbase = n0 + (l >> 4) * 4, cb = l & 15;
#pragma unroll
    for (int r = 0; r < 4; r++) {
        int n = rbase + r;
        if (n >= NN) break;
#pragma unroll
        for (int nt = 0; nt < 4; nt++) xs[n*64 + nt*16 + cb] = acc[nt][r];
        if (cb < 8) asrc[n*8 + cb] = acc[4][r];
        else        adst[n*8 + (cb-8)] = acc[4][r];
    }
}

// ============ fused BN1-apply + residual + layer-2 attention logits (MFMA) ============
__global__ void k_bnattn(const float* __restrict__ agg, const float* __restrict__ ab,
                         const short* __restrict__ bswa,
                         float* __restrict__ xb,
                         float* __restrict__ asrc, float* __restrict__ adst) {
    int l = threadIdx.x & 63;
    int wid = (blockIdx.x * blockDim.x + threadIdx.x) >> 6;
    int n0 = wid * 16;
    if (n0 >= NN) return;
    int ra = n0 + (l & 15); if (ra > NN-1) ra = NN-1;
    int kq = (l >> 4) * 4;
    const sh8* Bs = (const sh8*)bswa;
    sh8 af0, af1;
#pragma unroll
    for (int kb = 0; kb < 2; kb++) {
        int c0 = kb*32 + kq;
        float4 a0 = *(const float4*)&agg[ra*64 + c0];
        float4 a1 = *(const float4*)&agg[ra*64 + c0 + 16];
        float4 x0 = *(const float4*)&xb[ra*64 + c0];
        float4 x1 = *(const float4*)&xb[ra*64 + c0 + 16];
        float4 sc0 = *(const float4*)&ab[c0];
        float4 sh0 = *(const float4*)&ab[64 + c0];
        float4 sc1 = *(const float4*)&ab[c0 + 16];
        float4 sh1 = *(const float4*)&ab[64 + c0 + 16];
        float o[8];
        o[0] = a0.x*sc0.x + sh0.x; o[1] = a0.y*sc0.y + sh0.y;
        o[2] = a0.z*sc0.z + sh0.z; o[3] = a0.w*sc0.w + sh0.w;
        o[4] = a1.x*sc1.x + sh1.x; o[5] = a1.y*sc1.y + sh1.y;
        o[6] = a1.z*sc1.z + sh1.z; o[7] = a1.w*sc1.w + sh1.w;
#pragma unroll
        for (int u = 0; u < 8; u++) o[u] = (o[u] > 0.f) ? o[u] : (__expf(o[u]) - 1.f);
        o[0] += x0.x; o[1] += x0.y; o[2] += x0.z; o[3] += x0.w;
        o[4] += x1.x; o[5] += x1.y; o[6] += x1.z; o[7] += x1.w;
        float4 w0v = {o[0],o[1],o[2],o[3]}, w1v = {o[4],o[5],o[6],o[7]};
        *(float4*)&xb[ra*64 + c0]      = w0v;
        *(float4*)&xb[ra*64 + c0 + 16] = w1v;
        sh8 af;
#pragma unroll
        for (int u = 0; u < 8; u++) af[u] = f2bf(o[u]);
        if (kb == 0) af0 = af; else af1 = af;
    }
    f32x4 acc = {0,0,0,0};
    acc = __builtin_amdgcn_mfma_f32_16x16x32_bf16(af0, Bs[l],      acc, 0, 0, 0);
    acc = __builtin_amdgcn_mfma_f32_16x16x32_bf16(af1, Bs[64 + l], acc, 0, 0, 0);
    int rbase = n0 + (l >> 4) * 4, cb = l & 15;
#pragma unroll
    for (int r = 0; r < 4; r++) {
        int n = rbase + r;
        if (n >= NN) break;
        if (cb < 8) asrc[n*8 + cb] = acc[r];
        else        adst[n*8 + (cb-8)] = acc[r];
    }
}

// ============ layer-2 fused: edge-softmax + aggregate + MFMA projection (chunked+2x) ============
__global__ __launch_bounds__(256) void k_l2f(
        const int* __restrict__ rows, const int* __restrict__ csrc,
        const float* __restrict__ cea,
        const float* __restrict__ asrc, const float* __restrict__ adst,
        const float* __restrict__ wev,
        const float* __restrict__ x, const short* __restrict__ bsw,
        float* __restrict__ agg) {
    __shared__ short zl[16 * 520];
    int t = threadIdx.x, lane = t & 63, wv = t >> 6;
    int blk = blockIdx.x;
    int h = lane >> 3;
    float wh = wev[h];
    const float4* x4 = (const float4*)x;
    int fo   = (lane & 7) * 2;
    int kb_w = lane >> 2;
    int qd0  = 2 * (lane & 1);
    int jhi  = 4 * ((lane >> 1) & 1);
    for (int q = 0; q < 4; q++) {
        int r = wv * 4 + q;
        int d = blk * 16 + r;
        float acc[8] = {0,0,0,0,0,0,0,0};
        float den = 0.f;
        if (d < NN) {
            float adh = adst[d*8 + h];
            int rs = rows[d], re = rows[d+1];
            for (int c0 = rs; c0 < re; c0 += 64) {
                int cnt = re - c0; if (cnt > 64) cnt = 64;
                int ii = c0 + (lane < cnt ? lane : 0);
                int es = csrc[ii];
                float ef = cea[ii];
                int j = 0;
                for (; j + 1 < cnt; j += 2) {
                    int s0 = __shfl(es, j), s1 = __shfl(es, j+1);
                    float a0 = __shfl(ef, j), a1 = __shfl(ef, j+1);
                    float l0 = asrc[s0*8+h], l1 = asrc[s1*8+h];
                    float4 u0 = x4[s0*16 + fo], u1 = x4[s0*16 + fo + 1];
                    float4 v0 = x4[s1*16 + fo], v1 = x4[s1*16 + fo + 1];
                    l0 += adh + a0*wh; l1 += adh + a1*wh;
                    l0 = fmaxf(l0, 0.2f*l0); l1 = fmaxf(l1, 0.2f*l1);
                    float e0 = __expf(l0), e1 = __expf(l1);
                    den += e0 + e1;
                    acc[0] += e0*u0.x + e1*v0.x;
                    acc[1] += e0*u0.y + e1*v0.y;
                    acc[2] += e0*u0.z + e1*v0.z;
                    acc[3] += e0*u0.w + e1*v0.w;
                    acc[4] += e0*u1.x + e1*v1.x;
                    acc[5] += e0*u1.y + e1*v1.y;
                    acc[6] += e0*u1.z + e1*v1.z;
                    acc[7] += e0*u1.w + e1*v1.w;
                }
                if (j < cnt) {
                    int s = __shfl(es, j);
                    float a = __shfl(ef, j);
                    float l = asrc[s*8+h] + adh + a*wh;
                    l = fmaxf(l, 0.2f*l);
                    float e = __expf(l);
                    den += e;
                    float4 u0 = x4[s*16 + fo], u1 = x4[s*16 + fo + 1];
                    acc[0] += e*u0.x; acc[1] += e*u0.y; acc[2] += e*u0.z; acc[3] += e*u0.w;
                    acc[4] += e*u1.x; acc[5] += e*u1.y; acc[6] += e*u1.z; acc[7] += e*u1.w;
                }
            }
        }
        float inv = 1.0f / fmaxf(den, 1e-16f);
        short4 lo, hi;
        lo.x = f2bf(acc[0]*inv); lo.y = f2bf(acc[1]*inv);
        lo.z = f2bf(acc[2]*inv); lo.w = f2bf(acc[3]*inv);
        hi.x = f2bf(acc[4]*inv); hi.y = f2bf(acc[5]*inv);
        hi.z = f2bf(acc[6]*inv); hi.w = f2bf(acc[7]*inv);
        *(short4*)&zl[kb_w*520 + (r + 16*qd0)*8 + jhi]     = lo;
        *(short4*)&zl[kb_w*520 + (r + 16*(qd0+1))*8 + jhi] = hi;
    }
    __syncthreads();
    const sh8* Bs = (const sh8*)bsw;
    f32x4 acc = {0,0,0,0};
    for (int kb = 0; kb < 16; kb++) {
        sh8 a = *(const sh8*)&zl[kb*520 + lane*8];
        sh8 bf = Bs[(kb*4 + wv)*64 + lane];
        acc = __builtin_amdgcn_mfma_f32_16x16x32_bf16(a, bf, acc, 0, 0, 0);
    }
    int row = blk*16 + (lane >> 4) * 4;
    int col = wv*16 + (lane & 15);
#pragma unroll
    for (int rr = 0; rr < 4; rr++) {
        int n = row + rr;
        if (n < NN) agg[(size_t)n*64 + col] = acc[rr] * 0.125f;
    }
}

// ============ BN stats partials (bias cancels in training-mode BN) ============
__global__ void k_bnstats(const float* __restrict__ agg, float* __restrict__ part) {
    int t = threadIdx.x;
    int c = t & 63;
    int r0 = blockIdx.x * 4 + (t >> 6);
    float s = 0.f, q = 0.f;
    for (int n = r0; n < NN; n += gridDim.x * 4) {
        float y = agg[n*64 + c];
        s += y; q += y*y;
    }
    __shared__ float sd[512];
    sd[t] = s; sd[256 + t] = q;
    __syncthreads();
    if (t < 128) { sd[t] += sd[t+128]; sd[256+t] += sd[256+t+128]; }
    __syncthreads();
    if (t < 64) {
        part[blockIdx.x*128 + t]      = sd[t] + sd[t+64];
        part[blockIdx.x*128 + 64 + t] = sd[256+t] + sd[256+t+64];
    }
}

// ============ BN finalize ============
__global__ void k_bnfin(const float* __restrict__ part, const float* __restrict__ gam,
                        const float* __restrict__ bet, float* __restrict__ ab) {
    int c = threadIdx.x;
    if (c >= 64) return;
    float s = 0.f, q = 0.f;
    for (int b = 0; b < 128; b++) { s += part[b*128 + c]; q += part[b*128 + 64 + c]; }
    float m = s * (1.0f / NN);
    float v = q * (1.0f / NN) - m*m;
    float a = gam[c] * rsqrtf(v + 1e-5f);
    ab[c] = a;
    ab[64 + c] = bet[c] - m * a;
}

// ============ fused: BN2-apply + residual + dual pooling + MLP head ============
__global__ void k_poolmlp(const float* __restrict__ xb, const float* __restrict__ agg,
                          const float* __restrict__ ab, const int* __restrict__ goff,
                          const float* __restrict__ fc1w, const float* __restrict__ fc1b,
                          const float* __restrict__ fc2w, const float* __restrict__ fc2b,
                          const float* __restrict__ fgw, const float* __restrict__ fgb,
                          const float* __restrict__ fbw, const float* __restrict__ fbb,
                          float* __restrict__ out) {
    int g = blockIdx.x, t = threadIdx.x;
    int c = t & 63, r = t >> 6;
    float a = ab[c], sh = ab[64 + c];
    int st = goff[g], en = goff[g+1];
    float s = 0.f, mx = -INFINITY;
    for (int n = st + r; n < en; n += 4) {
        float o = agg[n*64 + c] * a + sh;
        o = (o > 0.f) ? o : (__expf(o) - 1.0f);
        float v = xb[n*64 + c] + o;
        s += v; mx = fmaxf(mx, v);
    }
    __shared__ float sd[512];
    __shared__ float sg[128], s1[128], s2[64];
    sd[t] = s; sd[256 + t] = mx;
    __syncthreads();
    if (t < 128) { sd[t] += sd[t+128]; sd[256+t] = fmaxf(sd[256+t], sd[256+t+128]); }
    __syncthreads();
    if (t < 64) {
        float cnt = (float)(en - st);
        sg[t]      = (sd[t] + sd[t+64]) / fmaxf(cnt, 1.0f);
        sg[64 + t] = fmaxf(sd[256+t], sd[256+t+64]);
    }
    __syncthreads();
    if (t < 128) {
        float av = fc1b[t];
        for (int i = 0; i < 128; i++) av += sg[i] * fc1w[i*128 + t];
        s1[t] = (av > 0.f) ? av : (__expf(av) - 1.f);
    }
    __syncthreads();
    if (t < 64) {
        float bv = fc2b[t];
        for (int i = 0; i < 128; i++) bv += s1[i] * fc2w[i*64 + t];
        s2[t] = (bv > 0.f) ? bv : (__expf(bv) - 1.f);
    }
    __syncthreads();
    if (t == 0) {
        float ga = fgb[0], be = fbb[0];
        for (int i = 0; i < 64; i++) { ga += s2[i] * fgw[i]; be += s2[i] * fbw[i]; }
        out[g*2 + 0] = ga;
        out[g*2 + 1] = be;
    }
}

extern "C" void kernel_launch(void* const* d_in, const int* in_sizes, int n_in,
                              void* d_out, int out_size, void* d_ws, size_t ws_size,
                              hipStream_t stream) {
    (void)in_sizes; (void)n_in; (void)out_size; (void)ws_size;
    const float* x3    = (const float*)d_in[0];
    const int*   ei    = (const int*)d_in[1];
    const float* ea    = (const float*)d_in[2];
    const int*   batch = (const int*)d_in[3];
    const float* ing   = (const float*)d_in[4];
    const float* inb   = (const float*)d_in[5];
    const float* w0    = (const float*)d_in[6];
    const float* we0   = (const float*)d_in[7];
    const float* as0   = (const float*)d_in[8];
    const float* ad0   = (const float*)d_in[9];
    const float* ae0   = (const float*)d_in[10];
    const float* bng0  = (const float*)d_in[12];
    const float* bnb0  = (const float*)d_in[13];
    const float* w1    = (const float*)d_in[14];
    const float* we1   = (const float*)d_in[15];
    const float* as1   = (const float*)d_in[16];
    const float* ad1   = (const float*)d_in[17];
    const float* ae1   = (const float*)d_in[18];
    const float* bng1  = (const float*)d_in[20];
    const float* bnb1  = (const float*)d_in[21];
    const float* w2    = (const float*)d_in[22];
    const float* we2   = (const float*)d_in[23];
    const float* as2   = (const float*)d_in[24];
    const float* ad2   = (const float*)d_in[25];
    const float* ae2   = (const float*)d_in[26];
    const float* bng2  = (const float*)d_in[28];
    const float* bnb2  = (const float*)d_in[29];
    const float* fc1w  = (const float*)d_in[30];
    const float* fc1b  = (const float*)d_in[31];
    const float* fc2w  = (const float*)d_in[32];
    const float* fc2b  = (const float*)d_in[33];
    const float* fgw   = (const float*)d_in[34];
    const float* fgb   = (const float*)d_in[35];
    const float* fbw   = (const float*)d_in[36];
    const float* fbb   = (const float*)d_in[37];

    float* fws = (float*)d_ws;
    int*   iws = (int*)d_ws;
    int*   cnt   = iws + O_CNT;
    int*   rows  = iws + O_ROWS;
    int*   cur   = iws + O_CUR;
    int*   goff  = iws + O_GOFF;
    float* ipart = fws + O_IPART;
    float* inbn  = fws + O_INBN;
    float* Ws    = fws + O_WS;
    float* Wd    = fws + O_WD;
    float* wev   = fws + O_WE;
    float* bpart = fws + O_BPART;
    float* ab    = fws + O_AB;
    short* bsw   = (short*)(fws + O_BSW);
    int*   csrc  = iws + O_CSRC;
    float* cea   = fws + O_CEA;
    float* xs    = fws + O_XS;
    float* asrc  = fws + O_ASRC;
    float* adst  = fws + O_ADST;
    float* agg   = fws + O_AGG;
    float* xb    = fws + O_X;
    short* bswc  = (short*)(fws + O_BSWC);
    short* bswa  = (short*)(fws + O_BSWA);
    int*   bsum  = iws + O_BSUM;
    int*   boff  = iws + O_BOFF;

    k_pre<<<172, 256, 0, stream>>>(batch, x3,
                                   w0, we0, as0, ad0, ae0,
                                   w1, we1, as1, ad1, ae1,
                                   w2, we2, as2, ad2, ae2,
                                   goff, ipart, Ws, Wd, wev, bsw, bswc, bswa);
    k_hist<<<NB, 256, 0, stream>>>(ei, cnt);
    k_scan1<<<98, 256, 0, stream>>>(cnt, rows, bsum);
    k_scan2<<<1, 64, 0, stream>>>(bsum, boff, ipart, inbn);
    k_scan3<<<98, 256, 0, stream>>>(boff, cnt, rows, cur);
    k_fill<<<NB, 256, 0, stream>>>(ei, ea, cur, csrc, cea);

    const int nblk64 = (NN * 64 + 255) / 256;   // 6250
    const int wblk16 = ((NN + 15) / 16 + 3) / 4; // 391 blocks of 4 waves (16 nodes/wave)

    // ---- layer 0 ----
    k_proj0<<<nblk64, 256, 0, stream>>>(x3, inbn, ing, inb, w0, Ws, Wd, xs, asrc, adst);
    k_agg8f<<<nblk64, 256, 0, stream>>>(rows, csrc, cea, asrc, adst, wev, xs, agg);
    k_bnstats<<<128, 256, 0, stream>>>(agg, bpart);
    k_bnfin<<<1, 64, 0, stream>>>(bpart, bng0, bnb0, ab);

    // ---- layer 1 (BN0-apply + xb + projection + logits via MFMA) ----
    k_proj1m<<<wblk16, 256, 0, stream>>>(agg, ab, bswc, xb, xs, asrc, adst);
    k_agg8f<<<nblk64, 256, 0, stream>>>(rows, csrc, cea, asrc, adst, wev + 8, xs, agg);
    k_bnstats<<<128, 256, 0, stream>>>(agg, bpart);
    k_bnfin<<<1, 64, 0, stream>>>(bpart, bng1, bnb1, ab);

    // ---- layer 2 (BN1-apply + residual + logits fused; then fused agg+MFMA) ----
    k_bnattn<<<wblk16, 256, 0, stream>>>(agg, ab, bswa, xb, asrc, adst);
    k_l2f<<<(NN + 15) / 16, 256, 0, stream>>>(rows, csrc, cea, asrc, adst, wev + 16,
                                              xb, bsw, agg);
    k_bnstats<<<128, 256, 0, stream>>>(agg, bpart);
    k_bnfin<<<1, 64, 0, stream>>>(bpart, bng2, bnb2, ab);

    // ---- BN2-apply + residual + pooling + MLP head ----
    k_poolmlp<<<GG, 256, 0, stream>>>(xb, agg, ab, goff, fc1w, fc1b, fc2w, fc2b,
                                      fgw, fgb, fbw, fbb, (float*)d_out);
}

// Round 12
// 413.794 us; speedup vs baseline: 1.9997x; 1.0064x over previous
//
#include <hip/hip_runtime.h>
#include <math.h>

#define NN 25000
#define EE 400000
#define GG 64
#define NB 64          // CSR-build blocks (private histogram copies)
#define PL 25024       // plane stride (NN padded to 16B)
#define EPB 6250       // edges per build block (EE/NB exact)

// ---- workspace layout (element offsets, 16B-aligned; NO memset needed) ----
static const int O_CNT   = 0;        // NB*PL ints (per-block histograms)
static const int O_ROWS  = 1601536;  // 25008 ints
static const int O_CUR   = 1626544;  // NB*PL ints (per-block cursor bases)
static const int O_GOFF  = 3228080;  // 72 ints
static const int O_IPART = 3228152;  // 96 f
static const int O_INBN  = 3228248;  // 8 f
static const int O_WS    = 3228256;  // 3*512 f
static const int O_WD    = 3229792;  // 3*512 f
static const int O_WE    = 3231328;  // 32 f
static const int O_BPART = 3231360;  // 128*128 f
static const int O_AB    = 3247744;  // 128 f
static const int O_BSW   = 3247872;  // 16384 f = 32768 bf16 (swizzled W2)
static const int O_CSRC  = 3264256;  // 400000 int
static const int O_CEA   = 3664256;  // 400000 f
static const int O_XS    = 4064256;  // 1.6M f
static const int O_ASRC  = 5664256;  // 200000 f
static const int O_ADST  = 5864256;  // 200000 f
static const int O_AGG   = 6064256;  // 1.6M f
static const int O_X     = 7664256;  // 1.6M f
static const int O_BSWC  = 9264256;  // 2560 f = 5120 bf16
static const int O_BSWA  = 9266816;  // 512 f = 1024 bf16
static const int O_BSUM  = 9267328;  // 104 ints
static const int O_BOFF  = 9267432;  // 104 ints

using f32x4 = __attribute__((ext_vector_type(4))) float;
using sh8   = __attribute__((ext_vector_type(8))) short;  // 8 bf16

__device__ inline short f2bf(float f) {
    unsigned u = __float_as_uint(f);
    unsigned r = (u + 0x7FFFu + ((u >> 16) & 1u)) >> 16;   // RNE to bf16
    return (short)r;
}

// ============ setup (no histogram): instats | goff | prew x3 | bswz | bswc | bswa ============
__global__ void k_pre(const int* __restrict__ batch, const float* __restrict__ x3,
                      const float* w0, const float* we0, const float* as0, const float* ad0, const float* ae0,
                      const float* w1, const float* we1, const float* as1, const float* ad1, const float* ae1,
                      const float* w2, const float* we2, const float* as2, const float* ad2, const float* ae2,
                      int* __restrict__ goff, float* __restrict__ ipart,
                      float* __restrict__ Ws, float* __restrict__ Wd, float* __restrict__ wev,
                      short* __restrict__ bsw, short* __restrict__ bswc, short* __restrict__ bswa) {
    __shared__ float sd[1536];
    int b = blockIdx.x, t = threadIdx.x;
    if (b < 16) {                         // input-BN partial stats
        int ib = b;
        float s[3] = {0,0,0}, q[3] = {0,0,0};
        for (int n = ib * 256 + t; n < NN; n += 16 * 256) {
#pragma unroll
            for (int i = 0; i < 3; i++) { float v = x3[n*3+i]; s[i] += v; q[i] += v*v; }
        }
#pragma unroll
        for (int i = 0; i < 3; i++) { sd[t*6+i] = s[i]; sd[t*6+3+i] = q[i]; }
        __syncthreads();
        for (int off = 128; off > 0; off >>= 1) {
            if (t < off) {
#pragma unroll
                for (int i = 0; i < 6; i++) sd[t*6+i] += sd[(t+off)*6+i];
            }
            __syncthreads();
        }
        if (t < 6) ipart[ib*6 + t] = sd[t];
    } else if (b == 16) {                 // graph offsets (batch sorted)
        if (t <= GG) {
            int g = t, lo = 0, hi = NN;
            while (lo < hi) { int mid = (lo + hi) >> 1; if (batch[mid] < g) lo = mid + 1; else hi = mid; }
            goff[g] = lo;
        }
    } else if (b < 20) {                  // per-layer attention weight fold
        int L = b - 17;
        const float *W, *Wep, *as_, *ad_, *ae_; int INF, CC;
        if (L == 0)      { W = w0; Wep = we0; as_ = as0; ad_ = ad0; ae_ = ae0; INF = 3;  CC = 8;  }
        else if (L == 1) { W = w1; Wep = we1; as_ = as1; ad_ = ad1; ae_ = ae1; INF = 64; CC = 8;  }
        else             { W = w2; Wep = we2; as_ = as2; ad_ = ad2; ae_ = ae2; INF = 64; CC = 64; }
        int HC = 8 * CC;
        for (int tt = t; tt < INF * 8; tt += 256) {
            int i = tt >> 3, h = tt & 7;
            float s = 0.f, d = 0.f;
            for (int c = 0; c < CC; c++) {
                float w = W[i*HC + h*CC + c];
                s += w * as_[h*CC + c];
                d += w * ad_[h*CC + c];
            }
            Ws[L*512 + i*8 + h] = s; Wd[L*512 + i*8 + h] = d;
        }
        if (t < 8) {
            float s = 0.f;
            for (int c = 0; c < CC; c++) s += Wep[t*CC + c] * ae_[t*CC + c];
            wev[L*8 + t] = s;
        }
    } else if (b < 148) {                 // W2 swizzle (128 blocks)
        int idx = (b - 20) * 256 + t;     // < 32768
        int j  = idx & 7;
        int l  = (idx >> 3) & 63;
        int nt = (idx >> 9) & 3;
        int kb = idx >> 11;
        int k = kb*32 + (l >> 4)*4 + (j & 3) + 16*(j >> 2);
        int c = nt*16 + (l & 15);
        int h = k >> 6, i = k & 63;
        bsw[idx] = f2bf(w2[i*512 + h*64 + c]);
    } else if (b < 168) {                 // layer-1 cat [W1|Ws1|Wd1] swizzle (20 blocks)
        int idx = (b - 148) * 256 + t;    // < 5120
        int j  = idx & 7;
        int l  = (idx >> 3) & 63;
        int r2 = idx >> 9;                // 0..9
        int nt = r2 % 5, kb = r2 / 5;
        int k = kb*32 + (l >> 4)*4 + (j & 3) + 16*(j >> 2);
        int c = nt*16 + (l & 15);
        float val;
        if (c < 64) val = w1[k*64 + c];
        else {
            int h = (c - 64) & 7;
            const float* aa = (c < 72) ? as1 : ad1;
            float s = 0.f;
            for (int cc = 0; cc < 8; cc++) s += w1[k*64 + h*8 + cc] * aa[h*8 + cc];
            val = s;
        }
        bswc[idx] = f2bf(val);
    } else {                              // layer-2 [Ws2|Wd2] swizzle (4 blocks)
        int idx = (b - 168) * 256 + t;    // < 1024
        int j  = idx & 7;
        int l  = (idx >> 3) & 63;
        int kb = idx >> 9;                // 0..1
        int k = kb*32 + (l >> 4)*4 + (j & 3) + 16*(j >> 2);
        int c = l & 15;
        int h = c & 7;
        const float* aa = (c < 8) ? as2 : ad2;
        float s = 0.f;
        for (int cc = 0; cc < 64; cc++) s += w2[k*512 + h*64 + cc] * aa[h*64 + cc];
        bswa[idx] = f2bf(s);
    }
}

// ============ edge histogram: per-block private LDS histogram, zero global atomics ============
__global__ __launch_bounds__(256) void k_hist(const int* __restrict__ ei, int* __restrict__ cnt) {
    __shared__ int hb[PL];
    int t = threadIdx.x, b = blockIdx.x;
    for (int i = t; i < PL; i += 256) hb[i] = 0;
    __syncthreads();
    int e0 = b * EPB;
    for (int e = e0 + t; e < e0 + EPB; e += 256)
        atomicAdd(&hb[ei[EE + e]], 1);
    __syncthreads();
    for (int i = t; i < NN; i += 256) cnt[b * PL + i] = hb[i];
}

// ============ hierarchical degree scan ============
__global__ void k_scan1(const int* __restrict__ cnt, int* __restrict__ rows,
                        int* __restrict__ bsum) {
    int t = threadIdx.x, b = blockIdx.x;
    int i = b * 256 + t;
    int v = 0;
    if (i < NN) {
        for (int r = 0; r < NB; r++) v += cnt[r * PL + i];
    }
    __shared__ int sd[256];
    sd[t] = v; __syncthreads();
    for (int off = 1; off < 256; off <<= 1) {
        int x = (t >= off) ? sd[t - off] : 0;
        __syncthreads();
        sd[t] += x;
        __syncthreads();
    }
    if (i < NN) rows[i] = sd[t] - v;     // exclusive local scan
    if (t == 255) bsum[b] = sd[255];
}

__global__ void k_scan2(const int* __restrict__ bsum, int* __restrict__ boff,
                        const float* __restrict__ ipart, float* __restrict__ inbn) {
    int t = threadIdx.x;
    if (t == 0) {
        int run = 0;
        for (int b = 0; b < 98; b++) { int v = bsum[b]; boff[b] = run; run += v; }
    }
    if (t < 6) { float s = 0.f; for (int b = 0; b < 16; b++) s += ipart[b*6 + t]; inbn[t] = s; }
}

__global__ void k_scan3(const int* __restrict__ boff, const int* __restrict__ cnt,
                        int* __restrict__ rows, int* __restrict__ cur) {
    int t = threadIdx.x, b = blockIdx.x;
    int i = b * 256 + t;
    if (i < NN) {
        int run = rows[i] + boff[b];
        rows[i] = run;
        for (int r = 0; r < NB; r++) {
            cur[r * PL + i] = run;
            run += cnt[r * PL + i];
        }
    }
    if (b == 0 && t == 0) rows[NN] = EE;
}

// ============ CSR fill: LDS cursor per block, zero global atomics ============
__global__ __launch_bounds__(256) void k_fill(const int* __restrict__ ei, const float* __restrict__ ea,
                       const int* __restrict__ cur, int* __restrict__ csrc,
                       float* __restrict__ cea) {
    __shared__ int lc[PL];
    int t = threadIdx.x, b = blockIdx.x;
    for (int i = t; i < NN; i += 256) lc[i] = cur[b * PL + i];
    __syncthreads();
    int e0 = b * EPB;
    for (int e = e0 + t; e < e0 + EPB; e += 256) {
        int s = ei[e], d = ei[EE + e];
        int pos = atomicAdd(&lc[d], 1);
        csrc[pos] = s; cea[pos] = ea[e];
    }
}

// ============ layer-0 projection (input BN fused, in=3) ============
__global__ void k_proj0(const float* __restrict__ x, const float* __restrict__ sums,
                        const float* __restrict__ g, const float* __restrict__ b,
                        const float* __restrict__ W0,
                        const float* __restrict__ Ws, const float* __restrict__ Wd,
                        float* __restrict__ xs, float* __restrict__ asrc, float* __restrict__ adst) {
    int idx = blockIdx.x * 256 + threadIdx.x;
    if (idx >= NN * 64) return;
    int n = idx >> 6, j = idx & 63;
    float xn[3];
#pragma unroll
    for (int i = 0; i < 3; i++) {
        float m = sums[i] * (1.0f / NN);
        float v = sums[3+i] * (1.0f / NN) - m*m;
        xn[i] = (x[n*3+i] - m) * rsqrtf(v + 1e-5f) * g[i] + b[i];
    }
    float a = 0.f;
#pragma unroll
    for (int i = 0; i < 3; i++) a += xn[i] * W0[i*64 + j];
    xs[n*64 + j] = a;
    if (j < 16) {
        const float* WA = (j < 8) ? Ws : Wd;
        int h = j & 7;
        float s = 0.f;
#pragma unroll
        for (int i = 0; i < 3; i++) s += xn[i] * WA[i*8 + h];
        if (j < 8) asrc[n*8 + h] = s; else adst[n*8 + h] = s;
    }
}

// ============ fused edge-softmax + aggregation, C=8 (layers 0,1), chunked+4x ============
__global__ void k_agg8f(const int* __restrict__ rows, const int* __restrict__ csrc,
                        const float* __restrict__ cea,
                        const float* __restrict__ asrc, const float* __restrict__ adst,
                        const float* __restrict__ wev,
                        const float* __restrict__ xs, float* __restrict__ agg) {
    int lane = threadIdx.x & 63;
    int d = (blockIdx.x * blockDim.x + threadIdx.x) >> 6;
    if (d >= NN) return;
    int h = lane >> 3;
    float adh = adst[d*8 + h];
    float wh  = wev[h];
    int rs = rows[d], re = rows[d+1];
    float acc = 0.f, den = 0.f;
    for (int c0 = rs; c0 < re; c0 += 64) {
        int cnt = re - c0; if (cnt > 64) cnt = 64;
        int ii = c0 + (lane < cnt ? lane : 0);
        int es = csrc[ii];
        float ef = cea[ii];
        int j = 0;
        for (; j + 3 < cnt; j += 4) {
            int s0 = __shfl(es, j),   s1 = __shfl(es, j+1);
            int s2 = __shfl(es, j+2), s3 = __shfl(es, j+3);
            float a0 = __shfl(ef, j),   a1 = __shfl(ef, j+1);
            float a2 = __shfl(ef, j+2), a3 = __shfl(ef, j+3);
            float l0 = asrc[s0*8+h], l1 = asrc[s1*8+h];
            float l2 = asrc[s2*8+h], l3 = asrc[s3*8+h];
            float x0 = xs[s0*64+lane], x1 = xs[s1*64+lane];
            float x2 = xs[s2*64+lane], x3 = xs[s3*64+lane];
            l0 += adh + a0*wh; l1 += adh + a1*wh;
            l2 += adh + a2*wh; l3 += adh + a3*wh;
            l0 = fmaxf(l0, 0.2f*l0); l1 = fmaxf(l1, 0.2f*l1);
            l2 = fmaxf(l2, 0.2f*l2); l3 = fmaxf(l3, 0.2f*l3);
            float e0 = __expf(l0), e1 = __expf(l1), e2 = __expf(l2), e3 = __expf(l3);
            den += (e0 + e1) + (e2 + e3);
            acc += e0*x0; acc += e1*x1; acc += e2*x2; acc += e3*x3;
        }
        for (; j < cnt; j++) {
            int s = __shfl(es, j);
            float a = __shfl(ef, j);
            float l = asrc[s*8+h] + adh + a*wh;
            l = fmaxf(l, 0.2f*l);
            float e = __expf(l);
            den += e;
            acc += e * xs[s*64+lane];
        }
    }
    agg[d*64 + lane] = acc / fmaxf(den, 1e-16f);
}

// ============ layer-1 projection via MFMA: [xb | asrc | adst] = elu(bn(agg)) @ [W1|Ws1|Wd1] ============
__global__ void k_proj1m(const float* __restrict__ agg, const float* __restrict__ ab,
                         const short* __restrict__ bswc,
                         float* __restrict__ xb, float* __restrict__ xs,
                         float* __restrict__ asrc, float* __restrict__ adst) {
    int l = threadIdx.x & 63;
    int wid = (blockIdx.x * blockDim.x + threadIdx.x) >> 6;
    int n0 = wid * 16;
    if (n0 >= NN) return;
    int ra = n0 + (l & 15); if (ra > NN-1) ra = NN-1;
    int kq = (l >> 4) * 4;
    const sh8* Bs = (const sh8*)bswc;
    sh8 af0, af1;
#pragma unroll
    for (int kb = 0; kb < 2; kb++) {
        int c0 = kb*32 + kq;
        float4 a0 = *(const float4*)&agg[ra*64 + c0];
        float4 a1 = *(const float4*)&agg[ra*64 + c0 + 16];
        float4 sc0 = *(const float4*)&ab[c0];
        float4 sh0 = *(const float4*)&ab[64 + c0];
        float4 sc1 = *(const float4*)&ab[c0 + 16];
        float4 sh1 = *(const float4*)&ab[64 + c0 + 16];
        float o[8];
        o[0] = a0.x*sc0.x + sh0.x; o[1] = a0.y*sc0.y + sh0.y;
        o[2] = a0.z*sc0.z + sh0.z; o[3] = a0.w*sc0.w + sh0.w;
        o[4] = a1.x*sc1.x + sh1.x; o[5] = a1.y*sc1.y + sh1.y;
        o[6] = a1.z*sc1.z + sh1.z; o[7] = a1.w*sc1.w + sh1.w;
#pragma unroll
        for (int u = 0; u < 8; u++) o[u] = (o[u] > 0.f) ? o[u] : (__expf(o[u]) - 1.f);
        float4 w0v = {o[0],o[1],o[2],o[3]}, w1v = {o[4],o[5],o[6],o[7]};
        *(float4*)&xb[ra*64 + c0]      = w0v;
        *(float4*)&xb[ra*64 + c0 + 16] = w1v;
        sh8 af;
#pragma unroll
        for (int u = 0; u < 8; u++) af[u] = f2bf(o[u]);
        if (kb == 0) af0 = af; else af1 = af;
    }
    f32x4 acc[5];
#pragma unroll
    for (int nt = 0; nt < 5; nt++) acc[nt] = (f32x4){0,0,0,0};
#pragma unroll
    for (int nt = 0; nt < 5; nt++) {
        acc[nt] = __builtin_amdgcn_mfma_f32_16x16x32_bf16(af0, Bs[nt*64 + l], acc[nt], 0, 0, 0);
        acc[nt] = __builtin_amdgcn_mfma_f32_16x16x32_bf16(af1, Bs[(5+nt)*64 + l], acc[nt], 0, 0, 0);
    }
    int rbase = n0 + (l >> 4) * 4, cb = l & 15;
#pragma unroll
    for (int r = 0; r < 4; r++) {
        int n = rbase + r;
        if (n >= NN) break;
#pragma unroll
        for (int nt = 0; nt < 4; nt++) xs[n*64 + nt*16 + cb] = acc[nt][r];
        if (cb < 8) asrc[n*8 + cb] = acc[4][r];
        else        adst[n*8 + (cb-8)] = acc[4][r];
    }
}

// ============ fused BN1-apply + residual + layer-2 attention logits (MFMA) ============
__global__ void k_bnattn(const float* __restrict__ agg, const float* __restrict__ ab,
                         const short* __restrict__ bswa,
                         float* __restrict__ xb,
                         float* __restrict__ asrc, float* __restrict__ adst) {
    int l = threadIdx.x & 63;
    int wid = (blockIdx.x * blockDim.x + threadIdx.x) >> 6;
    int n0 = wid * 16;
    if (n0 >= NN) return;
    int ra = n0 + (l & 15); if (ra > NN-1) ra = NN-1;
    int kq = (l >> 4) * 4;
    const sh8* Bs = (const sh8*)bswa;
    sh8 af0, af1;
#pragma unroll
    for (int kb = 0; kb < 2; kb++) {
        int c0 = kb*32 + kq;
        float4 a0 = *(const float4*)&agg[ra*64 + c0];
        float4 a1 = *(const float4*)&agg[ra*64 + c0 + 16];
        float4 x0 = *(const float4*)&xb[ra*64 + c0];
        float4 x1 = *(const float4*)&xb[ra*64 + c0 + 16];
        float4 sc0 = *(const float4*)&ab[c0];
        float4 sh0 = *(const float4*)&ab[64 + c0];
        float4 sc1 = *(const float4*)&ab[c0 + 16];
        float4 sh1 = *(const float4*)&ab[64 + c0 + 16];
        float o[8];
        o[0] = a0.x*sc0.x + sh0.x; o[1] = a0.y*sc0.y + sh0.y;
        o[2] = a0.z*sc0.z + sh0.z; o[3] = a0.w*sc0.w + sh0.w;
        o[4] = a1.x*sc1.x + sh1.x; o[5] = a1.y*sc1.y + sh1.y;
        o[6] = a1.z*sc1.z + sh1.z; o[7] = a1.w*sc1.w + sh1.w;
#pragma unroll
        for (int u = 0; u < 8; u++) o[u] = (o[u] > 0.f) ? o[u] : (__expf(o[u]) - 1.f);
        o[0] += x0.x; o[1] += x0.y; o[2] += x0.z; o[3] += x0.w;
        o[4] += x1.x; o[5] += x1.y; o[6] += x1.z; o[7] += x1.w;
        float4 w0v = {o[0],o[1],o[2],o[3]}, w1v = {o[4],o[5],o[6],o[7]};
        *(float4*)&xb[ra*64 + c0]      = w0v;
        *(float4*)&xb[ra*64 + c0 + 16] = w1v;
        sh8 af;
#pragma unroll
        for (int u = 0; u < 8; u++) af[u] = f2bf(o[u]);
        if (kb == 0) af0 = af; else af1 = af;
    }
    f32x4 acc = {0,0,0,0};
    acc = __builtin_amdgcn_mfma_f32_16x16x32_bf16(af0, Bs[l],      acc, 0, 0, 0);
    acc = __builtin_amdgcn_mfma_f32_16x16x32_bf16(af1, Bs[64 + l], acc, 0, 0, 0);
    int rbase = n0 + (l >> 4) * 4, cb = l & 15;
#pragma unroll
    for (int r = 0; r < 4; r++) {
        int n = rbase + r;
        if (n >= NN) break;
        if (cb < 8) asrc[n*8 + cb] = acc[r];
        else        adst[n*8 + (cb-8)] = acc[r];
    }
}

// ============ layer-2 fused: edge-softmax + aggregate + MFMA projection ============
// 16 waves/block, ONE node per wave (was 4 nodes serially) -> 4x less serial gather work.
__global__ __launch_bounds__(1024) void k_l2f(
        const int* __restrict__ rows, const int* __restrict__ csrc,
        const float* __restrict__ cea,
        const float* __restrict__ asrc, const float* __restrict__ adst,
        const float* __restrict__ wev,
        const float* __restrict__ x, const short* __restrict__ bsw,
        float* __restrict__ agg) {
    __shared__ short zl[16 * 520];
    int t = threadIdx.x, lane = t & 63, wv = t >> 6;   // wv in 0..15
    int blk = blockIdx.x;
    int h = lane >> 3;
    float wh = wev[h];
    const float4* x4 = (const float4*)x;
    int fo   = (lane & 7) * 2;
    int kb_w = lane >> 2;
    int qd0  = 2 * (lane & 1);
    int jhi  = 4 * ((lane >> 1) & 1);
    int r = wv;                 // this wave's row in the 16-node tile
    int d = blk * 16 + r;
    float acc[8] = {0,0,0,0,0,0,0,0};
    float den = 0.f;
    if (d < NN) {
        float adh = adst[d*8 + h];
        int rs = rows[d], re = rows[d+1];
        for (int c0 = rs; c0 < re; c0 += 64) {
            int cnt = re - c0; if (cnt > 64) cnt = 64;
            int ii = c0 + (lane < cnt ? lane : 0);
            int es = csrc[ii];
            float ef = cea[ii];
            int j = 0;
            for (; j + 1 < cnt; j += 2) {
                int s0 = __shfl(es, j), s1 = __shfl(es, j+1);
                float a0 = __shfl(ef, j), a1 = __shfl(ef, j+1);
                float l0 = asrc[s0*8+h], l1 = asrc[s1*8+h];
                float4 u0 = x4[s0*16 + fo], u1 = x4[s0*16 + fo + 1];
                float4 v0 = x4[s1*16 + fo], v1 = x4[s1*16 + fo + 1];
                l0 += adh + a0*wh; l1 += adh + a1*wh;
                l0 = fmaxf(l0, 0.2f*l0); l1 = fmaxf(l1, 0.2f*l1);
                float e0 = __expf(l0), e1 = __expf(l1);
                den += e0 + e1;
                acc[0] += e0*u0.x + e1*v0.x;
                acc[1] += e0*u0.y + e1*v0.y;
                acc[2] += e0*u0.z + e1*v0.z;
                acc[3] += e0*u0.w + e1*v0.w;
                acc[4] += e0*u1.x + e1*v1.x;
                acc[5] += e0*u1.y + e1*v1.y;
                acc[6] += e0*u1.z + e1*v1.z;
                acc[7] += e0*u1.w + e1*v1.w;
            }
            if (j < cnt) {
                int s = __shfl(es, j);
                float a = __shfl(ef, j);
                float l = asrc[s*8+h] + adh + a*wh;
                l = fmaxf(l, 0.2f*l);
                float e = __expf(l);
                den += e;
                float4 u0 = x4[s*16 + fo], u1 = x4[s*16 + fo + 1];
                acc[0] += e*u0.x; acc[1] += e*u0.y; acc[2] += e*u0.z; acc[3] += e*u0.w;
                acc[4] += e*u1.x; acc[5] += e*u1.y; acc[6] += e*u1.z; acc[7] += e*u1.w;
            }
        }
    }
    float inv = 1.0f / fmaxf(den, 1e-16f);
    short4 lo, hi;
    lo.x = f2bf(acc[0]*inv); lo.y = f2bf(acc[1]*inv);
    lo.z = f2bf(acc[2]*inv); lo.w = f2bf(acc[3]*inv);
    hi.x = f2bf(acc[4]*inv); hi.y = f2bf(acc[5]*inv);
    hi.z = f2bf(acc[6]*inv); hi.w = f2bf(acc[7]*inv);
    *(short4*)&zl[kb_w*520 + (r + 16*qd0)*8 + jhi]     = lo;
    *(short4*)&zl[kb_w*520 + (r + 16*(qd0+1))*8 + jhi] = hi;
    __syncthreads();
    if (wv < 4) {
        const sh8* Bs = (const sh8*)bsw;
        f32x4 oacc = {0,0,0,0};
        for (int kb = 0; kb < 16; kb++) {
            sh8 a = *(const sh8*)&zl[kb*520 + lane*8];
            sh8 bf = Bs[(kb*4 + wv)*64 + lane];
            oacc = __builtin_amdgcn_mfma_f32_16x16x32_bf16(a, bf, oacc, 0, 0, 0);
        }
        int row = blk*16 + (lane >> 4) * 4;
        int col = wv*16 + (lane & 15);
#pragma unroll
        for (int rr = 0; rr < 4; rr++) {
            int n = row + rr;
            if (n < NN) agg[(size_t)n*64 + col] = oacc[rr] * 0.125f;
        }
    }
}

// ============ BN stats partials (bias cancels in training-mode BN) ============
__global__ void k_bnstats(const float* __restrict__ agg, float* __restrict__ part) {
    int t = threadIdx.x;
    int c = t & 63;
    int r0 = blockIdx.x * 4 + (t >> 6);
    float s = 0.f, q = 0.f;
    for (int n = r0; n < NN; n += gridDim.x * 4) {
        float y = agg[n*64 + c];
        s += y; q += y*y;
    }
    __shared__ float sd[512];
    sd[t] = s; sd[256 + t] = q;
    __syncthreads();
    if (t < 128) { sd[t] += sd[t+128]; sd[256+t] += sd[256+t+128]; }
    __syncthreads();
    if (t < 64) {
        part[blockIdx.x*128 + t]      = sd[t] + sd[t+64];
        part[blockIdx.x*128 + 64 + t] = sd[256+t] + sd[256+t+64];
    }
}

// ============ BN finalize ============
__global__ void k_bnfin(const float* __restrict__ part, const float* __restrict__ gam,
                        const float* __restrict__ bet, float* __restrict__ ab) {
    int c = threadIdx.x;
    if (c >= 64) return;
    float s = 0.f, q = 0.f;
    for (int b = 0; b < 128; b++) { s += part[b*128 + c]; q += part[b*128 + 64 + c]; }
    float m = s * (1.0f / NN);
    float v = q * (1.0f / NN) - m*m;
    float a = gam[c] * rsqrtf(v + 1e-5f);
    ab[c] = a;
    ab[64 + c] = bet[c] - m * a;
}

// ============ fused: BN2-apply + residual + dual pooling + MLP head ============
__global__ void k_poolmlp(const float* __restrict__ xb, const float* __restrict__ agg,
                          const float* __restrict__ ab, const int* __restrict__ goff,
                          const float* __restrict__ fc1w, const float* __restrict__ fc1b,
                          const float* __restrict__ fc2w, const float* __restrict__ fc2b,
                          const float* __restrict__ fgw, const float* __restrict__ fgb,
                          const float* __restrict__ fbw, const float* __restrict__ fbb,
                          float* __restrict__ out) {
    int g = blockIdx.x, t = threadIdx.x;
    int c = t & 63, r = t >> 6;
    float a = ab[c], sh = ab[64 + c];
    int st = goff[g], en = goff[g+1];
    float s = 0.f, mx = -INFINITY;
    for (int n = st + r; n < en; n += 4) {
        float o = agg[n*64 + c] * a + sh;
        o = (o > 0.f) ? o : (__expf(o) - 1.0f);
        float v = xb[n*64 + c] + o;
        s += v; mx = fmaxf(mx, v);
    }
    __shared__ float sd[512];
    __shared__ float sg[128], s1[128], s2[64];
    sd[t] = s; sd[256 + t] = mx;
    __syncthreads();
    if (t < 128) { sd[t] += sd[t+128]; sd[256+t] = fmaxf(sd[256+t], sd[256+t+128]); }
    __syncthreads();
    if (t < 64) {
        float cnt = (float)(en - st);
        sg[t]      = (sd[t] + sd[t+64]) / fmaxf(cnt, 1.0f);
        sg[64 + t] = fmaxf(sd[256+t], sd[256+t+64]);
    }
    __syncthreads();
    if (t < 128) {
        float av = fc1b[t];
        for (int i = 0; i < 128; i++) av += sg[i] * fc1w[i*128 + t];
        s1[t] = (av > 0.f) ? av : (__expf(av) - 1.f);
    }
    __syncthreads();
    if (t < 64) {
        float bv = fc2b[t];
        for (int i = 0; i < 128; i++) bv += s1[i] * fc2w[i*64 + t];
        s2[t] = (bv > 0.f) ? bv : (__expf(bv) - 1.f);
    }
    __syncthreads();
    if (t == 0) {
        float ga = fgb[0], be = fbb[0];
        for (int i = 0; i < 64; i++) { ga += s2[i] * fgw[i]; be += s2[i] * fbw[i]; }
        out[g*2 + 0] = ga;
        out[g*2 + 1] = be;
    }
}

extern "C" void kernel_launch(void* const* d_in, const int* in_sizes, int n_in,
                              void* d_out, int out_size, void* d_ws, size_t ws_size,
                              hipStream_t stream) {
    (void)in_sizes; (void)n_in; (void)out_size; (void)ws_size;
    const float* x3    = (const float*)d_in[0];
    const int*   ei    = (const int*)d_in[1];
    const float* ea    = (const float*)d_in[2];
    const int*   batch = (const int*)d_in[3];
    const float* ing   = (const float*)d_in[4];
    const float* inb   = (const float*)d_in[5];
    const float* w0    = (const float*)d_in[6];
    const float* we0   = (const float*)d_in[7];
    const float* as0   = (const float*)d_in[8];
    const float* ad0   = (const float*)d_in[9];
    const float* ae0   = (const float*)d_in[10];
    const float* bng0  = (const float*)d_in[12];
    const float* bnb0  = (const float*)d_in[13];
    const float* w1    = (const float*)d_in[14];
    const float* we1   = (const float*)d_in[15];
    const float* as1   = (const float*)d_in[16];
    const float* ad1   = (const float*)d_in[17];
    const float* ae1   = (const float*)d_in[18];
    const float* bng1  = (const float*)d_in[20];
    const float* bnb1  = (const float*)d_in[21];
    const float* w2    = (const float*)d_in[22];
    const float* we2   = (const float*)d_in[23];
    const float* as2   = (const float*)d_in[24];
    const float* ad2   = (const float*)d_in[25];
    const float* ae2   = (const float*)d_in[26];
    const float* bng2  = (const float*)d_in[28];
    const float* bnb2  = (const float*)d_in[29];
    const float* fc1w  = (const float*)d_in[30];
    const float* fc1b  = (const float*)d_in[31];
    const float* fc2w  = (const float*)d_in[32];
    const float* fc2b  = (const float*)d_in[33];
    const float* fgw   = (const float*)d_in[34];
    const float* fgb   = (const float*)d_in[35];
    const float* fbw   = (const float*)d_in[36];
    const float* fbb   = (const float*)d_in[37];

    float* fws = (float*)d_ws;
    int*   iws = (int*)d_ws;
    int*   cnt   = iws + O_CNT;
    int*   rows  = iws + O_ROWS;
    int*   cur   = iws + O_CUR;
    int*   goff  = iws + O_GOFF;
    float* ipart = fws + O_IPART;
    float* inbn  = fws + O_INBN;
    float* Ws    = fws + O_WS;
    float* Wd    = fws + O_WD;
    float* wev   = fws + O_WE;
    float* bpart = fws + O_BPART;
    float* ab    = fws + O_AB;
    short* bsw   = (short*)(fws + O_BSW);
    int*   csrc  = iws + O_CSRC;
    float* cea   = fws + O_CEA;
    float* xs    = fws + O_XS;
    float* asrc  = fws + O_ASRC;
    float* adst  = fws + O_ADST;
    float* agg   = fws + O_AGG;
    float* xb    = fws + O_X;
    short* bswc  = (short*)(fws + O_BSWC);
    short* bswa  = (short*)(fws + O_BSWA);
    int*   bsum  = iws + O_BSUM;
    int*   boff  = iws + O_BOFF;

    k_pre<<<172, 256, 0, stream>>>(batch, x3,
                                   w0, we0, as0, ad0, ae0,
                                   w1, we1, as1, ad1, ae1,
                                   w2, we2, as2, ad2, ae2,
                                   goff, ipart, Ws, Wd, wev, bsw, bswc, bswa);
    k_hist<<<NB, 256, 0, stream>>>(ei, cnt);
    k_scan1<<<98, 256, 0, stream>>>(cnt, rows, bsum);
    k_scan2<<<1, 64, 0, stream>>>(bsum, boff, ipart, inbn);
    k_scan3<<<98, 256, 0, stream>>>(boff, cnt, rows, cur);
    k_fill<<<NB, 256, 0, stream>>>(ei, ea, cur, csrc, cea);

    const int nblk64 = (NN * 64 + 255) / 256;   // 6250
    const int wblk16 = ((NN + 15) / 16 + 3) / 4; // 391 blocks of 4 waves (16 nodes/wave)

    // ---- layer 0 ----
    k_proj0<<<nblk64, 256, 0, stream>>>(x3, inbn, ing, inb, w0, Ws, Wd, xs, asrc, adst);
    k_agg8f<<<nblk64, 256, 0, stream>>>(rows, csrc, cea, asrc, adst, wev, xs, agg);
    k_bnstats<<<128, 256, 0, stream>>>(agg, bpart);
    k_bnfin<<<1, 64, 0, stream>>>(bpart, bng0, bnb0, ab);

    // ---- layer 1 (BN0-apply + xb + projection + logits via MFMA) ----
    k_proj1m<<<wblk16, 256, 0, stream>>>(agg, ab, bswc, xb, xs, asrc, adst);
    k_agg8f<<<nblk64, 256, 0, stream>>>(rows, csrc, cea, asrc, adst, wev + 8, xs, agg);
    k_bnstats<<<128, 256, 0, stream>>>(agg, bpart);
    k_bnfin<<<1, 64, 0, stream>>>(bpart, bng1, bnb1, ab);

    // ---- layer 2 (BN1-apply + residual + logits fused; then fused agg+MFMA, 16 waves/block) ----
    k_bnattn<<<wblk16, 256, 0, stream>>>(agg, ab, bswa, xb, asrc, adst);
    k_l2f<<<(NN + 15) / 16, 1024, 0, stream>>>(rows, csrc, cea, asrc, adst, wev + 16,
                                               xb, bsw, agg);
    k_bnstats<<<128, 256, 0, stream>>>(agg, bpart);
    k_bnfin<<<1, 64, 0, stream>>>(bpart, bng2, bnb2, ab);

    // ---- BN2-apply + residual + pooling + MLP head ----
    k_poolmlp<<<GG, 256, 0, stream>>>(xb, agg, ab, goff, fc1w, fc1b, fc2w, fc2b,
                                      fgw, fgb, fbw, fbb, (float*)d_out);
}